// Round 10
// baseline (589.936 us; speedup 1.0000x reference)
//
#include <hip/hip_runtime.h>
#include <hip/hip_bf16.h>

#define NN 100000
#define NE 600000
#define DD 128
#define RR 200
#define SCAN_NB ((NN + 255) / 256)   // 391

typedef __attribute__((ext_vector_type(8))) short bf16x8;
typedef __attribute__((ext_vector_type(4))) float f32x4;

__device__ __forceinline__ unsigned int bfbits(float x) {
    return (unsigned int)__builtin_bit_cast(unsigned short, __float2bfloat16(x));
}
__device__ __forceinline__ unsigned int pk2(float a, float b) {
    return bfbits(a) | (bfbits(b) << 16);
}
__device__ __forceinline__ unsigned short bf16s(float x) {
    return __builtin_bit_cast(unsigned short, __float2bfloat16(x));
}
__device__ __forceinline__ float unbf(unsigned short u) {
    return __builtin_bit_cast(float, ((unsigned int)u) << 16);
}
__device__ __forceinline__ float unlo(unsigned int u) {
    return __builtin_bit_cast(float, u << 16);
}
__device__ __forceinline__ float unhi(unsigned int u) {
    return __builtin_bit_cast(float, u & 0xffff0000u);
}

__device__ __forceinline__ void gload_lds16(const void* g, void* l) {
    __builtin_amdgcn_global_load_lds(
        (const __attribute__((address_space(1))) void*)g,
        (__attribute__((address_space(3))) void*)l, 16, 0, 0);
}

// ---------------- zero edge-count histogram ----------------
__global__ void k_initc(int* __restrict__ cnt) {
    int i = blockIdx.x * 256 + threadIdx.x;
    if (i < NN) cnt[i] = 0;
}

// ---------------- histogram of dst ----------------
__global__ void k_hist(const int* __restrict__ dst, int* __restrict__ cnt) {
    int e = blockIdx.x * 256 + threadIdx.x;
    if (e < NE) atomicAdd(&cnt[dst[e]], 1);
}

// ---------------- 3-kernel exclusive scan over cnt[NN] ----------------
__global__ void k_scanA(const int* __restrict__ cnt, int* __restrict__ bsum) {
    __shared__ int red[256];
    int i = blockIdx.x * 256 + threadIdx.x;
    red[threadIdx.x] = (i < NN) ? cnt[i] : 0;
    __syncthreads();
    for (int off = 128; off >= 1; off >>= 1) {
        if (threadIdx.x < off) red[threadIdx.x] += red[threadIdx.x + off];
        __syncthreads();
    }
    if (threadIdx.x == 0) bsum[blockIdx.x] = red[0];
}

__global__ void k_scanB(int* __restrict__ bsum) {
    __shared__ int sh[512];
    int t = threadIdx.x;
    int v = (t < SCAN_NB) ? bsum[t] : 0;
    sh[t] = v;
    __syncthreads();
    for (int off = 1; off < 512; off <<= 1) {
        int add = (t >= off) ? sh[t - off] : 0;
        __syncthreads();
        sh[t] += add;
        __syncthreads();
    }
    if (t < SCAN_NB) bsum[t] = sh[t] - v;   // exclusive
}

__global__ void k_scanC(const int* __restrict__ cnt, const int* __restrict__ bsum,
                        int* __restrict__ row_start, int* __restrict__ cursor) {
    __shared__ int sh[256];
    int i = blockIdx.x * 256 + threadIdx.x;
    int t = threadIdx.x;
    int v = (i < NN) ? cnt[i] : 0;
    sh[t] = v;
    __syncthreads();
    for (int off = 1; off < 256; off <<= 1) {
        int add = (t >= off) ? sh[t - off] : 0;
        __syncthreads();
        sh[t] += add;
        __syncthreads();
    }
    if (i < NN) {
        int ex = bsum[blockIdx.x] + sh[t] - v;
        row_start[i] = ex;
        cursor[i] = ex;
    }
}

// ---------------- bucket: permuted src/etype/dst grouped by dst ----------------
__global__ void k_bucket(const int* __restrict__ src, const int* __restrict__ dst,
                         const int* __restrict__ etype, int* __restrict__ cursor,
                         int* __restrict__ srcs, int* __restrict__ ets,
                         int* __restrict__ dsts) {
    int e = blockIdx.x * 256 + threadIdx.x;
    if (e < NE) {
        int d = dst[e];
        int p = atomicAdd(&cursor[d], 1);
        srcs[p] = src[e];
        ets[p]  = etype[e];
        dsts[p] = d;
    }
}

// ---------------- setup: all weight packing + small folds (one launch) ------
__global__ void k_setup(const float* __restrict__ mw1, const float* __restrict__ mb1,
                        const float* __restrict__ mw2, const float* __restrict__ mb2,
                        const float* __restrict__ aw1, const float* __restrict__ rel,
                        const float* __restrict__ fw1, const float* __restrict__ fw2,
                        unsigned short* __restrict__ mw1p,
                        unsigned short* __restrict__ mw2p,
                        unsigned short* __restrict__ awTp,
                        unsigned short* __restrict__ mwBp,
                        unsigned short* __restrict__ fw1p,
                        unsigned short* __restrict__ fw2p,
                        unsigned short* __restrict__ relcb,
                        float* __restrict__ zb) {
    int idx = blockIdx.x * 256 + threadIdx.x;   // 222336 total
    if (idx < 16384) {            // mw1 TOP: K=128, N=128
        int i = idx & 7, l = (idx >> 3) & 63, ks = (idx >> 9) & 3, nt = idx >> 11;
        int k = ks * 32 + (l >> 4) * 8 + i, n = nt * 16 + (l & 15);
        mw1p[idx] = bf16s(mw1[k * 128 + n]);
    } else if (idx < 32768) {     // mw2: K=128, N=128
        int j = idx - 16384;
        int i = j & 7, l = (j >> 3) & 63, ks = (j >> 9) & 3, nt = j >> 11;
        int k = ks * 32 + (l >> 4) * 8 + i, n = nt * 16 + (l & 15);
        mw2p[j] = bf16s(mw2[k * 128 + n]);
    } else if (idx < 49152) {     // aw1 TOP: K=128, N=128
        int j = idx - 32768;
        int i = j & 7, l = (j >> 3) & 63, ks = (j >> 9) & 3, nt = j >> 11;
        int k = ks * 32 + (l >> 4) * 8 + i, n = nt * 16 + (l & 15);
        awTp[j] = bf16s(aw1[k * 128 + n]);
    } else if (idx < 65536) {     // mwB = mw2 @ aw1_bot (direct dot)
        int j = idx - 49152;
        int i = j & 7, l = (j >> 3) & 63, ks = (j >> 9) & 3, nt = j >> 11;
        int k = ks * 32 + (l >> 4) * 8 + i, n = nt * 16 + (l & 15);
        float s = 0.0f;
        for (int j2 = 0; j2 < 128; ++j2)
            s = fmaf(mw2[k * 128 + j2], aw1[(128 + j2) * 128 + n], s);
        mwBp[j] = bf16s(s);
    } else if (idx < 131072) {    // fw1: K=128, N=512
        int j = idx - 65536;
        int i = j & 7, l = (j >> 3) & 63, ks = (j >> 9) & 3, nt = j >> 11;
        int k = ks * 32 + (l >> 4) * 8 + i, n = nt * 16 + (l & 15);
        fw1p[j] = bf16s(fw1[k * 512 + n]);
    } else if (idx < 196608) {    // fw2: K=512 (KS=16), N=128
        int j = idx - 131072;
        int i = j & 7, l = (j >> 3) & 63, ks = (j >> 9) & 15, nt = j >> 13;
        int k = ks * 32 + (l >> 4) * 8 + i, n = nt * 16 + (l & 15);
        fw2p[j] = bf16s(fw2[k * 128 + n]);
    } else if (idx < 222208) {    // relcb = bf16(rel @ mw1_bot + mb1)
        int j = idx - 196608;
        int r = j >> 7, n = j & 127;
        float s = mb1[n];
        for (int k = 0; k < 128; ++k)
            s = fmaf(rel[r * 128 + k], mw1[(128 + k) * 128 + n], s);
        relcb[j] = bf16s(s);
    } else if (idx < 222336) {    // zb = mb2 @ aw1_bot
        int n = idx - 222208;
        float s = 0.0f;
        for (int j2 = 0; j2 < 128; ++j2)
            s = fmaf(mb2[j2], aw1[(128 + j2) * 128 + n], s);
        zb[n] = s;
    }
}

// ---------------- prep+nfa fused: nfb = bf16(nf); nfa = nf @ aw1_top + ab1 ---
// block = 256 thr (4 waves 2x2), 64 rows.
__global__ __launch_bounds__(256) void k_prepnfa(
    const float* __restrict__ nf, const unsigned short* __restrict__ awTp,
    const float* __restrict__ ab1,
    unsigned short* __restrict__ nfb, unsigned short* __restrict__ nfa)
{
    __shared__ alignas(16) unsigned short XB[64 * 128]; // 16 KB
    const int t = threadIdx.x;
    const int w = t >> 6, l = t & 63;
    const int wm = w >> 1, wn = w & 1;
    const int lm = l & 15, lk = l >> 4;
    const int n0 = blockIdx.x * 64;

    // ---- read nf fp32, convert; write nfb global + XB LDS (swizzled) ----
    {
        const int row = t >> 2, seg = t & 3;      // 32 floats per thread
        long ng = n0 + row; if (ng >= NN) ng = NN - 1;
        const float* sp = nf + ng * DD + seg * 32;
        uint4 o[4];
        #pragma unroll
        for (int i = 0; i < 4; ++i) {
            float4 f0 = *reinterpret_cast<const float4*>(sp + i * 8);
            float4 f1 = *reinterpret_cast<const float4*>(sp + i * 8 + 4);
            o[i].x = pk2(f0.x, f0.y); o[i].y = pk2(f0.z, f0.w);
            o[i].z = pk2(f1.x, f1.y); o[i].w = pk2(f1.z, f1.w);
        }
        if (n0 + row < NN) {
            #pragma unroll
            for (int i = 0; i < 4; ++i)
                *reinterpret_cast<uint4*>(&nfb[(size_t)(n0 + row) * DD + (seg * 4 + i) * 8]) = o[i];
        }
        #pragma unroll
        for (int i = 0; i < 4; ++i) {
            int c = seg * 4 + i, slot = c ^ (row & 7);
            *reinterpret_cast<uint4*>(&XB[row * 128 + slot * 8]) = o[i];
        }
    }
    __syncthreads();

    f32x4 acc[2][4];
    #pragma unroll
    for (int mf = 0; mf < 2; ++mf)
        #pragma unroll
        for (int nfr = 0; nfr < 4; ++nfr) acc[mf][nfr] = (f32x4){0.f, 0.f, 0.f, 0.f};

    #pragma unroll
    for (int ks = 0; ks < 4; ++ks) {
        bf16x8 a[2];
        #pragma unroll
        for (int mf = 0; mf < 2; ++mf) {
            int m = wm * 32 + mf * 16 + lm;
            int slot = (ks * 4 + lk) ^ (m & 7);
            a[mf] = *reinterpret_cast<const bf16x8*>(&XB[m * 128 + slot * 8]);
        }
        #pragma unroll
        for (int nfr = 0; nfr < 4; ++nfr) {
            int nt = wn * 4 + nfr;
            bf16x8 b = *reinterpret_cast<const bf16x8*>(&awTp[((nt * 4 + ks) * 64 + l) * 8]);
            acc[0][nfr] = __builtin_amdgcn_mfma_f32_16x16x32_bf16(a[0], b, acc[0][nfr], 0, 0, 0);
            acc[1][nfr] = __builtin_amdgcn_mfma_f32_16x16x32_bf16(a[1], b, acc[1][nfr], 0, 0, 0);
        }
    }
    __syncthreads();

    #pragma unroll
    for (int nfr = 0; nfr < 4; ++nfr) {
        int n = wn * 64 + nfr * 16 + lm;
        float bv = ab1[n];
        #pragma unroll
        for (int mf = 0; mf < 2; ++mf)
            #pragma unroll
            for (int r = 0; r < 4; ++r) {
                int m = wm * 32 + mf * 16 + lk * 4 + r;
                XB[m * 128 + n] = bf16s(acc[mf][nfr][r] + bv);
            }
    }
    __syncthreads();

    #pragma unroll
    for (int j = 0; j < 4; ++j) {
        int q = j * 256 + t;
        int row = q >> 4, c16 = q & 15;
        if (n0 + row < NN)
            *reinterpret_cast<uint4*>(&nfa[(size_t)(n0 + row) * DD + c16 * 8]) =
                *reinterpret_cast<const uint4*>(&XB[row * 128 + c16 * 8]);
    }
}

// ---------------- edge kernel: GEMM1(hidden) + GEMM-z(logits) ---------------
__global__ __launch_bounds__(512) void k_edge(
    const unsigned short* __restrict__ nfb, const int* __restrict__ srcs,
    const int* __restrict__ dsts, const int* __restrict__ ets,
    const unsigned short* __restrict__ nfa, const unsigned short* __restrict__ relcb,
    const unsigned short* __restrict__ mw1p, const unsigned short* __restrict__ mwBp,
    const float* __restrict__ zb, const float* __restrict__ aw2,
    const float* __restrict__ ab2,
    unsigned short* __restrict__ hid_out, float* __restrict__ attn_raw)
{
    __shared__ alignas(16) unsigned short S[64 * 128];  // src rows, then nfa[dst]
    __shared__ alignas(16) unsigned short H[64 * 128];  // relc, then hidden
    __shared__ float RED[64][4];

    const int t = threadIdx.x;
    const int w = t >> 6, l = t & 63;
    const int wm = w >> 2, wn = w & 3;
    const int lm = l & 15, lk = l >> 4;
    const int lrow = l >> 4, lslot = l & 15;
    const int e0 = blockIdx.x * 64;

    #pragma unroll
    for (int it = 0; it < 2; ++it) {
        int rb = w * 8 + it * 4;
        int row = rb + lrow;
        int c = lslot ^ (row & 7);
        gload_lds16(nfb + (size_t)srcs[e0 + row] * DD + c * 8, &S[rb * 128]);
    }
    #pragma unroll
    for (int it = 0; it < 2; ++it) {
        int rb = w * 8 + it * 4;
        int row = rb + lrow;
        int c = lslot ^ (row & 7);
        gload_lds16(relcb + (size_t)ets[e0 + row] * DD + c * 8, &H[rb * 128]);
    }
    __syncthreads();

    // ---- GEMM1: hidden = relu(src @ mw1_top + relc), K=128; H slot RMW ----
    {
        f32x4 acc1[2][2];
        #pragma unroll
        for (int mf = 0; mf < 2; ++mf)
            #pragma unroll
            for (int nfr = 0; nfr < 2; ++nfr) acc1[mf][nfr] = (f32x4){0.f, 0.f, 0.f, 0.f};

        #pragma unroll
        for (int ks = 0; ks < 4; ++ks) {
            bf16x8 a[2];
            #pragma unroll
            for (int mf = 0; mf < 2; ++mf) {
                int m = wm * 32 + mf * 16 + lm;
                int slot = (ks * 4 + lk) ^ (m & 7);
                a[mf] = *reinterpret_cast<const bf16x8*>(&S[m * 128 + slot * 8]);
            }
            #pragma unroll
            for (int nfr = 0; nfr < 2; ++nfr) {
                int nt = wn * 2 + nfr;
                bf16x8 b = *reinterpret_cast<const bf16x8*>(&mw1p[((nt * 4 + ks) * 64 + l) * 8]);
                acc1[0][nfr] = __builtin_amdgcn_mfma_f32_16x16x32_bf16(a[0], b, acc1[0][nfr], 0, 0, 0);
                acc1[1][nfr] = __builtin_amdgcn_mfma_f32_16x16x32_bf16(a[1], b, acc1[1][nfr], 0, 0, 0);
            }
        }
        #pragma unroll
        for (int nfr = 0; nfr < 2; ++nfr) {
            int n = (wn * 2 + nfr) * 16 + lm;
            #pragma unroll
            for (int mf = 0; mf < 2; ++mf)
                #pragma unroll
                for (int r = 0; r < 4; ++r) {
                    int m = wm * 32 + mf * 16 + lk * 4 + r;
                    int sl = m * 128 + ((n >> 3) ^ (m & 7)) * 8 + (n & 7);
                    float v = acc1[mf][nfr][r] + unbf(H[sl]);
                    v = fmaxf(v, 0.0f);
                    H[sl] = bf16s(v);
                }
        }
    }
    __syncthreads(); // hidden complete; S (src) reads done

    // ---- copy hidden -> global (overlaps GEMM-z); stage S <- nfa[dsts] ----
    #pragma unroll
    for (int j = 0; j < 2; ++j) {
        int q = j * 512 + t;
        int row = q >> 4, c16 = q & 15;
        int slot = c16 ^ (row & 7);
        *reinterpret_cast<uint4*>(&hid_out[(size_t)(e0 + row) * DD + c16 * 8]) =
            *reinterpret_cast<const uint4*>(&H[row * 128 + slot * 8]);
    }
    #pragma unroll
    for (int it = 0; it < 2; ++it) {
        int rb = w * 8 + it * 4;
        int row = rb + lrow;
        int c = lslot ^ (row & 7);
        gload_lds16(nfa + (size_t)dsts[e0 + row] * DD + c * 8, &S[rb * 128]);
    }

    // ---- GEMM-z: zpre = hidden @ mwB, K=128, N=128 ----
    f32x4 acc[2][2];
    #pragma unroll
    for (int mf = 0; mf < 2; ++mf)
        #pragma unroll
        for (int nfr = 0; nfr < 2; ++nfr) acc[mf][nfr] = (f32x4){0.f, 0.f, 0.f, 0.f};

    #pragma unroll
    for (int ks = 0; ks < 4; ++ks) {
        bf16x8 a[2];
        #pragma unroll
        for (int mf = 0; mf < 2; ++mf) {
            int m = wm * 32 + mf * 16 + lm;
            int slot = (ks * 4 + lk) ^ (m & 7);
            a[mf] = *reinterpret_cast<const bf16x8*>(&H[m * 128 + slot * 8]);
        }
        #pragma unroll
        for (int nfr = 0; nfr < 2; ++nfr) {
            int nt = wn * 2 + nfr;
            bf16x8 b = *reinterpret_cast<const bf16x8*>(&mwBp[((nt * 4 + ks) * 64 + l) * 8]);
            acc[0][nfr] = __builtin_amdgcn_mfma_f32_16x16x32_bf16(a[0], b, acc[0][nfr], 0, 0, 0);
            acc[1][nfr] = __builtin_amdgcn_mfma_f32_16x16x32_bf16(a[1], b, acc[1][nfr], 0, 0, 0);
        }
    }
    __syncthreads(); // nfa staged into S; H reads done

    // ---- z epilogue (all 8 waves) ----
    {
        float zbv[2], aw2v[2];
        #pragma unroll
        for (int nfr = 0; nfr < 2; ++nfr) {
            int nc = (wn * 2 + nfr) * 16 + lm;
            zbv[nfr] = zb[nc];
            aw2v[nfr] = aw2[nc];
        }
        #pragma unroll
        for (int mf = 0; mf < 2; ++mf)
            #pragma unroll
            for (int r = 0; r < 4; ++r) {
                int m = wm * 32 + mf * 16 + lk * 4 + r;
                float s = 0.0f;
                #pragma unroll
                for (int nfr = 0; nfr < 2; ++nfr) {
                    int nc = (wn * 2 + nfr) * 16 + lm;
                    float v = acc[mf][nfr][r] + zbv[nfr]
                            + unbf(S[m * 128 + ((nc >> 3) ^ (m & 7)) * 8 + (nc & 7)]);
                    v = (v > 0.0f) ? v : 0.2f * v;
                    s = fmaf(v, aw2v[nfr], s);
                }
                s += __shfl_xor(s, 1, 64);
                s += __shfl_xor(s, 2, 64);
                s += __shfl_xor(s, 4, 64);
                s += __shfl_xor(s, 8, 64);
                if (lm == 0) RED[m][wn] = s;
            }
    }
    __syncthreads();

    if (t < 64) {
        attn_raw[e0 + t] = RED[t][0] + RED[t][1] + RED[t][2] + RED[t][3] + ab2[0];
    }
}

// ---------------- node kernel: AGGR + GEMM0(mw2) + LN1 + FFN + LN2 ----------
// block = 512 thr (8 waves); 64 nodes/block.
// Phase A: wave w softmax-aggregates nodes w*8..w*8+7 (sorted hid slab) -> HG.
__global__ __launch_bounds__(512) void k_node(
    const float* __restrict__ nf, const unsigned short* __restrict__ hid,
    const float* __restrict__ raw, const int* __restrict__ row_start,
    const int* __restrict__ cnt,
    const unsigned short* __restrict__ mw2p, const float* __restrict__ mb2,
    const float* __restrict__ g1, const float* __restrict__ b1,
    const unsigned short* __restrict__ fw1p, const float* __restrict__ fb1,
    const unsigned short* __restrict__ fw2p, const float* __restrict__ fb2,
    const float* __restrict__ g2, const float* __restrict__ b2,
    float* __restrict__ out)
{
    __shared__ alignas(16) unsigned short XB[64 * 128]; // 16 KB
    __shared__ alignas(16) unsigned short HB[64 * 256]; // 32 KB (first 16KB = HG)

    const int t = threadIdx.x;
    const int w = t >> 6, l = t & 63;
    const int wm = w >> 2, wn = w & 3;
    const int lm = l & 15, lk = l >> 4;
    const int row = t >> 3;      // 0..63
    const int q = t & 7;         // 16-col segment
    const long n0 = (long)blockIdx.x * 64;
    const long rg = n0 + row;
    const long rc = (rg < NN) ? rg : (NN - 1);

    unsigned short* HG = HB;

    // ---- phase A: per-wave softmax + aggregate of 8 nodes -> HG (swizzled) --
    #pragma unroll 1
    for (int i = 0; i < 8; ++i) {
        int nl = w * 8 + i;
        long ng = n0 + nl;
        float a0 = 0.0f, a1 = 0.0f;
        if (ng < NN) {
            int rs = row_start[ng], deg = cnt[ng];
            float m = -INFINITY;
            for (int j = l; j < deg; j += 64) m = fmaxf(m, raw[rs + j]);
            #pragma unroll
            for (int off = 32; off >= 1; off >>= 1) m = fmaxf(m, __shfl_xor(m, off, 64));
            float s = 0.0f;
            for (int j = l; j < deg; j += 64) s += expf(raw[rs + j] - m);
            #pragma unroll
            for (int off = 32; off >= 1; off >>= 1) s += __shfl_xor(s, off, 64);
            const float rinv = 1.0f / (s + 1e-8f);
            for (int j = 0; j < deg; ++j) {
                float wj = expf(raw[rs + j] - m) * rinv;  // uniform across lanes
                unsigned int v = *reinterpret_cast<const unsigned int*>(
                    &hid[(size_t)(rs + j) * DD + l * 2]);
                a0 = fmaf(wj, unlo(v), a0);
                a1 = fmaf(wj, unhi(v), a1);
            }
        }
        int c = l >> 2;                       // chunk of columns l*2, l*2+1
        int slot = c ^ (nl & 7);
        *reinterpret_cast<unsigned int*>(&HG[nl * 128 + slot * 8 + ((l * 2) & 7)]) = pk2(a0, a1);
    }
    __syncthreads();

    // ---- GEMM0: aggr = haggr @ mw2 + mb2 -> XB (bf16, swizzled) ----
    {
        f32x4 acc0[2][2];
        #pragma unroll
        for (int mf = 0; mf < 2; ++mf)
            #pragma unroll
            for (int nfr = 0; nfr < 2; ++nfr) acc0[mf][nfr] = (f32x4){0.f, 0.f, 0.f, 0.f};

        #pragma unroll
        for (int ks = 0; ks < 4; ++ks) {
            bf16x8 a[2];
            #pragma unroll
            for (int mf = 0; mf < 2; ++mf) {
                int m = wm * 32 + mf * 16 + lm;
                int slot = (ks * 4 + lk) ^ (m & 7);
                a[mf] = *reinterpret_cast<const bf16x8*>(&HG[m * 128 + slot * 8]);
            }
            #pragma unroll
            for (int nfr = 0; nfr < 2; ++nfr) {
                int nt = wn * 2 + nfr;
                bf16x8 b = *reinterpret_cast<const bf16x8*>(&mw2p[((nt * 4 + ks) * 64 + l) * 8]);
                acc0[0][nfr] = __builtin_amdgcn_mfma_f32_16x16x32_bf16(a[0], b, acc0[0][nfr], 0, 0, 0);
                acc0[1][nfr] = __builtin_amdgcn_mfma_f32_16x16x32_bf16(a[1], b, acc0[1][nfr], 0, 0, 0);
            }
        }
        #pragma unroll
        for (int nfr = 0; nfr < 2; ++nfr) {
            int n = (wn * 2 + nfr) * 16 + lm;
            float bv = mb2[n];
            #pragma unroll
            for (int mf = 0; mf < 2; ++mf)
                #pragma unroll
                for (int r = 0; r < 4; ++r) {
                    int m = wm * 32 + mf * 16 + lk * 4 + r;
                    XB[m * 128 + ((n >> 3) ^ (m & 7)) * 8 + (n & 7)] = bf16s(acc0[mf][nfr][r] + bv);
                }
        }
    }
    __syncthreads(); // XB = aggr (bf16); HG reads done

    // ---- LN1: x = nf + aggr ----
    float xr[16];
    float s = 0.0f, ss = 0.0f;
    {
        const float* xp = nf + rc * DD + q * 16;
        #pragma unroll
        for (int i = 0; i < 2; ++i) {
            int c = q * 2 + i, slot = c ^ (row & 7);
            uint4 v = *reinterpret_cast<const uint4*>(&XB[row * 128 + slot * 8]);
            float f[8];
            f[0] = unlo(v.x); f[1] = unhi(v.x); f[2] = unlo(v.y); f[3] = unhi(v.y);
            f[4] = unlo(v.z); f[5] = unhi(v.z); f[6] = unlo(v.w); f[7] = unhi(v.w);
            float4 a = *reinterpret_cast<const float4*>(xp + i * 8);
            float4 b = *reinterpret_cast<const float4*>(xp + i * 8 + 4);
            float vv[8] = {a.x + f[0], a.y + f[1], a.z + f[2], a.w + f[3],
                           b.x + f[4], b.y + f[5], b.z + f[6], b.w + f[7]};
            #pragma unroll
            for (int j = 0; j < 8; ++j) {
                xr[i * 8 + j] = vv[j];
                s += vv[j];
                ss = fmaf(vv[j], vv[j], ss);
            }
        }
    }
    s  += __shfl_xor(s, 1, 64);  s  += __shfl_xor(s, 2, 64);  s  += __shfl_xor(s, 4, 64);
    ss += __shfl_xor(ss, 1, 64); ss += __shfl_xor(ss, 2, 64); ss += __shfl_xor(ss, 4, 64);
    {
        float mu = s * (1.0f / DD);
        float var = ss * (1.0f / DD) - mu * mu;
        float rstd = rsqrtf(var + 1e-5f);
        #pragma unroll
        for (int i = 0; i < 4; ++i) {
            float4 gv = *reinterpret_cast<const float4*>(g1 + q * 16 + i * 4);
            float4 bv = *reinterpret_cast<const float4*>(b1 + q * 16 + i * 4);
            xr[i * 4 + 0] = (xr[i * 4 + 0] - mu) * rstd * gv.x + bv.x;
            xr[i * 4 + 1] = (xr[i * 4 + 1] - mu) * rstd * gv.y + bv.y;
            xr[i * 4 + 2] = (xr[i * 4 + 2] - mu) * rstd * gv.z + bv.z;
            xr[i * 4 + 3] = (xr[i * 4 + 3] - mu) * rstd * gv.w + bv.w;
        }
        #pragma unroll
        for (int i = 0; i < 2; ++i) {
            int c = q * 2 + i, slot = c ^ (row & 7);
            uint4 v;
            v.x = pk2(xr[i * 8 + 0], xr[i * 8 + 1]);
            v.y = pk2(xr[i * 8 + 2], xr[i * 8 + 3]);
            v.z = pk2(xr[i * 8 + 4], xr[i * 8 + 5]);
            v.w = pk2(xr[i * 8 + 6], xr[i * 8 + 7]);
            *reinterpret_cast<uint4*>(&XB[row * 128 + slot * 8]) = v;
        }
    }
    __syncthreads();

    // ---- FFN: two 256-col halves ----
    f32x4 acc2[2][2];
    #pragma unroll
    for (int mf = 0; mf < 2; ++mf)
        #pragma unroll
        for (int nfr = 0; nfr < 2; ++nfr) acc2[mf][nfr] = (f32x4){0.f, 0.f, 0.f, 0.f};

    #pragma unroll
    for (int half = 0; half < 2; ++half) {
        f32x4 acc[2][4];
        #pragma unroll
        for (int mf = 0; mf < 2; ++mf)
            #pragma unroll
            for (int nfr = 0; nfr < 4; ++nfr) acc[mf][nfr] = (f32x4){0.f, 0.f, 0.f, 0.f};

        #pragma unroll
        for (int ks = 0; ks < 4; ++ks) {
            bf16x8 a[2];
            #pragma unroll
            for (int mf = 0; mf < 2; ++mf) {
                int m = wm * 32 + mf * 16 + lm;
                int slot = (ks * 4 + lk) ^ (m & 7);
                a[mf] = *reinterpret_cast<const bf16x8*>(&XB[m * 128 + slot * 8]);
            }
            #pragma unroll
            for (int nfr = 0; nfr < 4; ++nfr) {
                int nt = half * 16 + wn * 4 + nfr;
                bf16x8 b = *reinterpret_cast<const bf16x8*>(&fw1p[((nt * 4 + ks) * 64 + l) * 8]);
                acc[0][nfr] = __builtin_amdgcn_mfma_f32_16x16x32_bf16(a[0], b, acc[0][nfr], 0, 0, 0);
                acc[1][nfr] = __builtin_amdgcn_mfma_f32_16x16x32_bf16(a[1], b, acc[1][nfr], 0, 0, 0);
            }
        }
        #pragma unroll
        for (int nfr = 0; nfr < 4; ++nfr) {
            int nl = (wn * 4 + nfr) * 16 + lm;
            float bv = fb1[half * 256 + nl];
            #pragma unroll
            for (int mf = 0; mf < 2; ++mf)
                #pragma unroll
                for (int r = 0; r < 4; ++r) {
                    int m = wm * 32 + mf * 16 + lk * 4 + r;
                    float h = acc[mf][nfr][r] + bv;
                    float e = __expf(h * -1.702f);
                    float gvv = h * __builtin_amdgcn_rcpf(1.0f + e);
                    HB[m * 256 + (((nl >> 3) ^ (m & 7)) * 8) + (nl & 7)] = bf16s(gvv);
                }
        }
        __syncthreads();

        #pragma unroll
        for (int ks = 0; ks < 8; ++ks) {
            bf16x8 a[2];
            #pragma unroll
            for (int mf = 0; mf < 2; ++mf) {
                int m = wm * 32 + mf * 16 + lm;
                int slot = (ks * 4 + lk) ^ (m & 7);
                a[mf] = *reinterpret_cast<const bf16x8*>(&HB[m * 256 + slot * 8]);
            }
            #pragma unroll
            for (int nfr = 0; nfr < 2; ++nfr) {
                int nt = wn * 2 + nfr;
                int kg = half * 8 + ks;
                bf16x8 b = *reinterpret_cast<const bf16x8*>(&fw2p[((nt * 16 + kg) * 64 + l) * 8]);
                acc2[0][nfr] = __builtin_amdgcn_mfma_f32_16x16x32_bf16(a[0], b, acc2[0][nfr], 0, 0, 0);
                acc2[1][nfr] = __builtin_amdgcn_mfma_f32_16x16x32_bf16(a[1], b, acc2[1][nfr], 0, 0, 0);
            }
        }
        __syncthreads();
    }

    // ---- ffn -> XB (bf16) ----
    #pragma unroll
    for (int nfr = 0; nfr < 2; ++nfr) {
        int n = (wn * 2 + nfr) * 16 + lm;
        float bv = fb2[n];
        #pragma unroll
        for (int mf = 0; mf < 2; ++mf)
            #pragma unroll
            for (int r = 0; r < 4; ++r) {
                int m = wm * 32 + mf * 16 + lk * 4 + r;
                XB[m * 128 + (((n >> 3) ^ (m & 7)) * 8) + (n & 7)] = bf16s(acc2[mf][nfr][r] + bv);
            }
    }
    __syncthreads();

    // ---- residual + LN2 ----
    float s2 = 0.0f, ss2 = 0.0f;
    #pragma unroll
    for (int i = 0; i < 2; ++i) {
        int c = q * 2 + i, slot = c ^ (row & 7);
        uint4 v = *reinterpret_cast<const uint4*>(&XB[row * 128 + slot * 8]);
        float f[8];
        f[0] = unlo(v.x); f[1] = unhi(v.x); f[2] = unlo(v.y); f[3] = unhi(v.y);
        f[4] = unlo(v.z); f[5] = unhi(v.z); f[6] = unlo(v.w); f[7] = unhi(v.w);
        #pragma unroll
        for (int j = 0; j < 8; ++j) {
            float vv = xr[i * 8 + j] + f[j];
            xr[i * 8 + j] = vv;
            s2 += vv;
            ss2 = fmaf(vv, vv, ss2);
        }
    }
    s2  += __shfl_xor(s2, 1, 64);  s2  += __shfl_xor(s2, 2, 64);  s2  += __shfl_xor(s2, 4, 64);
    ss2 += __shfl_xor(ss2, 1, 64); ss2 += __shfl_xor(ss2, 2, 64); ss2 += __shfl_xor(ss2, 4, 64);
    {
        float mu = s2 * (1.0f / DD);
        float var = ss2 * (1.0f / DD) - mu * mu;
        float rstd = rsqrtf(var + 1e-5f);
        if (rg < NN) {
            float* op = out + rg * DD + q * 16;
            #pragma unroll
            for (int i = 0; i < 4; ++i) {
                float4 gv = *reinterpret_cast<const float4*>(g2 + q * 16 + i * 4);
                float4 bv = *reinterpret_cast<const float4*>(b2 + q * 16 + i * 4);
                float4 o;
                o.x = (xr[i * 4 + 0] - mu) * rstd * gv.x + bv.x;
                o.y = (xr[i * 4 + 1] - mu) * rstd * gv.y + bv.y;
                o.z = (xr[i * 4 + 2] - mu) * rstd * gv.z + bv.z;
                o.w = (xr[i * 4 + 3] - mu) * rstd * gv.w + bv.w;
                *reinterpret_cast<float4*>(op + i * 4) = o;
            }
        }
    }
}

extern "C" void kernel_launch(void* const* d_in, const int* in_sizes, int n_in,
                              void* d_out, int out_size, void* d_ws, size_t ws_size,
                              hipStream_t stream)
{
    const float* nf  = (const float*)d_in[0];
    const int*   ei  = (const int*)d_in[1];
    const int*   et  = (const int*)d_in[2];
    const float* rel = (const float*)d_in[3];
    const float* mw1 = (const float*)d_in[4];
    const float* mb1 = (const float*)d_in[5];
    const float* mw2 = (const float*)d_in[6];
    const float* mb2 = (const float*)d_in[7];
    const float* aw1 = (const float*)d_in[8];
    const float* ab1 = (const float*)d_in[9];
    const float* aw2 = (const float*)d_in[10];
    const float* ab2 = (const float*)d_in[11];
    const float* g1  = (const float*)d_in[12];
    const float* b1  = (const float*)d_in[13];
    const float* fw1 = (const float*)d_in[14];
    const float* fb1 = (const float*)d_in[15];
    const float* fw2 = (const float*)d_in[16];
    const float* fb2 = (const float*)d_in[17];
    const float* g2  = (const float*)d_in[18];
    const float* b2  = (const float*)d_in[19];
    float* out = (float*)d_out;

    char* ws = (char*)d_ws;
    size_t off = 0;
    auto alloc = [&](size_t bytes) -> char* {
        char* p = ws + off;
        off += (bytes + 255) & ~(size_t)255;
        return p;
    };
    unsigned short* hid = (unsigned short*)alloc((size_t)NE * DD * 2);
    float* attn_raw = (float*)alloc((size_t)NE * 4);
    unsigned short* nfa = (unsigned short*)alloc((size_t)NN * DD * 2);
    unsigned short* nfb = (unsigned short*)alloc((size_t)NN * DD * 2);
    unsigned short* relcb = (unsigned short*)alloc((size_t)RR * DD * 2);
    float* zb  = (float*)alloc((size_t)128 * 4);
    int* cnt       = (int*)alloc((size_t)NN * 4);
    int* row_start = (int*)alloc((size_t)NN * 4);
    int* cursor    = (int*)alloc((size_t)NN * 4);
    int* srcs      = (int*)alloc((size_t)NE * 4);
    int* ets       = (int*)alloc((size_t)NE * 4);
    int* dsts      = (int*)alloc((size_t)NE * 4);
    int* bsum      = (int*)alloc((size_t)SCAN_NB * 4);
    unsigned short* mw1p = (unsigned short*)alloc(16384 * 2);
    unsigned short* mw2p = (unsigned short*)alloc(16384 * 2);
    unsigned short* awTp = (unsigned short*)alloc(16384 * 2);
    unsigned short* mwBp = (unsigned short*)alloc(16384 * 2);
    unsigned short* fw1p = (unsigned short*)alloc(65536 * 2);
    unsigned short* fw2p = (unsigned short*)alloc(65536 * 2);

    const int* srcp = ei;
    const int* dstp = ei + NE;

    hipLaunchKernelGGL(k_initc, dim3(SCAN_NB), dim3(256), 0, stream, cnt);
    hipLaunchKernelGGL(k_hist, dim3((NE + 255) / 256), dim3(256), 0, stream, dstp, cnt);
    hipLaunchKernelGGL(k_scanA, dim3(SCAN_NB), dim3(256), 0, stream, cnt, bsum);
    hipLaunchKernelGGL(k_scanB, dim3(1), dim3(512), 0, stream, bsum);
    hipLaunchKernelGGL(k_scanC, dim3(SCAN_NB), dim3(256), 0, stream, cnt, bsum, row_start, cursor);
    hipLaunchKernelGGL(k_bucket, dim3((NE + 255) / 256), dim3(256), 0, stream,
                       srcp, dstp, et, cursor, srcs, ets, dsts);
    hipLaunchKernelGGL(k_setup, dim3(869), dim3(256), 0, stream,
                       mw1, mb1, mw2, mb2, aw1, rel, fw1, fw2,
                       mw1p, mw2p, awTp, mwBp, fw1p, fw2p, relcb, zb);
    hipLaunchKernelGGL(k_prepnfa, dim3((NN + 63) / 64), dim3(256), 0, stream,
                       nf, awTp, ab1, nfb, nfa);
    hipLaunchKernelGGL(k_edge, dim3(NE / 64), dim3(512), 0, stream,
                       nfb, srcs, dsts, ets, nfa, relcb,
                       mw1p, mwBp, zb, aw2, ab2,
                       hid, attn_raw);
    hipLaunchKernelGGL(k_node, dim3((NN + 63) / 64), dim3(512), 0, stream,
                       nf, hid, attn_raw, row_start, cnt,
                       mw2p, mb2, g1, b1, fw1p, fb1, fw2p, fb2, g2, b2, out);
}

// Round 11
// 437.600 us; speedup vs baseline: 1.3481x; 1.3481x over previous
//
#include <hip/hip_runtime.h>
#include <hip/hip_bf16.h>

#define NN 100000
#define NE 600000
#define DD 128
#define RR 200
#define SCAN_NB ((NN + 255) / 256)   // 391

typedef __attribute__((ext_vector_type(8))) short bf16x8;
typedef __attribute__((ext_vector_type(4))) float f32x4;

__device__ __forceinline__ unsigned int bfbits(float x) {
    return (unsigned int)__builtin_bit_cast(unsigned short, __float2bfloat16(x));
}
__device__ __forceinline__ unsigned int pk2(float a, float b) {
    return bfbits(a) | (bfbits(b) << 16);
}
__device__ __forceinline__ unsigned short bf16s(float x) {
    return __builtin_bit_cast(unsigned short, __float2bfloat16(x));
}
__device__ __forceinline__ float unbf(unsigned short u) {
    return __builtin_bit_cast(float, ((unsigned int)u) << 16);
}
__device__ __forceinline__ float unlo(unsigned int u) {
    return __builtin_bit_cast(float, u << 16);
}
__device__ __forceinline__ float unhi(unsigned int u) {
    return __builtin_bit_cast(float, u & 0xffff0000u);
}

__device__ __forceinline__ void gload_lds16(const void* g, void* l) {
    __builtin_amdgcn_global_load_lds(
        (const __attribute__((address_space(1))) void*)g,
        (__attribute__((address_space(3))) void*)l, 16, 0, 0);
}

// ---------------- zero edge-count histogram ----------------
__global__ void k_initc(int* __restrict__ cnt) {
    int i = blockIdx.x * 256 + threadIdx.x;
    if (i < NN) cnt[i] = 0;
}

// ---------------- histogram of dst ----------------
__global__ void k_hist(const int* __restrict__ dst, int* __restrict__ cnt) {
    int e = blockIdx.x * 256 + threadIdx.x;
    if (e < NE) atomicAdd(&cnt[dst[e]], 1);
}

// ---------------- 3-kernel exclusive scan over cnt[NN] ----------------
__global__ void k_scanA(const int* __restrict__ cnt, int* __restrict__ bsum) {
    __shared__ int red[256];
    int i = blockIdx.x * 256 + threadIdx.x;
    red[threadIdx.x] = (i < NN) ? cnt[i] : 0;
    __syncthreads();
    for (int off = 128; off >= 1; off >>= 1) {
        if (threadIdx.x < off) red[threadIdx.x] += red[threadIdx.x + off];
        __syncthreads();
    }
    if (threadIdx.x == 0) bsum[blockIdx.x] = red[0];
}

__global__ void k_scanB(int* __restrict__ bsum) {
    __shared__ int sh[512];
    int t = threadIdx.x;
    int v = (t < SCAN_NB) ? bsum[t] : 0;
    sh[t] = v;
    __syncthreads();
    for (int off = 1; off < 512; off <<= 1) {
        int add = (t >= off) ? sh[t - off] : 0;
        __syncthreads();
        sh[t] += add;
        __syncthreads();
    }
    if (t < SCAN_NB) bsum[t] = sh[t] - v;   // exclusive
}

__global__ void k_scanC(const int* __restrict__ cnt, const int* __restrict__ bsum,
                        int* __restrict__ row_start, int* __restrict__ cursor) {
    __shared__ int sh[256];
    int i = blockIdx.x * 256 + threadIdx.x;
    int t = threadIdx.x;
    int v = (i < NN) ? cnt[i] : 0;
    sh[t] = v;
    __syncthreads();
    for (int off = 1; off < 256; off <<= 1) {
        int add = (t >= off) ? sh[t - off] : 0;
        __syncthreads();
        sh[t] += add;
        __syncthreads();
    }
    if (i < NN) {
        int ex = bsum[blockIdx.x] + sh[t] - v;
        row_start[i] = ex;
        cursor[i] = ex;
    }
}

// ---------------- bucket: permuted src/etype/dst grouped by dst ----------------
__global__ void k_bucket(const int* __restrict__ src, const int* __restrict__ dst,
                         const int* __restrict__ etype, int* __restrict__ cursor,
                         int* __restrict__ srcs, int* __restrict__ ets,
                         int* __restrict__ dsts) {
    int e = blockIdx.x * 256 + threadIdx.x;
    if (e < NE) {
        int d = dst[e];
        int p = atomicAdd(&cursor[d], 1);
        srcs[p] = src[e];
        ets[p]  = etype[e];
        dsts[p] = d;
    }
}

// ---------------- setup: all weight packing + small folds (one launch) ------
__global__ void k_setup(const float* __restrict__ mw1, const float* __restrict__ mb1,
                        const float* __restrict__ mw2, const float* __restrict__ mb2,
                        const float* __restrict__ aw1, const float* __restrict__ rel,
                        const float* __restrict__ fw1, const float* __restrict__ fw2,
                        unsigned short* __restrict__ mw1p,
                        unsigned short* __restrict__ mw2p,
                        unsigned short* __restrict__ awTp,
                        unsigned short* __restrict__ mwBp,
                        unsigned short* __restrict__ fw1p,
                        unsigned short* __restrict__ fw2p,
                        unsigned short* __restrict__ relcb,
                        float* __restrict__ zb) {
    int idx = blockIdx.x * 256 + threadIdx.x;   // 222336 total
    if (idx < 16384) {            // mw1 TOP: K=128, N=128
        int i = idx & 7, l = (idx >> 3) & 63, ks = (idx >> 9) & 3, nt = idx >> 11;
        int k = ks * 32 + (l >> 4) * 8 + i, n = nt * 16 + (l & 15);
        mw1p[idx] = bf16s(mw1[k * 128 + n]);
    } else if (idx < 32768) {     // mw2: K=128, N=128
        int j = idx - 16384;
        int i = j & 7, l = (j >> 3) & 63, ks = (j >> 9) & 3, nt = j >> 11;
        int k = ks * 32 + (l >> 4) * 8 + i, n = nt * 16 + (l & 15);
        mw2p[j] = bf16s(mw2[k * 128 + n]);
    } else if (idx < 49152) {     // aw1 TOP: K=128, N=128
        int j = idx - 32768;
        int i = j & 7, l = (j >> 3) & 63, ks = (j >> 9) & 3, nt = j >> 11;
        int k = ks * 32 + (l >> 4) * 8 + i, n = nt * 16 + (l & 15);
        awTp[j] = bf16s(aw1[k * 128 + n]);
    } else if (idx < 65536) {     // mwB = mw2 @ aw1_bot (direct dot)
        int j = idx - 49152;
        int i = j & 7, l = (j >> 3) & 63, ks = (j >> 9) & 3, nt = j >> 11;
        int k = ks * 32 + (l >> 4) * 8 + i, n = nt * 16 + (l & 15);
        float s = 0.0f;
        for (int j2 = 0; j2 < 128; ++j2)
            s = fmaf(mw2[k * 128 + j2], aw1[(128 + j2) * 128 + n], s);
        mwBp[j] = bf16s(s);
    } else if (idx < 131072) {    // fw1: K=128, N=512
        int j = idx - 65536;
        int i = j & 7, l = (j >> 3) & 63, ks = (j >> 9) & 3, nt = j >> 11;
        int k = ks * 32 + (l >> 4) * 8 + i, n = nt * 16 + (l & 15);
        fw1p[j] = bf16s(fw1[k * 512 + n]);
    } else if (idx < 196608) {    // fw2: K=512 (KS=16), N=128
        int j = idx - 131072;
        int i = j & 7, l = (j >> 3) & 63, ks = (j >> 9) & 15, nt = j >> 13;
        int k = ks * 32 + (l >> 4) * 8 + i, n = nt * 16 + (l & 15);
        fw2p[j] = bf16s(fw2[k * 128 + n]);
    } else if (idx < 222208) {    // relcb = bf16(rel @ mw1_bot + mb1)
        int j = idx - 196608;
        int r = j >> 7, n = j & 127;
        float s = mb1[n];
        for (int k = 0; k < 128; ++k)
            s = fmaf(rel[r * 128 + k], mw1[(128 + k) * 128 + n], s);
        relcb[j] = bf16s(s);
    } else if (idx < 222336) {    // zb = mb2 @ aw1_bot
        int n = idx - 222208;
        float s = 0.0f;
        for (int j2 = 0; j2 < 128; ++j2)
            s = fmaf(mb2[j2], aw1[(128 + j2) * 128 + n], s);
        zb[n] = s;
    }
}

// ---------------- prep+nfa fused: nfb = bf16(nf); nfa = nf @ aw1_top + ab1 ---
// block = 256 thr (4 waves 2x2), 64 rows.
__global__ __launch_bounds__(256) void k_prepnfa(
    const float* __restrict__ nf, const unsigned short* __restrict__ awTp,
    const float* __restrict__ ab1,
    unsigned short* __restrict__ nfb, unsigned short* __restrict__ nfa)
{
    __shared__ alignas(16) unsigned short XB[64 * 128]; // 16 KB
    const int t = threadIdx.x;
    const int w = t >> 6, l = t & 63;
    const int wm = w >> 1, wn = w & 1;
    const int lm = l & 15, lk = l >> 4;
    const int n0 = blockIdx.x * 64;

    // ---- read nf fp32, convert; write nfb global + XB LDS (swizzled) ----
    {
        const int row = t >> 2, seg = t & 3;      // 32 floats per thread
        long ng = n0 + row; if (ng >= NN) ng = NN - 1;
        const float* sp = nf + ng * DD + seg * 32;
        uint4 o[4];
        #pragma unroll
        for (int i = 0; i < 4; ++i) {
            float4 f0 = *reinterpret_cast<const float4*>(sp + i * 8);
            float4 f1 = *reinterpret_cast<const float4*>(sp + i * 8 + 4);
            o[i].x = pk2(f0.x, f0.y); o[i].y = pk2(f0.z, f0.w);
            o[i].z = pk2(f1.x, f1.y); o[i].w = pk2(f1.z, f1.w);
        }
        if (n0 + row < NN) {
            #pragma unroll
            for (int i = 0; i < 4; ++i)
                *reinterpret_cast<uint4*>(&nfb[(size_t)(n0 + row) * DD + (seg * 4 + i) * 8]) = o[i];
        }
        #pragma unroll
        for (int i = 0; i < 4; ++i) {
            int c = seg * 4 + i, slot = c ^ (row & 7);
            *reinterpret_cast<uint4*>(&XB[row * 128 + slot * 8]) = o[i];
        }
    }
    __syncthreads();

    f32x4 acc[2][4];
    #pragma unroll
    for (int mf = 0; mf < 2; ++mf)
        #pragma unroll
        for (int nfr = 0; nfr < 4; ++nfr) acc[mf][nfr] = (f32x4){0.f, 0.f, 0.f, 0.f};

    #pragma unroll
    for (int ks = 0; ks < 4; ++ks) {
        bf16x8 a[2];
        #pragma unroll
        for (int mf = 0; mf < 2; ++mf) {
            int m = wm * 32 + mf * 16 + lm;
            int slot = (ks * 4 + lk) ^ (m & 7);
            a[mf] = *reinterpret_cast<const bf16x8*>(&XB[m * 128 + slot * 8]);
        }
        #pragma unroll
        for (int nfr = 0; nfr < 4; ++nfr) {
            int nt = wn * 4 + nfr;
            bf16x8 b = *reinterpret_cast<const bf16x8*>(&awTp[((nt * 4 + ks) * 64 + l) * 8]);
            acc[0][nfr] = __builtin_amdgcn_mfma_f32_16x16x32_bf16(a[0], b, acc[0][nfr], 0, 0, 0);
            acc[1][nfr] = __builtin_amdgcn_mfma_f32_16x16x32_bf16(a[1], b, acc[1][nfr], 0, 0, 0);
        }
    }
    __syncthreads();

    #pragma unroll
    for (int nfr = 0; nfr < 4; ++nfr) {
        int n = wn * 64 + nfr * 16 + lm;
        float bv = ab1[n];
        #pragma unroll
        for (int mf = 0; mf < 2; ++mf)
            #pragma unroll
            for (int r = 0; r < 4; ++r) {
                int m = wm * 32 + mf * 16 + lk * 4 + r;
                XB[m * 128 + n] = bf16s(acc[mf][nfr][r] + bv);
            }
    }
    __syncthreads();

    #pragma unroll
    for (int j = 0; j < 4; ++j) {
        int q = j * 256 + t;
        int row = q >> 4, c16 = q & 15;
        if (n0 + row < NN)
            *reinterpret_cast<uint4*>(&nfa[(size_t)(n0 + row) * DD + c16 * 8]) =
                *reinterpret_cast<const uint4*>(&XB[row * 128 + c16 * 8]);
    }
}

// ---------------- edge kernel: GEMM1(hidden) + GEMM-z(logits) ---------------
__global__ __launch_bounds__(512) void k_edge(
    const unsigned short* __restrict__ nfb, const int* __restrict__ srcs,
    const int* __restrict__ dsts, const int* __restrict__ ets,
    const unsigned short* __restrict__ nfa, const unsigned short* __restrict__ relcb,
    const unsigned short* __restrict__ mw1p, const unsigned short* __restrict__ mwBp,
    const float* __restrict__ zb, const float* __restrict__ aw2,
    const float* __restrict__ ab2,
    unsigned short* __restrict__ hid_out, float* __restrict__ attn_raw)
{
    __shared__ alignas(16) unsigned short S[64 * 128];  // src rows, then nfa[dst]
    __shared__ alignas(16) unsigned short H[64 * 128];  // relc, then hidden
    __shared__ float RED[64][4];

    const int t = threadIdx.x;
    const int w = t >> 6, l = t & 63;
    const int wm = w >> 2, wn = w & 3;
    const int lm = l & 15, lk = l >> 4;
    const int lrow = l >> 4, lslot = l & 15;
    const int e0 = blockIdx.x * 64;

    #pragma unroll
    for (int it = 0; it < 2; ++it) {
        int rb = w * 8 + it * 4;
        int row = rb + lrow;
        int c = lslot ^ (row & 7);
        gload_lds16(nfb + (size_t)srcs[e0 + row] * DD + c * 8, &S[rb * 128]);
    }
    #pragma unroll
    for (int it = 0; it < 2; ++it) {
        int rb = w * 8 + it * 4;
        int row = rb + lrow;
        int c = lslot ^ (row & 7);
        gload_lds16(relcb + (size_t)ets[e0 + row] * DD + c * 8, &H[rb * 128]);
    }
    __syncthreads();

    // ---- GEMM1: hidden = relu(src @ mw1_top + relc), K=128; H slot RMW ----
    {
        f32x4 acc1[2][2];
        #pragma unroll
        for (int mf = 0; mf < 2; ++mf)
            #pragma unroll
            for (int nfr = 0; nfr < 2; ++nfr) acc1[mf][nfr] = (f32x4){0.f, 0.f, 0.f, 0.f};

        #pragma unroll
        for (int ks = 0; ks < 4; ++ks) {
            bf16x8 a[2];
            #pragma unroll
            for (int mf = 0; mf < 2; ++mf) {
                int m = wm * 32 + mf * 16 + lm;
                int slot = (ks * 4 + lk) ^ (m & 7);
                a[mf] = *reinterpret_cast<const bf16x8*>(&S[m * 128 + slot * 8]);
            }
            #pragma unroll
            for (int nfr = 0; nfr < 2; ++nfr) {
                int nt = wn * 2 + nfr;
                bf16x8 b = *reinterpret_cast<const bf16x8*>(&mw1p[((nt * 4 + ks) * 64 + l) * 8]);
                acc1[0][nfr] = __builtin_amdgcn_mfma_f32_16x16x32_bf16(a[0], b, acc1[0][nfr], 0, 0, 0);
                acc1[1][nfr] = __builtin_amdgcn_mfma_f32_16x16x32_bf16(a[1], b, acc1[1][nfr], 0, 0, 0);
            }
        }
        #pragma unroll
        for (int nfr = 0; nfr < 2; ++nfr) {
            int n = (wn * 2 + nfr) * 16 + lm;
            #pragma unroll
            for (int mf = 0; mf < 2; ++mf)
                #pragma unroll
                for (int r = 0; r < 4; ++r) {
                    int m = wm * 32 + mf * 16 + lk * 4 + r;
                    int sl = m * 128 + ((n >> 3) ^ (m & 7)) * 8 + (n & 7);
                    float v = acc1[mf][nfr][r] + unbf(H[sl]);
                    v = fmaxf(v, 0.0f);
                    H[sl] = bf16s(v);
                }
        }
    }
    __syncthreads(); // hidden complete; S (src) reads done

    // ---- copy hidden -> global (overlaps GEMM-z); stage S <- nfa[dsts] ----
    #pragma unroll
    for (int j = 0; j < 2; ++j) {
        int q = j * 512 + t;
        int row = q >> 4, c16 = q & 15;
        int slot = c16 ^ (row & 7);
        *reinterpret_cast<uint4*>(&hid_out[(size_t)(e0 + row) * DD + c16 * 8]) =
            *reinterpret_cast<const uint4*>(&H[row * 128 + slot * 8]);
    }
    #pragma unroll
    for (int it = 0; it < 2; ++it) {
        int rb = w * 8 + it * 4;
        int row = rb + lrow;
        int c = lslot ^ (row & 7);
        gload_lds16(nfa + (size_t)dsts[e0 + row] * DD + c * 8, &S[rb * 128]);
    }

    // ---- GEMM-z: zpre = hidden @ mwB, K=128, N=128 ----
    f32x4 acc[2][2];
    #pragma unroll
    for (int mf = 0; mf < 2; ++mf)
        #pragma unroll
        for (int nfr = 0; nfr < 2; ++nfr) acc[mf][nfr] = (f32x4){0.f, 0.f, 0.f, 0.f};

    #pragma unroll
    for (int ks = 0; ks < 4; ++ks) {
        bf16x8 a[2];
        #pragma unroll
        for (int mf = 0; mf < 2; ++mf) {
            int m = wm * 32 + mf * 16 + lm;
            int slot = (ks * 4 + lk) ^ (m & 7);
            a[mf] = *reinterpret_cast<const bf16x8*>(&H[m * 128 + slot * 8]);
        }
        #pragma unroll
        for (int nfr = 0; nfr < 2; ++nfr) {
            int nt = wn * 2 + nfr;
            bf16x8 b = *reinterpret_cast<const bf16x8*>(&mwBp[((nt * 4 + ks) * 64 + l) * 8]);
            acc[0][nfr] = __builtin_amdgcn_mfma_f32_16x16x32_bf16(a[0], b, acc[0][nfr], 0, 0, 0);
            acc[1][nfr] = __builtin_amdgcn_mfma_f32_16x16x32_bf16(a[1], b, acc[1][nfr], 0, 0, 0);
        }
    }
    __syncthreads(); // nfa staged into S; H reads done

    // ---- z epilogue (all 8 waves) ----
    {
        float zbv[2], aw2v[2];
        #pragma unroll
        for (int nfr = 0; nfr < 2; ++nfr) {
            int nc = (wn * 2 + nfr) * 16 + lm;
            zbv[nfr] = zb[nc];
            aw2v[nfr] = aw2[nc];
        }
        #pragma unroll
        for (int mf = 0; mf < 2; ++mf)
            #pragma unroll
            for (int r = 0; r < 4; ++r) {
                int m = wm * 32 + mf * 16 + lk * 4 + r;
                float s = 0.0f;
                #pragma unroll
                for (int nfr = 0; nfr < 2; ++nfr) {
                    int nc = (wn * 2 + nfr) * 16 + lm;
                    float v = acc[mf][nfr][r] + zbv[nfr]
                            + unbf(S[m * 128 + ((nc >> 3) ^ (m & 7)) * 8 + (nc & 7)]);
                    v = (v > 0.0f) ? v : 0.2f * v;
                    s = fmaf(v, aw2v[nfr], s);
                }
                s += __shfl_xor(s, 1, 64);
                s += __shfl_xor(s, 2, 64);
                s += __shfl_xor(s, 4, 64);
                s += __shfl_xor(s, 8, 64);
                if (lm == 0) RED[m][wn] = s;
            }
    }
    __syncthreads();

    if (t < 64) {
        attn_raw[e0 + t] = RED[t][0] + RED[t][1] + RED[t][2] + RED[t][3] + ab2[0];
    }
}

// ---------------- fused per-node softmax + hidden aggregate (bf16 out) ------
// Standalone: 12 VGPR / 0 LDS -> ~85% occupancy hides the serial-loop latency.
__global__ __launch_bounds__(256) void k_aggr(
    const unsigned short* __restrict__ hid, const float* __restrict__ raw,
    const int* __restrict__ row_start, const int* __restrict__ cnt,
    unsigned short* __restrict__ haggrb)
{
    const int l = threadIdx.x & 63;
    const int n = blockIdx.x * 4 + (threadIdx.x >> 6);
    if (n >= NN) return;
    const int rs = row_start[n], deg = cnt[n];

    float m = -INFINITY;
    for (int j = l; j < deg; j += 64) m = fmaxf(m, raw[rs + j]);
    #pragma unroll
    for (int off = 32; off >= 1; off >>= 1) m = fmaxf(m, __shfl_xor(m, off, 64));

    float s = 0.0f;
    for (int j = l; j < deg; j += 64) s += expf(raw[rs + j] - m);
    #pragma unroll
    for (int off = 32; off >= 1; off >>= 1) s += __shfl_xor(s, off, 64);
    const float rinv = 1.0f / (s + 1e-8f);

    float a0 = 0.0f, a1 = 0.0f;
    for (int j = 0; j < deg; ++j) {
        float w = expf(raw[rs + j] - m) * rinv;   // uniform across lanes
        unsigned int v = *reinterpret_cast<const unsigned int*>(
            &hid[(size_t)(rs + j) * DD + l * 2]);
        a0 = fmaf(w, unlo(v), a0);
        a1 = fmaf(w, unhi(v), a1);
    }
    *reinterpret_cast<unsigned int*>(&haggrb[(size_t)n * DD + l * 2]) = pk2(a0, a1);
}

// ---------------- node kernel: GEMM0(mw2) + LN1 + FFN + LN2 (8 waves) -------
__global__ __launch_bounds__(512) void k_node(
    const float* __restrict__ nf, const unsigned short* __restrict__ haggrb,
    const unsigned short* __restrict__ mw2p, const float* __restrict__ mb2,
    const float* __restrict__ g1, const float* __restrict__ b1,
    const unsigned short* __restrict__ fw1p, const float* __restrict__ fb1,
    const unsigned short* __restrict__ fw2p, const float* __restrict__ fb2,
    const float* __restrict__ g2, const float* __restrict__ b2,
    float* __restrict__ out)
{
    __shared__ alignas(16) unsigned short XB[64 * 128]; // 16 KB
    __shared__ alignas(16) unsigned short HB[64 * 256]; // 32 KB (first 16KB = HG)

    const int t = threadIdx.x;
    const int w = t >> 6, l = t & 63;
    const int wm = w >> 2, wn = w & 3;
    const int lm = l & 15, lk = l >> 4;
    const int lrow = l >> 4, lslot = l & 15;
    const int row = t >> 3;      // 0..63
    const int q = t & 7;         // 16-col segment
    const long n0 = (long)blockIdx.x * 64;
    const long rg = n0 + row;
    const long rc = (rg < NN) ? rg : (NN - 1);

    // ---- stage HG <- haggrb (swizzled src) ----
    unsigned short* HG = HB;
    #pragma unroll
    for (int it = 0; it < 2; ++it) {
        int rb = w * 8 + it * 4;
        int rr = rb + lrow;
        long grow = n0 + rr; if (grow >= NN) grow = NN - 1;
        int c = lslot ^ (rr & 7);
        gload_lds16(haggrb + grow * DD + c * 8, &HG[rb * 128]);
    }
    __syncthreads();

    // ---- GEMM0: aggr = haggr @ mw2 + mb2 -> XB (bf16, swizzled) ----
    {
        f32x4 acc0[2][2];
        #pragma unroll
        for (int mf = 0; mf < 2; ++mf)
            #pragma unroll
            for (int nfr = 0; nfr < 2; ++nfr) acc0[mf][nfr] = (f32x4){0.f, 0.f, 0.f, 0.f};

        #pragma unroll
        for (int ks = 0; ks < 4; ++ks) {
            bf16x8 a[2];
            #pragma unroll
            for (int mf = 0; mf < 2; ++mf) {
                int m = wm * 32 + mf * 16 + lm;
                int slot = (ks * 4 + lk) ^ (m & 7);
                a[mf] = *reinterpret_cast<const bf16x8*>(&HG[m * 128 + slot * 8]);
            }
            #pragma unroll
            for (int nfr = 0; nfr < 2; ++nfr) {
                int nt = wn * 2 + nfr;
                bf16x8 b = *reinterpret_cast<const bf16x8*>(&mw2p[((nt * 4 + ks) * 64 + l) * 8]);
                acc0[0][nfr] = __builtin_amdgcn_mfma_f32_16x16x32_bf16(a[0], b, acc0[0][nfr], 0, 0, 0);
                acc0[1][nfr] = __builtin_amdgcn_mfma_f32_16x16x32_bf16(a[1], b, acc0[1][nfr], 0, 0, 0);
            }
        }
        #pragma unroll
        for (int nfr = 0; nfr < 2; ++nfr) {
            int n = (wn * 2 + nfr) * 16 + lm;
            float bv = mb2[n];
            #pragma unroll
            for (int mf = 0; mf < 2; ++mf)
                #pragma unroll
                for (int r = 0; r < 4; ++r) {
                    int m = wm * 32 + mf * 16 + lk * 4 + r;
                    XB[m * 128 + ((n >> 3) ^ (m & 7)) * 8 + (n & 7)] = bf16s(acc0[mf][nfr][r] + bv);
                }
        }
    }
    __syncthreads(); // XB = aggr (bf16)

    // ---- LN1: x = nf + aggr ----
    float xr[16];
    float s = 0.0f, ss = 0.0f;
    {
        const float* xp = nf + rc * DD + q * 16;
        #pragma unroll
        for (int i = 0; i < 2; ++i) {
            int c = q * 2 + i, slot = c ^ (row & 7);
            uint4 v = *reinterpret_cast<const uint4*>(&XB[row * 128 + slot * 8]);
            float f[8];
            f[0] = unlo(v.x); f[1] = unhi(v.x); f[2] = unlo(v.y); f[3] = unhi(v.y);
            f[4] = unlo(v.z); f[5] = unhi(v.z); f[6] = unlo(v.w); f[7] = unhi(v.w);
            float4 a = *reinterpret_cast<const float4*>(xp + i * 8);
            float4 b = *reinterpret_cast<const float4*>(xp + i * 8 + 4);
            float vv[8] = {a.x + f[0], a.y + f[1], a.z + f[2], a.w + f[3],
                           b.x + f[4], b.y + f[5], b.z + f[6], b.w + f[7]};
            #pragma unroll
            for (int j = 0; j < 8; ++j) {
                xr[i * 8 + j] = vv[j];
                s += vv[j];
                ss = fmaf(vv[j], vv[j], ss);
            }
        }
    }
    s  += __shfl_xor(s, 1, 64);  s  += __shfl_xor(s, 2, 64);  s  += __shfl_xor(s, 4, 64);
    ss += __shfl_xor(ss, 1, 64); ss += __shfl_xor(ss, 2, 64); ss += __shfl_xor(ss, 4, 64);
    {
        float mu = s * (1.0f / DD);
        float var = ss * (1.0f / DD) - mu * mu;
        float rstd = rsqrtf(var + 1e-5f);
        #pragma unroll
        for (int i = 0; i < 4; ++i) {
            float4 gv = *reinterpret_cast<const float4*>(g1 + q * 16 + i * 4);
            float4 bv = *reinterpret_cast<const float4*>(b1 + q * 16 + i * 4);
            xr[i * 4 + 0] = (xr[i * 4 + 0] - mu) * rstd * gv.x + bv.x;
            xr[i * 4 + 1] = (xr[i * 4 + 1] - mu) * rstd * gv.y + bv.y;
            xr[i * 4 + 2] = (xr[i * 4 + 2] - mu) * rstd * gv.z + bv.z;
            xr[i * 4 + 3] = (xr[i * 4 + 3] - mu) * rstd * gv.w + bv.w;
        }
        #pragma unroll
        for (int i = 0; i < 2; ++i) {
            int c = q * 2 + i, slot = c ^ (row & 7);
            uint4 v;
            v.x = pk2(xr[i * 8 + 0], xr[i * 8 + 1]);
            v.y = pk2(xr[i * 8 + 2], xr[i * 8 + 3]);
            v.z = pk2(xr[i * 8 + 4], xr[i * 8 + 5]);
            v.w = pk2(xr[i * 8 + 6], xr[i * 8 + 7]);
            *reinterpret_cast<uint4*>(&XB[row * 128 + slot * 8]) = v;
        }
    }
    __syncthreads();

    // ---- FFN: two 256-col halves ----
    f32x4 acc2[2][2];
    #pragma unroll
    for (int mf = 0; mf < 2; ++mf)
        #pragma unroll
        for (int nfr = 0; nfr < 2; ++nfr) acc2[mf][nfr] = (f32x4){0.f, 0.f, 0.f, 0.f};

    #pragma unroll
    for (int half = 0; half < 2; ++half) {
        f32x4 acc[2][4];
        #pragma unroll
        for (int mf = 0; mf < 2; ++mf)
            #pragma unroll
            for (int nfr = 0; nfr < 4; ++nfr) acc[mf][nfr] = (f32x4){0.f, 0.f, 0.f, 0.f};

        #pragma unroll
        for (int ks = 0; ks < 4; ++ks) {
            bf16x8 a[2];
            #pragma unroll
            for (int mf = 0; mf < 2; ++mf) {
                int m = wm * 32 + mf * 16 + lm;
                int slot = (ks * 4 + lk) ^ (m & 7);
                a[mf] = *reinterpret_cast<const bf16x8*>(&XB[m * 128 + slot * 8]);
            }
            #pragma unroll
            for (int nfr = 0; nfr < 4; ++nfr) {
                int nt = half * 16 + wn * 4 + nfr;
                bf16x8 b = *reinterpret_cast<const bf16x8*>(&fw1p[((nt * 4 + ks) * 64 + l) * 8]);
                acc[0][nfr] = __builtin_amdgcn_mfma_f32_16x16x32_bf16(a[0], b, acc[0][nfr], 0, 0, 0);
                acc[1][nfr] = __builtin_amdgcn_mfma_f32_16x16x32_bf16(a[1], b, acc[1][nfr], 0, 0, 0);
            }
        }
        #pragma unroll
        for (int nfr = 0; nfr < 4; ++nfr) {
            int nl = (wn * 4 + nfr) * 16 + lm;
            float bv = fb1[half * 256 + nl];
            #pragma unroll
            for (int mf = 0; mf < 2; ++mf)
                #pragma unroll
                for (int r = 0; r < 4; ++r) {
                    int m = wm * 32 + mf * 16 + lk * 4 + r;
                    float h = acc[mf][nfr][r] + bv;
                    float e = __expf(h * -1.702f);
                    float gvv = h * __builtin_amdgcn_rcpf(1.0f + e);
                    HB[m * 256 + (((nl >> 3) ^ (m & 7)) * 8) + (nl & 7)] = bf16s(gvv);
                }
        }
        __syncthreads();

        #pragma unroll
        for (int ks = 0; ks < 8; ++ks) {
            bf16x8 a[2];
            #pragma unroll
            for (int mf = 0; mf < 2; ++mf) {
                int m = wm * 32 + mf * 16 + lm;
                int slot = (ks * 4 + lk) ^ (m & 7);
                a[mf] = *reinterpret_cast<const bf16x8*>(&HB[m * 256 + slot * 8]);
            }
            #pragma unroll
            for (int nfr = 0; nfr < 2; ++nfr) {
                int nt = wn * 2 + nfr;
                int kg = half * 8 + ks;
                bf16x8 b = *reinterpret_cast<const bf16x8*>(&fw2p[((nt * 16 + kg) * 64 + l) * 8]);
                acc2[0][nfr] = __builtin_amdgcn_mfma_f32_16x16x32_bf16(a[0], b, acc2[0][nfr], 0, 0, 0);
                acc2[1][nfr] = __builtin_amdgcn_mfma_f32_16x16x32_bf16(a[1], b, acc2[1][nfr], 0, 0, 0);
            }
        }
        __syncthreads();
    }

    // ---- ffn -> XB (bf16) ----
    #pragma unroll
    for (int nfr = 0; nfr < 2; ++nfr) {
        int n = (wn * 2 + nfr) * 16 + lm;
        float bv = fb2[n];
        #pragma unroll
        for (int mf = 0; mf < 2; ++mf)
            #pragma unroll
            for (int r = 0; r < 4; ++r) {
                int m = wm * 32 + mf * 16 + lk * 4 + r;
                XB[m * 128 + (((n >> 3) ^ (m & 7)) * 8) + (n & 7)] = bf16s(acc2[mf][nfr][r] + bv);
            }
    }
    __syncthreads();

    // ---- residual + LN2 ----
    float s2 = 0.0f, ss2 = 0.0f;
    #pragma unroll
    for (int i = 0; i < 2; ++i) {
        int c = q * 2 + i, slot = c ^ (row & 7);
        uint4 v = *reinterpret_cast<const uint4*>(&XB[row * 128 + slot * 8]);
        float f[8];
        f[0] = unlo(v.x); f[1] = unhi(v.x); f[2] = unlo(v.y); f[3] = unhi(v.y);
        f[4] = unlo(v.z); f[5] = unhi(v.z); f[6] = unlo(v.w); f[7] = unhi(v.w);
        #pragma unroll
        for (int j = 0; j < 8; ++j) {
            float vv = xr[i * 8 + j] + f[j];
            xr[i * 8 + j] = vv;
            s2 += vv;
            ss2 = fmaf(vv, vv, ss2);
        }
    }
    s2  += __shfl_xor(s2, 1, 64);  s2  += __shfl_xor(s2, 2, 64);  s2  += __shfl_xor(s2, 4, 64);
    ss2 += __shfl_xor(ss2, 1, 64); ss2 += __shfl_xor(ss2, 2, 64); ss2 += __shfl_xor(ss2, 4, 64);
    {
        float mu = s2 * (1.0f / DD);
        float var = ss2 * (1.0f / DD) - mu * mu;
        float rstd = rsqrtf(var + 1e-5f);
        if (rg < NN) {
            float* op = out + rg * DD + q * 16;
            #pragma unroll
            for (int i = 0; i < 4; ++i) {
                float4 gv = *reinterpret_cast<const float4*>(g2 + q * 16 + i * 4);
                float4 bv = *reinterpret_cast<const float4*>(b2 + q * 16 + i * 4);
                float4 o;
                o.x = (xr[i * 4 + 0] - mu) * rstd * gv.x + bv.x;
                o.y = (xr[i * 4 + 1] - mu) * rstd * gv.y + bv.y;
                o.z = (xr[i * 4 + 2] - mu) * rstd * gv.z + bv.z;
                o.w = (xr[i * 4 + 3] - mu) * rstd * gv.w + bv.w;
                *reinterpret_cast<float4*>(op + i * 4) = o;
            }
        }
    }
}

extern "C" void kernel_launch(void* const* d_in, const int* in_sizes, int n_in,
                              void* d_out, int out_size, void* d_ws, size_t ws_size,
                              hipStream_t stream)
{
    const float* nf  = (const float*)d_in[0];
    const int*   ei  = (const int*)d_in[1];
    const int*   et  = (const int*)d_in[2];
    const float* rel = (const float*)d_in[3];
    const float* mw1 = (const float*)d_in[4];
    const float* mb1 = (const float*)d_in[5];
    const float* mw2 = (const float*)d_in[6];
    const float* mb2 = (const float*)d_in[7];
    const float* aw1 = (const float*)d_in[8];
    const float* ab1 = (const float*)d_in[9];
    const float* aw2 = (const float*)d_in[10];
    const float* ab2 = (const float*)d_in[11];
    const float* g1  = (const float*)d_in[12];
    const float* b1  = (const float*)d_in[13];
    const float* fw1 = (const float*)d_in[14];
    const float* fb1 = (const float*)d_in[15];
    const float* fw2 = (const float*)d_in[16];
    const float* fb2 = (const float*)d_in[17];
    const float* g2  = (const float*)d_in[18];
    const float* b2  = (const float*)d_in[19];
    float* out = (float*)d_out;

    char* ws = (char*)d_ws;
    size_t off = 0;
    auto alloc = [&](size_t bytes) -> char* {
        char* p = ws + off;
        off += (bytes + 255) & ~(size_t)255;
        return p;
    };
    unsigned short* hid = (unsigned short*)alloc((size_t)NE * DD * 2);
    float* attn_raw = (float*)alloc((size_t)NE * 4);
    unsigned short* haggrb = (unsigned short*)alloc((size_t)NN * DD * 2);
    unsigned short* nfa = (unsigned short*)alloc((size_t)NN * DD * 2);
    unsigned short* nfb = (unsigned short*)alloc((size_t)NN * DD * 2);
    unsigned short* relcb = (unsigned short*)alloc((size_t)RR * DD * 2);
    float* zb  = (float*)alloc((size_t)128 * 4);
    int* cnt       = (int*)alloc((size_t)NN * 4);
    int* row_start = (int*)alloc((size_t)NN * 4);
    int* cursor    = (int*)alloc((size_t)NN * 4);
    int* srcs      = (int*)alloc((size_t)NE * 4);
    int* ets       = (int*)alloc((size_t)NE * 4);
    int* dsts      = (int*)alloc((size_t)NE * 4);
    int* bsum      = (int*)alloc((size_t)SCAN_NB * 4);
    unsigned short* mw1p = (unsigned short*)alloc(16384 * 2);
    unsigned short* mw2p = (unsigned short*)alloc(16384 * 2);
    unsigned short* awTp = (unsigned short*)alloc(16384 * 2);
    unsigned short* mwBp = (unsigned short*)alloc(16384 * 2);
    unsigned short* fw1p = (unsigned short*)alloc(65536 * 2);
    unsigned short* fw2p = (unsigned short*)alloc(65536 * 2);

    const int* srcp = ei;
    const int* dstp = ei + NE;

    hipLaunchKernelGGL(k_initc, dim3(SCAN_NB), dim3(256), 0, stream, cnt);
    hipLaunchKernelGGL(k_hist, dim3((NE + 255) / 256), dim3(256), 0, stream, dstp, cnt);
    hipLaunchKernelGGL(k_scanA, dim3(SCAN_NB), dim3(256), 0, stream, cnt, bsum);
    hipLaunchKernelGGL(k_scanB, dim3(1), dim3(512), 0, stream, bsum);
    hipLaunchKernelGGL(k_scanC, dim3(SCAN_NB), dim3(256), 0, stream, cnt, bsum, row_start, cursor);
    hipLaunchKernelGGL(k_bucket, dim3((NE + 255) / 256), dim3(256), 0, stream,
                       srcp, dstp, et, cursor, srcs, ets, dsts);
    hipLaunchKernelGGL(k_setup, dim3(869), dim3(256), 0, stream,
                       mw1, mb1, mw2, mb2, aw1, rel, fw1, fw2,
                       mw1p, mw2p, awTp, mwBp, fw1p, fw2p, relcb, zb);
    hipLaunchKernelGGL(k_prepnfa, dim3((NN + 63) / 64), dim3(256), 0, stream,
                       nf, awTp, ab1, nfb, nfa);
    hipLaunchKernelGGL(k_edge, dim3(NE / 64), dim3(512), 0, stream,
                       nfb, srcs, dsts, ets, nfa, relcb,
                       mw1p, mwBp, zb, aw2, ab2,
                       hid, attn_raw);
    hipLaunchKernelGGL(k_aggr, dim3((NN + 3) / 4), dim3(256), 0, stream,
                       hid, attn_raw, row_start, cnt, haggrb);
    hipLaunchKernelGGL(k_node, dim3((NN + 63) / 64), dim3(512), 0, stream,
                       nf, haggrb, mw2p, mb2, g1, b1, fw1p, fb1, fw2p, fb2, g2, b2, out);
}

// Round 12
// 415.964 us; speedup vs baseline: 1.4182x; 1.0520x over previous
//
#include <hip/hip_runtime.h>
#include <hip/hip_bf16.h>

#define NN 100000
#define NE 600000
#define DD 128
#define RR 200
#define SCAN_NB ((NN + 255) / 256)   // 391

typedef __attribute__((ext_vector_type(8))) short bf16x8;
typedef __attribute__((ext_vector_type(4))) float f32x4;

__device__ __forceinline__ unsigned int bfbits(float x) {
    return (unsigned int)__builtin_bit_cast(unsigned short, __float2bfloat16(x));
}
__device__ __forceinline__ unsigned int pk2(float a, float b) {
    return bfbits(a) | (bfbits(b) << 16);
}
__device__ __forceinline__ unsigned short bf16s(float x) {
    return __builtin_bit_cast(unsigned short, __float2bfloat16(x));
}
__device__ __forceinline__ float unbf(unsigned short u) {
    return __builtin_bit_cast(float, ((unsigned int)u) << 16);
}
__device__ __forceinline__ float unlo(unsigned int u) {
    return __builtin_bit_cast(float, u << 16);
}
__device__ __forceinline__ float unhi(unsigned int u) {
    return __builtin_bit_cast(float, u & 0xffff0000u);
}

__device__ __forceinline__ void gload_lds16(const void* g, void* l) {
    __builtin_amdgcn_global_load_lds(
        (const __attribute__((address_space(1))) void*)g,
        (__attribute__((address_space(3))) void*)l, 16, 0, 0);
}

// ---------------- histogram of dst ----------------
__global__ void k_hist(const int* __restrict__ dst, int* __restrict__ cnt) {
    int e = blockIdx.x * 256 + threadIdx.x;
    if (e < NE) atomicAdd(&cnt[dst[e]], 1);
}

// ---------------- 3-kernel exclusive scan over cnt[NN] ----------------
__global__ void k_scanA(const int* __restrict__ cnt, int* __restrict__ bsum) {
    __shared__ int red[256];
    int i = blockIdx.x * 256 + threadIdx.x;
    red[threadIdx.x] = (i < NN) ? cnt[i] : 0;
    __syncthreads();
    for (int off = 128; off >= 1; off >>= 1) {
        if (threadIdx.x < off) red[threadIdx.x] += red[threadIdx.x + off];
        __syncthreads();
    }
    if (threadIdx.x == 0) bsum[blockIdx.x] = red[0];
}

__global__ void k_scanB(int* __restrict__ bsum) {
    __shared__ int sh[512];
    int t = threadIdx.x;
    int v = (t < SCAN_NB) ? bsum[t] : 0;
    sh[t] = v;
    __syncthreads();
    for (int off = 1; off < 512; off <<= 1) {
        int add = (t >= off) ? sh[t - off] : 0;
        __syncthreads();
        sh[t] += add;
        __syncthreads();
    }
    if (t < SCAN_NB) bsum[t] = sh[t] - v;   // exclusive
}

__global__ void k_scanC(const int* __restrict__ cnt, const int* __restrict__ bsum,
                        int* __restrict__ row_start, int* __restrict__ cursor) {
    __shared__ int sh[256];
    int i = blockIdx.x * 256 + threadIdx.x;
    int t = threadIdx.x;
    int v = (i < NN) ? cnt[i] : 0;
    sh[t] = v;
    __syncthreads();
    for (int off = 1; off < 256; off <<= 1) {
        int add = (t >= off) ? sh[t - off] : 0;
        __syncthreads();
        sh[t] += add;
        __syncthreads();
    }
    if (i < NN) {
        int ex = bsum[blockIdx.x] + sh[t] - v;
        row_start[i] = ex;
        cursor[i] = ex;
    }
}

// ---------------- bucket: permuted src/etype/dst grouped by dst ----------------
__global__ void k_bucket(const int* __restrict__ src, const int* __restrict__ dst,
                         const int* __restrict__ etype, int* __restrict__ cursor,
                         int* __restrict__ srcs, int* __restrict__ ets,
                         int* __restrict__ dsts) {
    int e = blockIdx.x * 256 + threadIdx.x;
    if (e < NE) {
        int d = dst[e];
        int p = atomicAdd(&cursor[d], 1);
        srcs[p] = src[e];
        ets[p]  = etype[e];
        dsts[p] = d;
    }
}

// ---------------- setup: weight packing + folds + cnt zeroing (one launch) ---
__global__ void k_setup(const float* __restrict__ mw1, const float* __restrict__ mb1,
                        const float* __restrict__ mw2, const float* __restrict__ mb2,
                        const float* __restrict__ aw1, const float* __restrict__ rel,
                        const float* __restrict__ fw1, const float* __restrict__ fw2,
                        unsigned short* __restrict__ mw1p,
                        unsigned short* __restrict__ mw2p,
                        unsigned short* __restrict__ awTp,
                        unsigned short* __restrict__ mwBp,
                        unsigned short* __restrict__ fw1p,
                        unsigned short* __restrict__ fw2p,
                        unsigned short* __restrict__ relcb,
                        float* __restrict__ zb, int* __restrict__ cnt) {
    int idx = blockIdx.x * 256 + threadIdx.x;   // 322336 total
    if (idx < 16384) {            // mw1 TOP: K=128, N=128
        int i = idx & 7, l = (idx >> 3) & 63, ks = (idx >> 9) & 3, nt = idx >> 11;
        int k = ks * 32 + (l >> 4) * 8 + i, n = nt * 16 + (l & 15);
        mw1p[idx] = bf16s(mw1[k * 128 + n]);
    } else if (idx < 32768) {     // mw2: K=128, N=128
        int j = idx - 16384;
        int i = j & 7, l = (j >> 3) & 63, ks = (j >> 9) & 3, nt = j >> 11;
        int k = ks * 32 + (l >> 4) * 8 + i, n = nt * 16 + (l & 15);
        mw2p[j] = bf16s(mw2[k * 128 + n]);
    } else if (idx < 49152) {     // aw1 TOP: K=128, N=128
        int j = idx - 32768;
        int i = j & 7, l = (j >> 3) & 63, ks = (j >> 9) & 3, nt = j >> 11;
        int k = ks * 32 + (l >> 4) * 8 + i, n = nt * 16 + (l & 15);
        awTp[j] = bf16s(aw1[k * 128 + n]);
    } else if (idx < 65536) {     // mwB = mw2 @ aw1_bot (direct dot)
        int j = idx - 49152;
        int i = j & 7, l = (j >> 3) & 63, ks = (j >> 9) & 3, nt = j >> 11;
        int k = ks * 32 + (l >> 4) * 8 + i, n = nt * 16 + (l & 15);
        float s = 0.0f;
        for (int j2 = 0; j2 < 128; ++j2)
            s = fmaf(mw2[k * 128 + j2], aw1[(128 + j2) * 128 + n], s);
        mwBp[j] = bf16s(s);
    } else if (idx < 131072) {    // fw1: K=128, N=512
        int j = idx - 65536;
        int i = j & 7, l = (j >> 3) & 63, ks = (j >> 9) & 3, nt = j >> 11;
        int k = ks * 32 + (l >> 4) * 8 + i, n = nt * 16 + (l & 15);
        fw1p[j] = bf16s(fw1[k * 512 + n]);
    } else if (idx < 196608) {    // fw2: K=512 (KS=16), N=128
        int j = idx - 131072;
        int i = j & 7, l = (j >> 3) & 63, ks = (j >> 9) & 15, nt = j >> 13;
        int k = ks * 32 + (l >> 4) * 8 + i, n = nt * 16 + (l & 15);
        fw2p[j] = bf16s(fw2[k * 128 + n]);
    } else if (idx < 222208) {    // relcb = bf16(rel @ mw1_bot + mb1)
        int j = idx - 196608;
        int r = j >> 7, n = j & 127;
        float s = mb1[n];
        for (int k = 0; k < 128; ++k)
            s = fmaf(rel[r * 128 + k], mw1[(128 + k) * 128 + n], s);
        relcb[j] = bf16s(s);
    } else if (idx < 222336) {    // zb = mb2 @ aw1_bot
        int n = idx - 222208;
        float s = 0.0f;
        for (int j2 = 0; j2 < 128; ++j2)
            s = fmaf(mb2[j2], aw1[(128 + j2) * 128 + n], s);
        zb[n] = s;
    } else if (idx < 322336) {    // zero cnt
        cnt[idx - 222336] = 0;
    }
}

// ---------------- prep+nfa fused: nfb = bf16(nf); nfa = nf @ aw1_top + ab1 ---
__global__ __launch_bounds__(256) void k_prepnfa(
    const float* __restrict__ nf, const unsigned short* __restrict__ awTp,
    const float* __restrict__ ab1,
    unsigned short* __restrict__ nfb, unsigned short* __restrict__ nfa)
{
    __shared__ alignas(16) unsigned short XB[64 * 128]; // 16 KB
    const int t = threadIdx.x;
    const int w = t >> 6, l = t & 63;
    const int wm = w >> 1, wn = w & 1;
    const int lm = l & 15, lk = l >> 4;
    const int n0 = blockIdx.x * 64;

    {
        const int row = t >> 2, seg = t & 3;
        long ng = n0 + row; if (ng >= NN) ng = NN - 1;
        const float* sp = nf + ng * DD + seg * 32;
        uint4 o[4];
        #pragma unroll
        for (int i = 0; i < 4; ++i) {
            float4 f0 = *reinterpret_cast<const float4*>(sp + i * 8);
            float4 f1 = *reinterpret_cast<const float4*>(sp + i * 8 + 4);
            o[i].x = pk2(f0.x, f0.y); o[i].y = pk2(f0.z, f0.w);
            o[i].z = pk2(f1.x, f1.y); o[i].w = pk2(f1.z, f1.w);
        }
        if (n0 + row < NN) {
            #pragma unroll
            for (int i = 0; i < 4; ++i)
                *reinterpret_cast<uint4*>(&nfb[(size_t)(n0 + row) * DD + (seg * 4 + i) * 8]) = o[i];
        }
        #pragma unroll
        for (int i = 0; i < 4; ++i) {
            int c = seg * 4 + i, slot = c ^ (row & 7);
            *reinterpret_cast<uint4*>(&XB[row * 128 + slot * 8]) = o[i];
        }
    }
    __syncthreads();

    f32x4 acc[2][4];
    #pragma unroll
    for (int mf = 0; mf < 2; ++mf)
        #pragma unroll
        for (int nfr = 0; nfr < 4; ++nfr) acc[mf][nfr] = (f32x4){0.f, 0.f, 0.f, 0.f};

    #pragma unroll
    for (int ks = 0; ks < 4; ++ks) {
        bf16x8 a[2];
        #pragma unroll
        for (int mf = 0; mf < 2; ++mf) {
            int m = wm * 32 + mf * 16 + lm;
            int slot = (ks * 4 + lk) ^ (m & 7);
            a[mf] = *reinterpret_cast<const bf16x8*>(&XB[m * 128 + slot * 8]);
        }
        #pragma unroll
        for (int nfr = 0; nfr < 4; ++nfr) {
            int nt = wn * 4 + nfr;
            bf16x8 b = *reinterpret_cast<const bf16x8*>(&awTp[((nt * 4 + ks) * 64 + l) * 8]);
            acc[0][nfr] = __builtin_amdgcn_mfma_f32_16x16x32_bf16(a[0], b, acc[0][nfr], 0, 0, 0);
            acc[1][nfr] = __builtin_amdgcn_mfma_f32_16x16x32_bf16(a[1], b, acc[1][nfr], 0, 0, 0);
        }
    }
    __syncthreads();

    #pragma unroll
    for (int nfr = 0; nfr < 4; ++nfr) {
        int n = wn * 64 + nfr * 16 + lm;
        float bv = ab1[n];
        #pragma unroll
        for (int mf = 0; mf < 2; ++mf)
            #pragma unroll
            for (int r = 0; r < 4; ++r) {
                int m = wm * 32 + mf * 16 + lk * 4 + r;
                XB[m * 128 + n] = bf16s(acc[mf][nfr][r] + bv);
            }
    }
    __syncthreads();

    #pragma unroll
    for (int j = 0; j < 4; ++j) {
        int q = j * 256 + t;
        int row = q >> 4, c16 = q & 15;
        if (n0 + row < NN)
            *reinterpret_cast<uint4*>(&nfa[(size_t)(n0 + row) * DD + c16 * 8]) =
                *reinterpret_cast<const uint4*>(&XB[row * 128 + c16 * 8]);
    }
}

// ---------------- edge kernel: GEMM1(hidden) + GEMM-z(logits) ---------------
__global__ __launch_bounds__(512) void k_edge(
    const unsigned short* __restrict__ nfb, const int* __restrict__ srcs,
    const int* __restrict__ dsts, const int* __restrict__ ets,
    const unsigned short* __restrict__ nfa, const unsigned short* __restrict__ relcb,
    const unsigned short* __restrict__ mw1p, const unsigned short* __restrict__ mwBp,
    const float* __restrict__ zb, const float* __restrict__ aw2,
    const float* __restrict__ ab2,
    unsigned short* __restrict__ hid_out, float* __restrict__ attn_raw)
{
    __shared__ alignas(16) unsigned short S[64 * 128];  // src rows, then nfa[dst]
    __shared__ alignas(16) unsigned short H[64 * 128];  // relc, then hidden
    __shared__ float RED[64][4];

    const int t = threadIdx.x;
    const int w = t >> 6, l = t & 63;
    const int wm = w >> 2, wn = w & 3;
    const int lm = l & 15, lk = l >> 4;
    const int lrow = l >> 4, lslot = l & 15;
    const int e0 = blockIdx.x * 64;

    #pragma unroll
    for (int it = 0; it < 2; ++it) {
        int rb = w * 8 + it * 4;
        int row = rb + lrow;
        int c = lslot ^ (row & 7);
        gload_lds16(nfb + (size_t)srcs[e0 + row] * DD + c * 8, &S[rb * 128]);
    }
    #pragma unroll
    for (int it = 0; it < 2; ++it) {
        int rb = w * 8 + it * 4;
        int row = rb + lrow;
        int c = lslot ^ (row & 7);
        gload_lds16(relcb + (size_t)ets[e0 + row] * DD + c * 8, &H[rb * 128]);
    }
    __syncthreads();

    // ---- GEMM1: hidden = relu(src @ mw1_top + relc), K=128; H slot RMW ----
    {
        f32x4 acc1[2][2];
        #pragma unroll
        for (int mf = 0; mf < 2; ++mf)
            #pragma unroll
            for (int nfr = 0; nfr < 2; ++nfr) acc1[mf][nfr] = (f32x4){0.f, 0.f, 0.f, 0.f};

        #pragma unroll
        for (int ks = 0; ks < 4; ++ks) {
            bf16x8 a[2];
            #pragma unroll
            for (int mf = 0; mf < 2; ++mf) {
                int m = wm * 32 + mf * 16 + lm;
                int slot = (ks * 4 + lk) ^ (m & 7);
                a[mf] = *reinterpret_cast<const bf16x8*>(&S[m * 128 + slot * 8]);
            }
            #pragma unroll
            for (int nfr = 0; nfr < 2; ++nfr) {
                int nt = wn * 2 + nfr;
                bf16x8 b = *reinterpret_cast<const bf16x8*>(&mw1p[((nt * 4 + ks) * 64 + l) * 8]);
                acc1[0][nfr] = __builtin_amdgcn_mfma_f32_16x16x32_bf16(a[0], b, acc1[0][nfr], 0, 0, 0);
                acc1[1][nfr] = __builtin_amdgcn_mfma_f32_16x16x32_bf16(a[1], b, acc1[1][nfr], 0, 0, 0);
            }
        }
        #pragma unroll
        for (int nfr = 0; nfr < 2; ++nfr) {
            int n = (wn * 2 + nfr) * 16 + lm;
            #pragma unroll
            for (int mf = 0; mf < 2; ++mf)
                #pragma unroll
                for (int r = 0; r < 4; ++r) {
                    int m = wm * 32 + mf * 16 + lk * 4 + r;
                    int sl = m * 128 + ((n >> 3) ^ (m & 7)) * 8 + (n & 7);
                    float v = acc1[mf][nfr][r] + unbf(H[sl]);
                    v = fmaxf(v, 0.0f);
                    H[sl] = bf16s(v);
                }
        }
    }
    __syncthreads(); // hidden complete; S (src) reads done

    // ---- copy hidden -> global (overlaps GEMM-z); stage S <- nfa[dsts] ----
    #pragma unroll
    for (int j = 0; j < 2; ++j) {
        int q = j * 512 + t;
        int row = q >> 4, c16 = q & 15;
        int slot = c16 ^ (row & 7);
        *reinterpret_cast<uint4*>(&hid_out[(size_t)(e0 + row) * DD + c16 * 8]) =
            *reinterpret_cast<const uint4*>(&H[row * 128 + slot * 8]);
    }
    #pragma unroll
    for (int it = 0; it < 2; ++it) {
        int rb = w * 8 + it * 4;
        int row = rb + lrow;
        int c = lslot ^ (row & 7);
        gload_lds16(nfa + (size_t)dsts[e0 + row] * DD + c * 8, &S[rb * 128]);
    }

    // ---- GEMM-z: zpre = hidden @ mwB, K=128, N=128 ----
    f32x4 acc[2][2];
    #pragma unroll
    for (int mf = 0; mf < 2; ++mf)
        #pragma unroll
        for (int nfr = 0; nfr < 2; ++nfr) acc[mf][nfr] = (f32x4){0.f, 0.f, 0.f, 0.f};

    #pragma unroll
    for (int ks = 0; ks < 4; ++ks) {
        bf16x8 a[2];
        #pragma unroll
        for (int mf = 0; mf < 2; ++mf) {
            int m = wm * 32 + mf * 16 + lm;
            int slot = (ks * 4 + lk) ^ (m & 7);
            a[mf] = *reinterpret_cast<const bf16x8*>(&H[m * 128 + slot * 8]);
        }
        #pragma unroll
        for (int nfr = 0; nfr < 2; ++nfr) {
            int nt = wn * 2 + nfr;
            bf16x8 b = *reinterpret_cast<const bf16x8*>(&mwBp[((nt * 4 + ks) * 64 + l) * 8]);
            acc[0][nfr] = __builtin_amdgcn_mfma_f32_16x16x32_bf16(a[0], b, acc[0][nfr], 0, 0, 0);
            acc[1][nfr] = __builtin_amdgcn_mfma_f32_16x16x32_bf16(a[1], b, acc[1][nfr], 0, 0, 0);
        }
    }
    __syncthreads(); // nfa staged into S; H reads done

    // ---- z epilogue (all 8 waves) ----
    {
        float zbv[2], aw2v[2];
        #pragma unroll
        for (int nfr = 0; nfr < 2; ++nfr) {
            int nc = (wn * 2 + nfr) * 16 + lm;
            zbv[nfr] = zb[nc];
            aw2v[nfr] = aw2[nc];
        }
        #pragma unroll
        for (int mf = 0; mf < 2; ++mf)
            #pragma unroll
            for (int r = 0; r < 4; ++r) {
                int m = wm * 32 + mf * 16 + lk * 4 + r;
                float s = 0.0f;
                #pragma unroll
                for (int nfr = 0; nfr < 2; ++nfr) {
                    int nc = (wn * 2 + nfr) * 16 + lm;
                    float v = acc[mf][nfr][r] + zbv[nfr]
                            + unbf(S[m * 128 + ((nc >> 3) ^ (m & 7)) * 8 + (nc & 7)]);
                    v = (v > 0.0f) ? v : 0.2f * v;
                    s = fmaf(v, aw2v[nfr], s);
                }
                s += __shfl_xor(s, 1, 64);
                s += __shfl_xor(s, 2, 64);
                s += __shfl_xor(s, 4, 64);
                s += __shfl_xor(s, 8, 64);
                if (lm == 0) RED[m][wn] = s;
            }
    }
    __syncthreads();

    if (t < 64) {
        attn_raw[e0 + t] = RED[t][0] + RED[t][1] + RED[t][2] + RED[t][3] + ab2[0];
    }
}

// ---------------- fused per-node softmax + hidden aggregate (bf16 out) ------
// 1 KB LDS weight stash avoids 64x-redundant uniform expf in the inner loop.
__global__ __launch_bounds__(256) void k_aggr(
    const unsigned short* __restrict__ hid, const float* __restrict__ raw,
    const int* __restrict__ row_start, const int* __restrict__ cnt,
    unsigned short* __restrict__ haggrb)
{
    __shared__ float wbuf[4][64];
    const int l = threadIdx.x & 63;
    const int nib = threadIdx.x >> 6;
    const int n = blockIdx.x * 4 + nib;
    if (n >= NN) return;
    const int rs = row_start[n], deg = cnt[n];

    float m = -INFINITY;
    for (int j = l; j < deg; j += 64) m = fmaxf(m, raw[rs + j]);
    #pragma unroll
    for (int off = 32; off >= 1; off >>= 1) m = fmaxf(m, __shfl_xor(m, off, 64));

    float s = 0.0f;
    for (int j = l; j < deg; j += 64) s += expf(raw[rs + j] - m);
    #pragma unroll
    for (int off = 32; off >= 1; off >>= 1) s += __shfl_xor(s, off, 64);
    const float rinv = 1.0f / (s + 1e-8f);

    float a0 = 0.0f, a1 = 0.0f;
    for (int base = 0; base < deg; base += 64) {
        int ntc = min(64, deg - base);
        if (l < ntc) wbuf[nib][l] = expf(raw[rs + base + l] - m) * rinv;
        // wave-private LDS (wave64 lockstep): no barrier needed
        for (int j = 0; j < ntc; ++j) {
            float w = wbuf[nib][j];     // broadcast read
            unsigned int v = *reinterpret_cast<const unsigned int*>(
                &hid[(size_t)(rs + base + j) * DD + l * 2]);
            a0 = fmaf(w, unlo(v), a0);
            a1 = fmaf(w, unhi(v), a1);
        }
    }
    *reinterpret_cast<unsigned int*>(&haggrb[(size_t)n * DD + l * 2]) = pk2(a0, a1);
}

// ---------------- node kernel: GEMM0(mw2) + LN1 + FFN(4 chunks) + LN2 -------
// LDS 32 KB -> 4 blocks/CU (100% wave occupancy).
__global__ __launch_bounds__(512) void k_node(
    const float* __restrict__ nf, const unsigned short* __restrict__ haggrb,
    const unsigned short* __restrict__ mw2p, const float* __restrict__ mb2,
    const float* __restrict__ g1, const float* __restrict__ b1,
    const unsigned short* __restrict__ fw1p, const float* __restrict__ fb1,
    const unsigned short* __restrict__ fw2p, const float* __restrict__ fb2,
    const float* __restrict__ g2, const float* __restrict__ b2,
    float* __restrict__ out)
{
    __shared__ alignas(16) unsigned short XB[64 * 128]; // 16 KB
    __shared__ alignas(16) unsigned short HB[64 * 128]; // 16 KB (also HG staging)

    const int t = threadIdx.x;
    const int w = t >> 6, l = t & 63;
    const int wm = w >> 2, wn = w & 3;
    const int lm = l & 15, lk = l >> 4;
    const int lrow = l >> 4, lslot = l & 15;
    const int row = t >> 3;      // 0..63
    const int q = t & 7;         // 16-col segment
    const long n0 = (long)blockIdx.x * 64;
    const long rg = n0 + row;
    const long rc = (rg < NN) ? rg : (NN - 1);

    // ---- stage HG <- haggrb (swizzled src) ----
    unsigned short* HG = HB;
    #pragma unroll
    for (int it = 0; it < 2; ++it) {
        int rb = w * 8 + it * 4;
        int rr = rb + lrow;
        long grow = n0 + rr; if (grow >= NN) grow = NN - 1;
        int c = lslot ^ (rr & 7);
        gload_lds16(haggrb + grow * DD + c * 8, &HG[rb * 128]);
    }
    __syncthreads();

    // ---- GEMM0: aggr = haggr @ mw2 + mb2 -> XB (bf16, swizzled) ----
    {
        f32x4 acc0[2][2];
        #pragma unroll
        for (int mf = 0; mf < 2; ++mf)
            #pragma unroll
            for (int nfr = 0; nfr < 2; ++nfr) acc0[mf][nfr] = (f32x4){0.f, 0.f, 0.f, 0.f};

        #pragma unroll
        for (int ks = 0; ks < 4; ++ks) {
            bf16x8 a[2];
            #pragma unroll
            for (int mf = 0; mf < 2; ++mf) {
                int m = wm * 32 + mf * 16 + lm;
                int slot = (ks * 4 + lk) ^ (m & 7);
                a[mf] = *reinterpret_cast<const bf16x8*>(&HG[m * 128 + slot * 8]);
            }
            #pragma unroll
            for (int nfr = 0; nfr < 2; ++nfr) {
                int nt = wn * 2 + nfr;
                bf16x8 b = *reinterpret_cast<const bf16x8*>(&mw2p[((nt * 4 + ks) * 64 + l) * 8]);
                acc0[0][nfr] = __builtin_amdgcn_mfma_f32_16x16x32_bf16(a[0], b, acc0[0][nfr], 0, 0, 0);
                acc0[1][nfr] = __builtin_amdgcn_mfma_f32_16x16x32_bf16(a[1], b, acc0[1][nfr], 0, 0, 0);
            }
        }
        __syncthreads(); // HG reads done (HB reused by FFN chunks)
        #pragma unroll
        for (int nfr = 0; nfr < 2; ++nfr) {
            int n = (wn * 2 + nfr) * 16 + lm;
            float bv = mb2[n];
            #pragma unroll
            for (int mf = 0; mf < 2; ++mf)
                #pragma unroll
                for (int r = 0; r < 4; ++r) {
                    int m = wm * 32 + mf * 16 + lk * 4 + r;
                    XB[m * 128 + ((n >> 3) ^ (m & 7)) * 8 + (n & 7)] = bf16s(acc0[mf][nfr][r] + bv);
                }
        }
    }
    __syncthreads(); // XB = aggr (bf16)

    // ---- LN1: x = nf + aggr ----
    float xr[16];
    float s = 0.0f, ss = 0.0f;
    {
        const float* xp = nf + rc * DD + q * 16;
        #pragma unroll
        for (int i = 0; i < 2; ++i) {
            int c = q * 2 + i, slot = c ^ (row & 7);
            uint4 v = *reinterpret_cast<const uint4*>(&XB[row * 128 + slot * 8]);
            float f[8];
            f[0] = unlo(v.x); f[1] = unhi(v.x); f[2] = unlo(v.y); f[3] = unhi(v.y);
            f[4] = unlo(v.z); f[5] = unhi(v.z); f[6] = unlo(v.w); f[7] = unhi(v.w);
            float4 a = *reinterpret_cast<const float4*>(xp + i * 8);
            float4 b = *reinterpret_cast<const float4*>(xp + i * 8 + 4);
            float vv[8] = {a.x + f[0], a.y + f[1], a.z + f[2], a.w + f[3],
                           b.x + f[4], b.y + f[5], b.z + f[6], b.w + f[7]};
            #pragma unroll
            for (int j = 0; j < 8; ++j) {
                xr[i * 8 + j] = vv[j];
                s += vv[j];
                ss = fmaf(vv[j], vv[j], ss);
            }
        }
    }
    s  += __shfl_xor(s, 1, 64);  s  += __shfl_xor(s, 2, 64);  s  += __shfl_xor(s, 4, 64);
    ss += __shfl_xor(ss, 1, 64); ss += __shfl_xor(ss, 2, 64); ss += __shfl_xor(ss, 4, 64);
    {
        float mu = s * (1.0f / DD);
        float var = ss * (1.0f / DD) - mu * mu;
        float rstd = rsqrtf(var + 1e-5f);
        #pragma unroll
        for (int i = 0; i < 4; ++i) {
            float4 gv = *reinterpret_cast<const float4*>(g1 + q * 16 + i * 4);
            float4 bv = *reinterpret_cast<const float4*>(b1 + q * 16 + i * 4);
            xr[i * 4 + 0] = (xr[i * 4 + 0] - mu) * rstd * gv.x + bv.x;
            xr[i * 4 + 1] = (xr[i * 4 + 1] - mu) * rstd * gv.y + bv.y;
            xr[i * 4 + 2] = (xr[i * 4 + 2] - mu) * rstd * gv.z + bv.z;
            xr[i * 4 + 3] = (xr[i * 4 + 3] - mu) * rstd * gv.w + bv.w;
        }
        #pragma unroll
        for (int i = 0; i < 2; ++i) {
            int c = q * 2 + i, slot = c ^ (row & 7);
            uint4 v;
            v.x = pk2(xr[i * 8 + 0], xr[i * 8 + 1]);
            v.y = pk2(xr[i * 8 + 2], xr[i * 8 + 3]);
            v.z = pk2(xr[i * 8 + 4], xr[i * 8 + 5]);
            v.w = pk2(xr[i * 8 + 6], xr[i * 8 + 7]);
            *reinterpret_cast<uint4*>(&XB[row * 128 + slot * 8]) = v;
        }
    }
    __syncthreads();

    // ---- FFN: four 128-col chunks of the 512-wide hidden ----
    f32x4 acc2[2][2];
    #pragma unroll
    for (int mf = 0; mf < 2; ++mf)
        #pragma unroll
        for (int nfr = 0; nfr < 2; ++nfr) acc2[mf][nfr] = (f32x4){0.f, 0.f, 0.f, 0.f};

    #pragma unroll
    for (int ch = 0; ch < 4; ++ch) {
        f32x4 acc[2][2];
        #pragma unroll
        for (int mf = 0; mf < 2; ++mf)
            #pragma unroll
            for (int nfr = 0; nfr < 2; ++nfr) acc[mf][nfr] = (f32x4){0.f, 0.f, 0.f, 0.f};

        // GEMM1 chunk: hidden cols ch*128 .. +128
        #pragma unroll
        for (int ks = 0; ks < 4; ++ks) {
            bf16x8 a[2];
            #pragma unroll
            for (int mf = 0; mf < 2; ++mf) {
                int m = wm * 32 + mf * 16 + lm;
                int slot = (ks * 4 + lk) ^ (m & 7);
                a[mf] = *reinterpret_cast<const bf16x8*>(&XB[m * 128 + slot * 8]);
            }
            #pragma unroll
            for (int nfr = 0; nfr < 2; ++nfr) {
                int nt = ch * 8 + wn * 2 + nfr;
                bf16x8 b = *reinterpret_cast<const bf16x8*>(&fw1p[((nt * 4 + ks) * 64 + l) * 8]);
                acc[0][nfr] = __builtin_amdgcn_mfma_f32_16x16x32_bf16(a[0], b, acc[0][nfr], 0, 0, 0);
                acc[1][nfr] = __builtin_amdgcn_mfma_f32_16x16x32_bf16(a[1], b, acc[1][nfr], 0, 0, 0);
            }
        }
        #pragma unroll
        for (int nfr = 0; nfr < 2; ++nfr) {
            int nl = (wn * 2 + nfr) * 16 + lm;   // col within chunk (0..127)
            float bv = fb1[ch * 128 + nl];
            #pragma unroll
            for (int mf = 0; mf < 2; ++mf)
                #pragma unroll
                for (int r = 0; r < 4; ++r) {
                    int m = wm * 32 + mf * 16 + lk * 4 + r;
                    float h = acc[mf][nfr][r] + bv;
                    float e = __expf(h * -1.702f);
                    float gvv = h * __builtin_amdgcn_rcpf(1.0f + e);
                    HB[m * 128 + (((nl >> 3) ^ (m & 7)) * 8) + (nl & 7)] = bf16s(gvv);
                }
        }
        __syncthreads();

        // GEMM2 partial: K chunk ch
        #pragma unroll
        for (int ks = 0; ks < 4; ++ks) {
            bf16x8 a[2];
            #pragma unroll
            for (int mf = 0; mf < 2; ++mf) {
                int m = wm * 32 + mf * 16 + lm;
                int slot = (ks * 4 + lk) ^ (m & 7);
                a[mf] = *reinterpret_cast<const bf16x8*>(&HB[m * 128 + slot * 8]);
            }
            #pragma unroll
            for (int nfr = 0; nfr < 2; ++nfr) {
                int nt = wn * 2 + nfr;
                int kg = ch * 4 + ks;
                bf16x8 b = *reinterpret_cast<const bf16x8*>(&fw2p[((nt * 16 + kg) * 64 + l) * 8]);
                acc2[0][nfr] = __builtin_amdgcn_mfma_f32_16x16x32_bf16(a[0], b, acc2[0][nfr], 0, 0, 0);
                acc2[1][nfr] = __builtin_amdgcn_mfma_f32_16x16x32_bf16(a[1], b, acc2[1][nfr], 0, 0, 0);
            }
        }
        __syncthreads();
    }

    // ---- ffn -> XB (bf16) ----
    #pragma unroll
    for (int nfr = 0; nfr < 2; ++nfr) {
        int n = (wn * 2 + nfr) * 16 + lm;
        float bv = fb2[n];
        #pragma unroll
        for (int mf = 0; mf < 2; ++mf)
            #pragma unroll
            for (int r = 0; r < 4; ++r) {
                int m = wm * 32 + mf * 16 + lk * 4 + r;
                XB[m * 128 + (((n >> 3) ^ (m & 7)) * 8) + (n & 7)] = bf16s(acc2[mf][nfr][r] + bv);
            }
    }
    __syncthreads();

    // ---- residual + LN2 ----
    float s2 = 0.0f, ss2 = 0.0f;
    #pragma unroll
    for (int i = 0; i < 2; ++i) {
        int c = q * 2 + i, slot = c ^ (row & 7);
        uint4 v = *reinterpret_cast<const uint4*>(&XB[row * 128 + slot * 8]);
        float f[8];
        f[0] = unlo(v.x); f[1] = unhi(v.x); f[2] = unlo(v.y); f[3] = unhi(v.y);
        f[4] = unlo(v.z); f[5] = unhi(v.z); f[6] = unlo(v.w); f[7] = unhi(v.w);
        #pragma unroll
        for (int j = 0; j < 8; ++j) {
            float vv = xr[i * 8 + j] + f[j];
            xr[i * 8 + j] = vv;
            s2 += vv;
            ss2 = fmaf(vv, vv, ss2);
        }
    }
    s2  += __shfl_xor(s2, 1, 64);  s2  += __shfl_xor(s2, 2, 64);  s2  += __shfl_xor(s2, 4, 64);
    ss2 += __shfl_xor(ss2, 1, 64); ss2 += __shfl_xor(ss2, 2, 64); ss2 += __shfl_xor(ss2, 4, 64);
    {
        float mu = s2 * (1.0f / DD);
        float var = ss2 * (1.0f / DD) - mu * mu;
        float rstd = rsqrtf(var + 1e-5f);
        if (rg < NN) {
            float* op = out + rg * DD + q * 16;
            #pragma unroll
            for (int i = 0; i < 4; ++i) {
                float4 gv = *reinterpret_cast<const float4*>(g2 + q * 16 + i * 4);
                float4 bv = *reinterpret_cast<const float4*>(b2 + q * 16 + i * 4);
                float4 o;
                o.x = (xr[i * 4 + 0] - mu) * rstd * gv.x + bv.x;
                o.y = (xr[i * 4 + 1] - mu) * rstd * gv.y + bv.y;
                o.z = (xr[i * 4 + 2] - mu) * rstd * gv.z + bv.z;
                o.w = (xr[i * 4 + 3] - mu) * rstd * gv.w + bv.w;
                *reinterpret_cast<float4*>(op + i * 4) = o;
            }
        }
    }
}

extern "C" void kernel_launch(void* const* d_in, const int* in_sizes, int n_in,
                              void* d_out, int out_size, void* d_ws, size_t ws_size,
                              hipStream_t stream)
{
    const float* nf  = (const float*)d_in[0];
    const int*   ei  = (const int*)d_in[1];
    const int*   et  = (const int*)d_in[2];
    const float* rel = (const float*)d_in[3];
    const float* mw1 = (const float*)d_in[4];
    const float* mb1 = (const float*)d_in[5];
    const float* mw2 = (const float*)d_in[6];
    const float* mb2 = (const float*)d_in[7];
    const float* aw1 = (const float*)d_in[8];
    const float* ab1 = (const float*)d_in[9];
    const float* aw2 = (const float*)d_in[10];
    const float* ab2 = (const float*)d_in[11];
    const float* g1  = (const float*)d_in[12];
    const float* b1  = (const float*)d_in[13];
    const float* fw1 = (const float*)d_in[14];
    const float* fb1 = (const float*)d_in[15];
    const float* fw2 = (const float*)d_in[16];
    const float* fb2 = (const float*)d_in[17];
    const float* g2  = (const float*)d_in[18];
    const float* b2  = (const float*)d_in[19];
    float* out = (float*)d_out;

    char* ws = (char*)d_ws;
    size_t off = 0;
    auto alloc = [&](size_t bytes) -> char* {
        char* p = ws + off;
        off += (bytes + 255) & ~(size_t)255;
        return p;
    };
    unsigned short* hid = (unsigned short*)alloc((size_t)NE * DD * 2);
    float* attn_raw = (float*)alloc((size_t)NE * 4);
    unsigned short* haggrb = (unsigned short*)alloc((size_t)NN * DD * 2);
    unsigned short* nfa = (unsigned short*)alloc((size_t)NN * DD * 2);
    unsigned short* nfb = (unsigned short*)alloc((size_t)NN * DD * 2);
    unsigned short* relcb = (unsigned short*)alloc((size_t)RR * DD * 2);
    float* zb  = (float*)alloc((size_t)128 * 4);
    int* cnt       = (int*)alloc((size_t)NN * 4);
    int* row_start = (int*)alloc((size_t)NN * 4);
    int* cursor    = (int*)alloc((size_t)NN * 4);
    int* srcs      = (int*)alloc((size_t)NE * 4);
    int* ets       = (int*)alloc((size_t)NE * 4);
    int* dsts      = (int*)alloc((size_t)NE * 4);
    int* bsum      = (int*)alloc((size_t)SCAN_NB * 4);
    unsigned short* mw1p = (unsigned short*)alloc(16384 * 2);
    unsigned short* mw2p = (unsigned short*)alloc(16384 * 2);
    unsigned short* awTp = (unsigned short*)alloc(16384 * 2);
    unsigned short* mwBp = (unsigned short*)alloc(16384 * 2);
    unsigned short* fw1p = (unsigned short*)alloc(65536 * 2);
    unsigned short* fw2p = (unsigned short*)alloc(65536 * 2);

    const int* srcp = ei;
    const int* dstp = ei + NE;

    hipLaunchKernelGGL(k_setup, dim3(1260), dim3(256), 0, stream,
                       mw1, mb1, mw2, mb2, aw1, rel, fw1, fw2,
                       mw1p, mw2p, awTp, mwBp, fw1p, fw2p, relcb, zb, cnt);
    hipLaunchKernelGGL(k_hist, dim3((NE + 255) / 256), dim3(256), 0, stream, dstp, cnt);
    hipLaunchKernelGGL(k_scanA, dim3(SCAN_NB), dim3(256), 0, stream, cnt, bsum);
    hipLaunchKernelGGL(k_scanB, dim3(1), dim3(512), 0, stream, bsum);
    hipLaunchKernelGGL(k_scanC, dim3(SCAN_NB), dim3(256), 0, stream, cnt, bsum, row_start, cursor);
    hipLaunchKernelGGL(k_bucket, dim3((NE + 255) / 256), dim3(256), 0, stream,
                       srcp, dstp, et, cursor, srcs, ets, dsts);
    hipLaunchKernelGGL(k_prepnfa, dim3((NN + 63) / 64), dim3(256), 0, stream,
                       nf, awTp, ab1, nfb, nfa);
    hipLaunchKernelGGL(k_edge, dim3(NE / 64), dim3(512), 0, stream,
                       nfb, srcs, dsts, ets, nfa, relcb,
                       mw1p, mwBp, zb, aw2, ab2,
                       hid, attn_raw);
    hipLaunchKernelGGL(k_aggr, dim3((NN + 3) / 4), dim3(256), 0, stream,
                       hid, attn_raw, row_start, cnt, haggrb);
    hipLaunchKernelGGL(k_node, dim3((NN + 63) / 64), dim3(512), 0, stream,
                       nf, haggrb, mw2p, mb2, g1, b1, fw1p, fb1, fw2p, fb2, g2, b2, out);
}

// Round 13
// 398.475 us; speedup vs baseline: 1.4805x; 1.0439x over previous
//
#include <hip/hip_runtime.h>
#include <hip/hip_bf16.h>
#include <hip/hip_fp8.h>

#define NN 100000
#define NE 600000
#define DD 128
#define RR 200
#define SCAN_NB ((NN + 255) / 256)   // 391

typedef __attribute__((ext_vector_type(8))) short bf16x8;
typedef __attribute__((ext_vector_type(4))) float f32x4;

__device__ __forceinline__ unsigned int bfbits(float x) {
    return (unsigned int)__builtin_bit_cast(unsigned short, __float2bfloat16(x));
}
__device__ __forceinline__ unsigned int pk2(float a, float b) {
    return bfbits(a) | (bfbits(b) << 16);
}
__device__ __forceinline__ unsigned short bf16s(float x) {
    return __builtin_bit_cast(unsigned short, __float2bfloat16(x));
}
__device__ __forceinline__ float unbf(unsigned short u) {
    return __builtin_bit_cast(float, ((unsigned int)u) << 16);
}
__device__ __forceinline__ float unlo(unsigned int u) {
    return __builtin_bit_cast(float, u << 16);
}
__device__ __forceinline__ float unhi(unsigned int u) {
    return __builtin_bit_cast(float, u & 0xffff0000u);
}
__device__ __forceinline__ unsigned char f8enc(float x) {
    __hip_fp8_e4m3 h(x);
    return (unsigned char)h.__x;
}
__device__ __forceinline__ float f8dec(unsigned char u) {
    __hip_fp8_e4m3 h;
    h.__x = u;
    return (float)h;
}

__device__ __forceinline__ void gload_lds16(const void* g, void* l) {
    __builtin_amdgcn_global_load_lds(
        (const __attribute__((address_space(1))) void*)g,
        (__attribute__((address_space(3))) void*)l, 16, 0, 0);
}

// ---------------- histogram of dst ----------------
__global__ void k_hist(const int* __restrict__ dst, int* __restrict__ cnt) {
    int e = blockIdx.x * 256 + threadIdx.x;
    if (e < NE) atomicAdd(&cnt[dst[e]], 1);
}

// ---------------- 3-kernel exclusive scan over cnt[NN] ----------------
__global__ void k_scanA(const int* __restrict__ cnt, int* __restrict__ bsum) {
    __shared__ int red[256];
    int i = blockIdx.x * 256 + threadIdx.x;
    red[threadIdx.x] = (i < NN) ? cnt[i] : 0;
    __syncthreads();
    for (int off = 128; off >= 1; off >>= 1) {
        if (threadIdx.x < off) red[threadIdx.x] += red[threadIdx.x + off];
        __syncthreads();
    }
    if (threadIdx.x == 0) bsum[blockIdx.x] = red[0];
}

__global__ void k_scanB(int* __restrict__ bsum) {
    __shared__ int sh[512];
    int t = threadIdx.x;
    int v = (t < SCAN_NB) ? bsum[t] : 0;
    sh[t] = v;
    __syncthreads();
    for (int off = 1; off < 512; off <<= 1) {
        int add = (t >= off) ? sh[t - off] : 0;
        __syncthreads();
        sh[t] += add;
        __syncthreads();
    }
    if (t < SCAN_NB) bsum[t] = sh[t] - v;   // exclusive
}

__global__ void k_scanC(const int* __restrict__ cnt, const int* __restrict__ bsum,
                        int* __restrict__ row_start, int* __restrict__ cursor) {
    __shared__ int sh[256];
    int i = blockIdx.x * 256 + threadIdx.x;
    int t = threadIdx.x;
    int v = (i < NN) ? cnt[i] : 0;
    sh[t] = v;
    __syncthreads();
    for (int off = 1; off < 256; off <<= 1) {
        int add = (t >= off) ? sh[t - off] : 0;
        __syncthreads();
        sh[t] += add;
        __syncthreads();
    }
    if (i < NN) {
        int ex = bsum[blockIdx.x] + sh[t] - v;
        row_start[i] = ex;
        cursor[i] = ex;
    }
}

// ---------------- bucket: permuted src/etype/dst grouped by dst ----------------
__global__ void k_bucket(const int* __restrict__ src, const int* __restrict__ dst,
                         const int* __restrict__ etype, int* __restrict__ cursor,
                         int* __restrict__ srcs, int* __restrict__ ets,
                         int* __restrict__ dsts) {
    int e = blockIdx.x * 256 + threadIdx.x;
    if (e < NE) {
        int d = dst[e];
        int p = atomicAdd(&cursor[d], 1);
        srcs[p] = src[e];
        ets[p]  = etype[e];
        dsts[p] = d;
    }
}

// ---------------- setup: weight packing + folds + cnt zeroing (one launch) ---
__global__ void k_setup(const float* __restrict__ mw1, const float* __restrict__ mb1,
                        const float* __restrict__ mw2, const float* __restrict__ mb2,
                        const float* __restrict__ aw1, const float* __restrict__ rel,
                        const float* __restrict__ fw1, const float* __restrict__ fw2,
                        unsigned short* __restrict__ mw1p,
                        unsigned short* __restrict__ mw2p,
                        unsigned short* __restrict__ awTp,
                        unsigned short* __restrict__ mwBp,
                        unsigned short* __restrict__ fw1p,
                        unsigned short* __restrict__ fw2p,
                        unsigned short* __restrict__ relcb,
                        float* __restrict__ zb, int* __restrict__ cnt) {
    int idx = blockIdx.x * 256 + threadIdx.x;   // 322336 total
    if (idx < 16384) {            // mw1 TOP: K=128, N=128
        int i = idx & 7, l = (idx >> 3) & 63, ks = (idx >> 9) & 3, nt = idx >> 11;
        int k = ks * 32 + (l >> 4) * 8 + i, n = nt * 16 + (l & 15);
        mw1p[idx] = bf16s(mw1[k * 128 + n]);
    } else if (idx < 32768) {     // mw2: K=128, N=128
        int j = idx - 16384;
        int i = j & 7, l = (j >> 3) & 63, ks = (j >> 9) & 3, nt = j >> 11;
        int k = ks * 32 + (l >> 4) * 8 + i, n = nt * 16 + (l & 15);
        mw2p[j] = bf16s(mw2[k * 128 + n]);
    } else if (idx < 49152) {     // aw1 TOP: K=128, N=128
        int j = idx - 32768;
        int i = j & 7, l = (j >> 3) & 63, ks = (j >> 9) & 3, nt = j >> 11;
        int k = ks * 32 + (l >> 4) * 8 + i, n = nt * 16 + (l & 15);
        awTp[j] = bf16s(aw1[k * 128 + n]);
    } else if (idx < 65536) {     // mwB = mw2 @ aw1_bot (direct dot)
        int j = idx - 49152;
        int i = j & 7, l = (j >> 3) & 63, ks = (j >> 9) & 3, nt = j >> 11;
        int k = ks * 32 + (l >> 4) * 8 + i, n = nt * 16 + (l & 15);
        float s = 0.0f;
        for (int j2 = 0; j2 < 128; ++j2)
            s = fmaf(mw2[k * 128 + j2], aw1[(128 + j2) * 128 + n], s);
        mwBp[j] = bf16s(s);
    } else if (idx < 131072) {    // fw1: K=128, N=512
        int j = idx - 65536;
        int i = j & 7, l = (j >> 3) & 63, ks = (j >> 9) & 3, nt = j >> 11;
        int k = ks * 32 + (l >> 4) * 8 + i, n = nt * 16 + (l & 15);
        fw1p[j] = bf16s(fw1[k * 512 + n]);
    } else if (idx < 196608) {    // fw2: K=512 (KS=16), N=128
        int j = idx - 131072;
        int i = j & 7, l = (j >> 3) & 63, ks = (j >> 9) & 15, nt = j >> 13;
        int k = ks * 32 + (l >> 4) * 8 + i, n = nt * 16 + (l & 15);
        fw2p[j] = bf16s(fw2[k * 128 + n]);
    } else if (idx < 222208) {    // relcb = bf16(rel @ mw1_bot + mb1)
        int j = idx - 196608;
        int r = j >> 7, n = j & 127;
        float s = mb1[n];
        for (int k = 0; k < 128; ++k)
            s = fmaf(rel[r * 128 + k], mw1[(128 + k) * 128 + n], s);
        relcb[j] = bf16s(s);
    } else if (idx < 222336) {    // zb = mb2 @ aw1_bot
        int n = idx - 222208;
        float s = 0.0f;
        for (int j2 = 0; j2 < 128; ++j2)
            s = fmaf(mb2[j2], aw1[(128 + j2) * 128 + n], s);
        zb[n] = s;
    } else if (idx < 322336) {    // zero cnt
        cnt[idx - 222336] = 0;
    }
}

// ---------------- prep+nfa fused: nfb = bf16(nf); nfa = nf @ aw1_top + ab1 ---
__global__ __launch_bounds__(256) void k_prepnfa(
    const float* __restrict__ nf, const unsigned short* __restrict__ awTp,
    const float* __restrict__ ab1,
    unsigned short* __restrict__ nfb, unsigned short* __restrict__ nfa)
{
    __shared__ alignas(16) unsigned short XB[64 * 128]; // 16 KB
    const int t = threadIdx.x;
    const int w = t >> 6, l = t & 63;
    const int wm = w >> 1, wn = w & 1;
    const int lm = l & 15, lk = l >> 4;
    const int n0 = blockIdx.x * 64;

    {
        const int row = t >> 2, seg = t & 3;
        long ng = n0 + row; if (ng >= NN) ng = NN - 1;
        const float* sp = nf + ng * DD + seg * 32;
        uint4 o[4];
        #pragma unroll
        for (int i = 0; i < 4; ++i) {
            float4 f0 = *reinterpret_cast<const float4*>(sp + i * 8);
            float4 f1 = *reinterpret_cast<const float4*>(sp + i * 8 + 4);
            o[i].x = pk2(f0.x, f0.y); o[i].y = pk2(f0.z, f0.w);
            o[i].z = pk2(f1.x, f1.y); o[i].w = pk2(f1.z, f1.w);
        }
        if (n0 + row < NN) {
            #pragma unroll
            for (int i = 0; i < 4; ++i)
                *reinterpret_cast<uint4*>(&nfb[(size_t)(n0 + row) * DD + (seg * 4 + i) * 8]) = o[i];
        }
        #pragma unroll
        for (int i = 0; i < 4; ++i) {
            int c = seg * 4 + i, slot = c ^ (row & 7);
            *reinterpret_cast<uint4*>(&XB[row * 128 + slot * 8]) = o[i];
        }
    }
    __syncthreads();

    f32x4 acc[2][4];
    #pragma unroll
    for (int mf = 0; mf < 2; ++mf)
        #pragma unroll
        for (int nfr = 0; nfr < 4; ++nfr) acc[mf][nfr] = (f32x4){0.f, 0.f, 0.f, 0.f};

    #pragma unroll
    for (int ks = 0; ks < 4; ++ks) {
        bf16x8 a[2];
        #pragma unroll
        for (int mf = 0; mf < 2; ++mf) {
            int m = wm * 32 + mf * 16 + lm;
            int slot = (ks * 4 + lk) ^ (m & 7);
            a[mf] = *reinterpret_cast<const bf16x8*>(&XB[m * 128 + slot * 8]);
        }
        #pragma unroll
        for (int nfr = 0; nfr < 4; ++nfr) {
            int nt = wn * 4 + nfr;
            bf16x8 b = *reinterpret_cast<const bf16x8*>(&awTp[((nt * 4 + ks) * 64 + l) * 8]);
            acc[0][nfr] = __builtin_amdgcn_mfma_f32_16x16x32_bf16(a[0], b, acc[0][nfr], 0, 0, 0);
            acc[1][nfr] = __builtin_amdgcn_mfma_f32_16x16x32_bf16(a[1], b, acc[1][nfr], 0, 0, 0);
        }
    }
    __syncthreads();

    #pragma unroll
    for (int nfr = 0; nfr < 4; ++nfr) {
        int n = wn * 64 + nfr * 16 + lm;
        float bv = ab1[n];
        #pragma unroll
        for (int mf = 0; mf < 2; ++mf)
            #pragma unroll
            for (int r = 0; r < 4; ++r) {
                int m = wm * 32 + mf * 16 + lk * 4 + r;
                XB[m * 128 + n] = bf16s(acc[mf][nfr][r] + bv);
            }
    }
    __syncthreads();

    #pragma unroll
    for (int j = 0; j < 4; ++j) {
        int q = j * 256 + t;
        int row = q >> 4, c16 = q & 15;
        if (n0 + row < NN)
            *reinterpret_cast<uint4*>(&nfa[(size_t)(n0 + row) * DD + c16 * 8]) =
                *reinterpret_cast<const uint4*>(&XB[row * 128 + c16 * 8]);
    }
}

// ---------------- edge kernel: GEMM1(hidden) + GEMM-z(logits) ---------------
// hidden exported as fp8 e4m3 (halves write traffic; LDS copy stays bf16).
__global__ __launch_bounds__(512) void k_edge(
    const unsigned short* __restrict__ nfb, const int* __restrict__ srcs,
    const int* __restrict__ dsts, const int* __restrict__ ets,
    const unsigned short* __restrict__ nfa, const unsigned short* __restrict__ relcb,
    const unsigned short* __restrict__ mw1p, const unsigned short* __restrict__ mwBp,
    const float* __restrict__ zb, const float* __restrict__ aw2,
    const float* __restrict__ ab2,
    unsigned char* __restrict__ hid_out, float* __restrict__ attn_raw)
{
    __shared__ alignas(16) unsigned short S[64 * 128];  // src rows, then nfa[dst]
    __shared__ alignas(16) unsigned short H[64 * 128];  // relc, then hidden
    __shared__ float RED[64][4];

    const int t = threadIdx.x;
    const int w = t >> 6, l = t & 63;
    const int wm = w >> 2, wn = w & 3;
    const int lm = l & 15, lk = l >> 4;
    const int lrow = l >> 4, lslot = l & 15;
    const int e0 = blockIdx.x * 64;

    #pragma unroll
    for (int it = 0; it < 2; ++it) {
        int rb = w * 8 + it * 4;
        int row = rb + lrow;
        int c = lslot ^ (row & 7);
        gload_lds16(nfb + (size_t)srcs[e0 + row] * DD + c * 8, &S[rb * 128]);
    }
    #pragma unroll
    for (int it = 0; it < 2; ++it) {
        int rb = w * 8 + it * 4;
        int row = rb + lrow;
        int c = lslot ^ (row & 7);
        gload_lds16(relcb + (size_t)ets[e0 + row] * DD + c * 8, &H[rb * 128]);
    }
    __syncthreads();

    // ---- GEMM1: hidden = relu(src @ mw1_top + relc), K=128; H slot RMW ----
    {
        f32x4 acc1[2][2];
        #pragma unroll
        for (int mf = 0; mf < 2; ++mf)
            #pragma unroll
            for (int nfr = 0; nfr < 2; ++nfr) acc1[mf][nfr] = (f32x4){0.f, 0.f, 0.f, 0.f};

        #pragma unroll
        for (int ks = 0; ks < 4; ++ks) {
            bf16x8 a[2];
            #pragma unroll
            for (int mf = 0; mf < 2; ++mf) {
                int m = wm * 32 + mf * 16 + lm;
                int slot = (ks * 4 + lk) ^ (m & 7);
                a[mf] = *reinterpret_cast<const bf16x8*>(&S[m * 128 + slot * 8]);
            }
            #pragma unroll
            for (int nfr = 0; nfr < 2; ++nfr) {
                int nt = wn * 2 + nfr;
                bf16x8 b = *reinterpret_cast<const bf16x8*>(&mw1p[((nt * 4 + ks) * 64 + l) * 8]);
                acc1[0][nfr] = __builtin_amdgcn_mfma_f32_16x16x32_bf16(a[0], b, acc1[0][nfr], 0, 0, 0);
                acc1[1][nfr] = __builtin_amdgcn_mfma_f32_16x16x32_bf16(a[1], b, acc1[1][nfr], 0, 0, 0);
            }
        }
        #pragma unroll
        for (int nfr = 0; nfr < 2; ++nfr) {
            int n = (wn * 2 + nfr) * 16 + lm;
            #pragma unroll
            for (int mf = 0; mf < 2; ++mf)
                #pragma unroll
                for (int r = 0; r < 4; ++r) {
                    int m = wm * 32 + mf * 16 + lk * 4 + r;
                    int sl = m * 128 + ((n >> 3) ^ (m & 7)) * 8 + (n & 7);
                    float v = acc1[mf][nfr][r] + unbf(H[sl]);
                    v = fmaxf(v, 0.0f);
                    H[sl] = bf16s(v);
                }
        }
    }
    __syncthreads(); // hidden complete; S (src) reads done

    // ---- copy hidden -> global fp8 (overlaps GEMM-z); stage S <- nfa[dsts] --
    #pragma unroll
    for (int j = 0; j < 2; ++j) {
        int q = j * 512 + t;
        int row = q >> 4, c16 = q & 15;
        int slot = c16 ^ (row & 7);
        uint4 v = *reinterpret_cast<const uint4*>(&H[row * 128 + slot * 8]);
        unsigned int lo = (unsigned int)f8enc(unlo(v.x))
                        | ((unsigned int)f8enc(unhi(v.x)) << 8)
                        | ((unsigned int)f8enc(unlo(v.y)) << 16)
                        | ((unsigned int)f8enc(unhi(v.y)) << 24);
        unsigned int hi = (unsigned int)f8enc(unlo(v.z))
                        | ((unsigned int)f8enc(unhi(v.z)) << 8)
                        | ((unsigned int)f8enc(unlo(v.w)) << 16)
                        | ((unsigned int)f8enc(unhi(v.w)) << 24);
        uint2 o = {lo, hi};
        *reinterpret_cast<uint2*>(&hid_out[(size_t)(e0 + row) * DD + c16 * 8]) = o;
    }
    #pragma unroll
    for (int it = 0; it < 2; ++it) {
        int rb = w * 8 + it * 4;
        int row = rb + lrow;
        int c = lslot ^ (row & 7);
        gload_lds16(nfa + (size_t)dsts[e0 + row] * DD + c * 8, &S[rb * 128]);
    }

    // ---- GEMM-z: zpre = hidden @ mwB, K=128, N=128 ----
    f32x4 acc[2][2];
    #pragma unroll
    for (int mf = 0; mf < 2; ++mf)
        #pragma unroll
        for (int nfr = 0; nfr < 2; ++nfr) acc[mf][nfr] = (f32x4){0.f, 0.f, 0.f, 0.f};

    #pragma unroll
    for (int ks = 0; ks < 4; ++ks) {
        bf16x8 a[2];
        #pragma unroll
        for (int mf = 0; mf < 2; ++mf) {
            int m = wm * 32 + mf * 16 + lm;
            int slot = (ks * 4 + lk) ^ (m & 7);
            a[mf] = *reinterpret_cast<const bf16x8*>(&H[m * 128 + slot * 8]);
        }
        #pragma unroll
        for (int nfr = 0; nfr < 2; ++nfr) {
            int nt = wn * 2 + nfr;
            bf16x8 b = *reinterpret_cast<const bf16x8*>(&mwBp[((nt * 4 + ks) * 64 + l) * 8]);
            acc[0][nfr] = __builtin_amdgcn_mfma_f32_16x16x32_bf16(a[0], b, acc[0][nfr], 0, 0, 0);
            acc[1][nfr] = __builtin_amdgcn_mfma_f32_16x16x32_bf16(a[1], b, acc[1][nfr], 0, 0, 0);
        }
    }
    __syncthreads(); // nfa staged into S; H reads done

    // ---- z epilogue (all 8 waves) ----
    {
        float zbv[2], aw2v[2];
        #pragma unroll
        for (int nfr = 0; nfr < 2; ++nfr) {
            int nc = (wn * 2 + nfr) * 16 + lm;
            zbv[nfr] = zb[nc];
            aw2v[nfr] = aw2[nc];
        }
        #pragma unroll
        for (int mf = 0; mf < 2; ++mf)
            #pragma unroll
            for (int r = 0; r < 4; ++r) {
                int m = wm * 32 + mf * 16 + lk * 4 + r;
                float s = 0.0f;
                #pragma unroll
                for (int nfr = 0; nfr < 2; ++nfr) {
                    int nc = (wn * 2 + nfr) * 16 + lm;
                    float v = acc[mf][nfr][r] + zbv[nfr]
                            + unbf(S[m * 128 + ((nc >> 3) ^ (m & 7)) * 8 + (nc & 7)]);
                    v = (v > 0.0f) ? v : 0.2f * v;
                    s = fmaf(v, aw2v[nfr], s);
                }
                s += __shfl_xor(s, 1, 64);
                s += __shfl_xor(s, 2, 64);
                s += __shfl_xor(s, 4, 64);
                s += __shfl_xor(s, 8, 64);
                if (lm == 0) RED[m][wn] = s;
            }
    }
    __syncthreads();

    if (t < 64) {
        attn_raw[e0 + t] = RED[t][0] + RED[t][1] + RED[t][2] + RED[t][3] + ab2[0];
    }
}

// ---------------- fused per-node softmax + hidden(fp8) aggregate ------------
__global__ __launch_bounds__(256) void k_aggr(
    const unsigned char* __restrict__ hid, const float* __restrict__ raw,
    const int* __restrict__ row_start, const int* __restrict__ cnt,
    unsigned short* __restrict__ haggrb)
{
    __shared__ float wbuf[4][64];
    const int l = threadIdx.x & 63;
    const int nib = threadIdx.x >> 6;
    const int n = blockIdx.x * 4 + nib;
    if (n >= NN) return;
    const int rs = row_start[n], deg = cnt[n];

    float m = -INFINITY;
    for (int j = l; j < deg; j += 64) m = fmaxf(m, raw[rs + j]);
    #pragma unroll
    for (int off = 32; off >= 1; off >>= 1) m = fmaxf(m, __shfl_xor(m, off, 64));

    float s = 0.0f;
    for (int j = l; j < deg; j += 64) s += expf(raw[rs + j] - m);
    #pragma unroll
    for (int off = 32; off >= 1; off >>= 1) s += __shfl_xor(s, off, 64);
    const float rinv = 1.0f / (s + 1e-8f);

    float a0 = 0.0f, a1 = 0.0f;
    for (int base = 0; base < deg; base += 64) {
        int ntc = min(64, deg - base);
        if (l < ntc) wbuf[nib][l] = expf(raw[rs + base + l] - m) * rinv;
        // wave-private LDS (wave64 lockstep): no barrier needed
        for (int j = 0; j < ntc; ++j) {
            float w = wbuf[nib][j];     // broadcast read
            unsigned short v = *reinterpret_cast<const unsigned short*>(
                &hid[(size_t)(rs + base + j) * DD + l * 2]);
            a0 = fmaf(w, f8dec((unsigned char)(v & 0xff)), a0);
            a1 = fmaf(w, f8dec((unsigned char)(v >> 8)), a1);
        }
    }
    *reinterpret_cast<unsigned int*>(&haggrb[(size_t)n * DD + l * 2]) = pk2(a0, a1);
}

// ---------------- node kernel: GEMM0(mw2) + LN1 + FFN(4 chunks) + LN2 -------
__global__ __launch_bounds__(512) void k_node(
    const float* __restrict__ nf, const unsigned short* __restrict__ haggrb,
    const unsigned short* __restrict__ mw2p, const float* __restrict__ mb2,
    const float* __restrict__ g1, const float* __restrict__ b1,
    const unsigned short* __restrict__ fw1p, const float* __restrict__ fb1,
    const unsigned short* __restrict__ fw2p, const float* __restrict__ fb2,
    const float* __restrict__ g2, const float* __restrict__ b2,
    float* __restrict__ out)
{
    __shared__ alignas(16) unsigned short XB[64 * 128]; // 16 KB
    __shared__ alignas(16) unsigned short HB[64 * 128]; // 16 KB (also HG staging)

    const int t = threadIdx.x;
    const int w = t >> 6, l = t & 63;
    const int wm = w >> 2, wn = w & 3;
    const int lm = l & 15, lk = l >> 4;
    const int lrow = l >> 4, lslot = l & 15;
    const int row = t >> 3;      // 0..63
    const int q = t & 7;         // 16-col segment
    const long n0 = (long)blockIdx.x * 64;
    const long rg = n0 + row;
    const long rc = (rg < NN) ? rg : (NN - 1);

    // ---- stage HG <- haggrb (swizzled src) ----
    unsigned short* HG = HB;
    #pragma unroll
    for (int it = 0; it < 2; ++it) {
        int rb = w * 8 + it * 4;
        int rr = rb + lrow;
        long grow = n0 + rr; if (grow >= NN) grow = NN - 1;
        int c = lslot ^ (rr & 7);
        gload_lds16(haggrb + grow * DD + c * 8, &HG[rb * 128]);
    }
    __syncthreads();

    // ---- GEMM0: aggr = haggr @ mw2 + mb2 -> XB (bf16, swizzled) ----
    {
        f32x4 acc0[2][2];
        #pragma unroll
        for (int mf = 0; mf < 2; ++mf)
            #pragma unroll
            for (int nfr = 0; nfr < 2; ++nfr) acc0[mf][nfr] = (f32x4){0.f, 0.f, 0.f, 0.f};

        #pragma unroll
        for (int ks = 0; ks < 4; ++ks) {
            bf16x8 a[2];
            #pragma unroll
            for (int mf = 0; mf < 2; ++mf) {
                int m = wm * 32 + mf * 16 + lm;
                int slot = (ks * 4 + lk) ^ (m & 7);
                a[mf] = *reinterpret_cast<const bf16x8*>(&HG[m * 128 + slot * 8]);
            }
            #pragma unroll
            for (int nfr = 0; nfr < 2; ++nfr) {
                int nt = wn * 2 + nfr;
                bf16x8 b = *reinterpret_cast<const bf16x8*>(&mw2p[((nt * 4 + ks) * 64 + l) * 8]);
                acc0[0][nfr] = __builtin_amdgcn_mfma_f32_16x16x32_bf16(a[0], b, acc0[0][nfr], 0, 0, 0);
                acc0[1][nfr] = __builtin_amdgcn_mfma_f32_16x16x32_bf16(a[1], b, acc0[1][nfr], 0, 0, 0);
            }
        }
        __syncthreads(); // HG reads done (HB reused by FFN chunks)
        #pragma unroll
        for (int nfr = 0; nfr < 2; ++nfr) {
            int n = (wn * 2 + nfr) * 16 + lm;
            float bv = mb2[n];
            #pragma unroll
            for (int mf = 0; mf < 2; ++mf)
                #pragma unroll
                for (int r = 0; r < 4; ++r) {
                    int m = wm * 32 + mf * 16 + lk * 4 + r;
                    XB[m * 128 + ((n >> 3) ^ (m & 7)) * 8 + (n & 7)] = bf16s(acc0[mf][nfr][r] + bv);
                }
        }
    }
    __syncthreads(); // XB = aggr (bf16)

    // ---- LN1: x = nf + aggr ----
    float xr[16];
    float s = 0.0f, ss = 0.0f;
    {
        const float* xp = nf + rc * DD + q * 16;
        #pragma unroll
        for (int i = 0; i < 2; ++i) {
            int c = q * 2 + i, slot = c ^ (row & 7);
            uint4 v = *reinterpret_cast<const uint4*>(&XB[row * 128 + slot * 8]);
            float f[8];
            f[0] = unlo(v.x); f[1] = unhi(v.x); f[2] = unlo(v.y); f[3] = unhi(v.y);
            f[4] = unlo(v.z); f[5] = unhi(v.z); f[6] = unlo(v.w); f[7] = unhi(v.w);
            float4 a = *reinterpret_cast<const float4*>(xp + i * 8);
            float4 b = *reinterpret_cast<const float4*>(xp + i * 8 + 4);
            float vv[8] = {a.x + f[0], a.y + f[1], a.z + f[2], a.w + f[3],
                           b.x + f[4], b.y + f[5], b.z + f[6], b.w + f[7]};
            #pragma unroll
            for (int j = 0; j < 8; ++j) {
                xr[i * 8 + j] = vv[j];
                s += vv[j];
                ss = fmaf(vv[j], vv[j], ss);
            }
        }
    }
    s  += __shfl_xor(s, 1, 64);  s  += __shfl_xor(s, 2, 64);  s  += __shfl_xor(s, 4, 64);
    ss += __shfl_xor(ss, 1, 64); ss += __shfl_xor(ss, 2, 64); ss += __shfl_xor(ss, 4, 64);
    {
        float mu = s * (1.0f / DD);
        float var = ss * (1.0f / DD) - mu * mu;
        float rstd = rsqrtf(var + 1e-5f);
        #pragma unroll
        for (int i = 0; i < 4; ++i) {
            float4 gv = *reinterpret_cast<const float4*>(g1 + q * 16 + i * 4);
            float4 bv = *reinterpret_cast<const float4*>(b1 + q * 16 + i * 4);
            xr[i * 4 + 0] = (xr[i * 4 + 0] - mu) * rstd * gv.x + bv.x;
            xr[i * 4 + 1] = (xr[i * 4 + 1] - mu) * rstd * gv.y + bv.y;
            xr[i * 4 + 2] = (xr[i * 4 + 2] - mu) * rstd * gv.z + bv.z;
            xr[i * 4 + 3] = (xr[i * 4 + 3] - mu) * rstd * gv.w + bv.w;
        }
        #pragma unroll
        for (int i = 0; i < 2; ++i) {
            int c = q * 2 + i, slot = c ^ (row & 7);
            uint4 v;
            v.x = pk2(xr[i * 8 + 0], xr[i * 8 + 1]);
            v.y = pk2(xr[i * 8 + 2], xr[i * 8 + 3]);
            v.z = pk2(xr[i * 8 + 4], xr[i * 8 + 5]);
            v.w = pk2(xr[i * 8 + 6], xr[i * 8 + 7]);
            *reinterpret_cast<uint4*>(&XB[row * 128 + slot * 8]) = v;
        }
    }
    __syncthreads();

    // ---- FFN: four 128-col chunks of the 512-wide hidden ----
    f32x4 acc2[2][2];
    #pragma unroll
    for (int mf = 0; mf < 2; ++mf)
        #pragma unroll
        for (int nfr = 0; nfr < 2; ++nfr) acc2[mf][nfr] = (f32x4){0.f, 0.f, 0.f, 0.f};

    #pragma unroll
    for (int ch = 0; ch < 4; ++ch) {
        f32x4 acc[2][2];
        #pragma unroll
        for (int mf = 0; mf < 2; ++mf)
            #pragma unroll
            for (int nfr = 0; nfr < 2; ++nfr) acc[mf][nfr] = (f32x4){0.f, 0.f, 0.f, 0.f};

        #pragma unroll
        for (int ks = 0; ks < 4; ++ks) {
            bf16x8 a[2];
            #pragma unroll
            for (int mf = 0; mf < 2; ++mf) {
                int m = wm * 32 + mf * 16 + lm;
                int slot = (ks * 4 + lk) ^ (m & 7);
                a[mf] = *reinterpret_cast<const bf16x8*>(&XB[m * 128 + slot * 8]);
            }
            #pragma unroll
            for (int nfr = 0; nfr < 2; ++nfr) {
                int nt = ch * 8 + wn * 2 + nfr;
                bf16x8 b = *reinterpret_cast<const bf16x8*>(&fw1p[((nt * 4 + ks) * 64 + l) * 8]);
                acc[0][nfr] = __builtin_amdgcn_mfma_f32_16x16x32_bf16(a[0], b, acc[0][nfr], 0, 0, 0);
                acc[1][nfr] = __builtin_amdgcn_mfma_f32_16x16x32_bf16(a[1], b, acc[1][nfr], 0, 0, 0);
            }
        }
        #pragma unroll
        for (int nfr = 0; nfr < 2; ++nfr) {
            int nl = (wn * 2 + nfr) * 16 + lm;
            float bv = fb1[ch * 128 + nl];
            #pragma unroll
            for (int mf = 0; mf < 2; ++mf)
                #pragma unroll
                for (int r = 0; r < 4; ++r) {
                    int m = wm * 32 + mf * 16 + lk * 4 + r;
                    float h = acc[mf][nfr][r] + bv;
                    float e = __expf(h * -1.702f);
                    float gvv = h * __builtin_amdgcn_rcpf(1.0f + e);
                    HB[m * 128 + (((nl >> 3) ^ (m & 7)) * 8) + (nl & 7)] = bf16s(gvv);
                }
        }
        __syncthreads();

        #pragma unroll
        for (int ks = 0; ks < 4; ++ks) {
            bf16x8 a[2];
            #pragma unroll
            for (int mf = 0; mf < 2; ++mf) {
                int m = wm * 32 + mf * 16 + lm;
                int slot = (ks * 4 + lk) ^ (m & 7);
                a[mf] = *reinterpret_cast<const bf16x8*>(&HB[m * 128 + slot * 8]);
            }
            #pragma unroll
            for (int nfr = 0; nfr < 2; ++nfr) {
                int nt = wn * 2 + nfr;
                int kg = ch * 4 + ks;
                bf16x8 b = *reinterpret_cast<const bf16x8*>(&fw2p[((nt * 16 + kg) * 64 + l) * 8]);
                acc2[0][nfr] = __builtin_amdgcn_mfma_f32_16x16x32_bf16(a[0], b, acc2[0][nfr], 0, 0, 0);
                acc2[1][nfr] = __builtin_amdgcn_mfma_f32_16x16x32_bf16(a[1], b, acc2[1][nfr], 0, 0, 0);
            }
        }
        __syncthreads();
    }

    // ---- ffn -> XB (bf16) ----
    #pragma unroll
    for (int nfr = 0; nfr < 2; ++nfr) {
        int n = (wn * 2 + nfr) * 16 + lm;
        float bv = fb2[n];
        #pragma unroll
        for (int mf = 0; mf < 2; ++mf)
            #pragma unroll
            for (int r = 0; r < 4; ++r) {
                int m = wm * 32 + mf * 16 + lk * 4 + r;
                XB[m * 128 + (((n >> 3) ^ (m & 7)) * 8) + (n & 7)] = bf16s(acc2[mf][nfr][r] + bv);
            }
    }
    __syncthreads();

    // ---- residual + LN2 ----
    float s2 = 0.0f, ss2 = 0.0f;
    #pragma unroll
    for (int i = 0; i < 2; ++i) {
        int c = q * 2 + i, slot = c ^ (row & 7);
        uint4 v = *reinterpret_cast<const uint4*>(&XB[row * 128 + slot * 8]);
        float f[8];
        f[0] = unlo(v.x); f[1] = unhi(v.x); f[2] = unlo(v.y); f[3] = unhi(v.y);
        f[4] = unlo(v.z); f[5] = unhi(v.z); f[6] = unlo(v.w); f[7] = unhi(v.w);
        #pragma unroll
        for (int j = 0; j < 8; ++j) {
            float vv = xr[i * 8 + j] + f[j];
            xr[i * 8 + j] = vv;
            s2 += vv;
            ss2 = fmaf(vv, vv, ss2);
        }
    }
    s2  += __shfl_xor(s2, 1, 64);  s2  += __shfl_xor(s2, 2, 64);  s2  += __shfl_xor(s2, 4, 64);
    ss2 += __shfl_xor(ss2, 1, 64); ss2 += __shfl_xor(ss2, 2, 64); ss2 += __shfl_xor(ss2, 4, 64);
    {
        float mu = s2 * (1.0f / DD);
        float var = ss2 * (1.0f / DD) - mu * mu;
        float rstd = rsqrtf(var + 1e-5f);
        if (rg < NN) {
            float* op = out + rg * DD + q * 16;
            #pragma unroll
            for (int i = 0; i < 4; ++i) {
                float4 gv = *reinterpret_cast<const float4*>(g2 + q * 16 + i * 4);
                float4 bv = *reinterpret_cast<const float4*>(b2 + q * 16 + i * 4);
                float4 o;
                o.x = (xr[i * 4 + 0] - mu) * rstd * gv.x + bv.x;
                o.y = (xr[i * 4 + 1] - mu) * rstd * gv.y + bv.y;
                o.z = (xr[i * 4 + 2] - mu) * rstd * gv.z + bv.z;
                o.w = (xr[i * 4 + 3] - mu) * rstd * gv.w + bv.w;
                *reinterpret_cast<float4*>(op + i * 4) = o;
            }
        }
    }
}

extern "C" void kernel_launch(void* const* d_in, const int* in_sizes, int n_in,
                              void* d_out, int out_size, void* d_ws, size_t ws_size,
                              hipStream_t stream)
{
    const float* nf  = (const float*)d_in[0];
    const int*   ei  = (const int*)d_in[1];
    const int*   et  = (const int*)d_in[2];
    const float* rel = (const float*)d_in[3];
    const float* mw1 = (const float*)d_in[4];
    const float* mb1 = (const float*)d_in[5];
    const float* mw2 = (const float*)d_in[6];
    const float* mb2 = (const float*)d_in[7];
    const float* aw1 = (const float*)d_in[8];
    const float* ab1 = (const float*)d_in[9];
    const float* aw2 = (const float*)d_in[10];
    const float* ab2 = (const float*)d_in[11];
    const float* g1  = (const float*)d_in[12];
    const float* b1  = (const float*)d_in[13];
    const float* fw1 = (const float*)d_in[14];
    const float* fb1 = (const float*)d_in[15];
    const float* fw2 = (const float*)d_in[16];
    const float* fb2 = (const float*)d_in[17];
    const float* g2  = (const float*)d_in[18];
    const float* b2  = (const float*)d_in[19];
    float* out = (float*)d_out;

    char* ws = (char*)d_ws;
    size_t off = 0;
    auto alloc = [&](size_t bytes) -> char* {
        char* p = ws + off;
        off += (bytes + 255) & ~(size_t)255;
        return p;
    };
    unsigned char* hid = (unsigned char*)alloc((size_t)NE * DD);
    float* attn_raw = (float*)alloc((size_t)NE * 4);
    unsigned short* haggrb = (unsigned short*)alloc((size_t)NN * DD * 2);
    unsigned short* nfa = (unsigned short*)alloc((size_t)NN * DD * 2);
    unsigned short* nfb = (unsigned short*)alloc((size_t)NN * DD * 2);
    unsigned short* relcb = (unsigned short*)alloc((size_t)RR * DD * 2);
    float* zb  = (float*)alloc((size_t)128 * 4);
    int* cnt       = (int*)alloc((size_t)NN * 4);
    int* row_start = (int*)alloc((size_t)NN * 4);
    int* cursor    = (int*)alloc((size_t)NN * 4);
    int* srcs      = (int*)alloc((size_t)NE * 4);
    int* ets       = (int*)alloc((size_t)NE * 4);
    int* dsts      = (int*)alloc((size_t)NE * 4);
    int* bsum      = (int*)alloc((size_t)SCAN_NB * 4);
    unsigned short* mw1p = (unsigned short*)alloc(16384 * 2);
    unsigned short* mw2p = (unsigned short*)alloc(16384 * 2);
    unsigned short* awTp = (unsigned short*)alloc(16384 * 2);
    unsigned short* mwBp = (unsigned short*)alloc(16384 * 2);
    unsigned short* fw1p = (unsigned short*)alloc(65536 * 2);
    unsigned short* fw2p = (unsigned short*)alloc(65536 * 2);

    const int* srcp = ei;
    const int* dstp = ei + NE;

    hipLaunchKernelGGL(k_setup, dim3(1260), dim3(256), 0, stream,
                       mw1, mb1, mw2, mb2, aw1, rel, fw1, fw2,
                       mw1p, mw2p, awTp, mwBp, fw1p, fw2p, relcb, zb, cnt);
    hipLaunchKernelGGL(k_hist, dim3((NE + 255) / 256), dim3(256), 0, stream, dstp, cnt);
    hipLaunchKernelGGL(k_scanA, dim3(SCAN_NB), dim3(256), 0, stream, cnt, bsum);
    hipLaunchKernelGGL(k_scanB, dim3(1), dim3(512), 0, stream, bsum);
    hipLaunchKernelGGL(k_scanC, dim3(SCAN_NB), dim3(256), 0, stream, cnt, bsum, row_start, cursor);
    hipLaunchKernelGGL(k_bucket, dim3((NE + 255) / 256), dim3(256), 0, stream,
                       srcp, dstp, et, cursor, srcs, ets, dsts);
    hipLaunchKernelGGL(k_prepnfa, dim3((NN + 63) / 64), dim3(256), 0, stream,
                       nf, awTp, ab1, nfb, nfa);
    hipLaunchKernelGGL(k_edge, dim3(NE / 64), dim3(512), 0, stream,
                       nfb, srcs, dsts, ets, nfa, relcb,
                       mw1p, mwBp, zb, aw2, ab2,
                       hid, attn_raw);
    hipLaunchKernelGGL(k_aggr, dim3((NN + 3) / 4), dim3(256), 0, stream,
                       hid, attn_raw, row_start, cnt, haggrb);
    hipLaunchKernelGGL(k_node, dim3((NN + 63) / 64), dim3(512), 0, stream,
                       nf, haggrb, mw2p, mb2, g1, b1, fw1p, fb1, fw2p, fb2, g2, b2, out);
}

// Round 15
// 396.330 us; speedup vs baseline: 1.4885x; 1.0054x over previous
//
#include <hip/hip_runtime.h>
#include <hip/hip_bf16.h>

#define NN 100000
#define NE 600000
#define DD 128
#define RR 200
#define SCAN_NB ((NN + 255) / 256)   // 391

typedef __attribute__((ext_vector_type(8))) short bf16x8;
typedef __attribute__((ext_vector_type(4))) float f32x4;
typedef __attribute__((ext_vector_type(2))) float f32x2;

__device__ __forceinline__ unsigned int bfbits(float x) {
    return (unsigned int)__builtin_bit_cast(unsigned short, __float2bfloat16(x));
}
__device__ __forceinline__ unsigned int pk2(float a, float b) {
    return bfbits(a) | (bfbits(b) << 16);
}
__device__ __forceinline__ unsigned short bf16s(float x) {
    return __builtin_bit_cast(unsigned short, __float2bfloat16(x));
}
__device__ __forceinline__ float unbf(unsigned short u) {
    return __builtin_bit_cast(float, ((unsigned int)u) << 16);
}
__device__ __forceinline__ float unlo(unsigned int u) {
    return __builtin_bit_cast(float, u << 16);
}
__device__ __forceinline__ float unhi(unsigned int u) {
    return __builtin_bit_cast(float, u & 0xffff0000u);
}

// ---- fp8 e4m3 codec for NON-NEGATIVE values (post-relu hidden) ----
// encode: RNE; x >= 0, x < 448. Normal path for x >= 2^-6, exact denormal RNE below.
__device__ __forceinline__ unsigned int f8e(float x) {
    unsigned int u = __float_as_uint(x);
    unsigned int r = u + 0x7FFFFu + ((u >> 20) & 1u);
    int n = (int)(r >> 20) - 960;            // (exp<<3)|mant for normals
    int d = (int)rintf(x * 512.0f);          // denormal: round(x * 2^9)
    if (d > 7) d = 7;
    return (unsigned int)((n >= 8) ? n : d) & 0xFFu;
}
__device__ __forceinline__ unsigned int f8enc4(float a, float b, float c, float d) {
    return f8e(a) | (f8e(b) << 8) | (f8e(c) << 16) | (f8e(d) << 24);
}
// decode (values >= 0): normals bits = (f8<<20)+0x3C000000; denormals f8 * 2^-9
__device__ __forceinline__ float f8d(unsigned int f8) {
    float nrm = __uint_as_float((f8 << 20) + 0x3C000000u);
    float den = (float)(int)f8 * 0.001953125f;
    return (f8 & 0x78u) ? nrm : den;
}
__device__ __forceinline__ f32x2 f8dec2(unsigned short v) {
    f32x2 r;
    r.x = f8d((unsigned int)(v & 0xFFu));
    r.y = f8d((unsigned int)(v >> 8));
    return r;
}

__device__ __forceinline__ void gload_lds16(const void* g, void* l) {
    __builtin_amdgcn_global_load_lds(
        (const __attribute__((address_space(1))) void*)g,
        (__attribute__((address_space(3))) void*)l, 16, 0, 0);
}

// ---------------- histogram of dst ----------------
__global__ void k_hist(const int* __restrict__ dst, int* __restrict__ cnt) {
    int e = blockIdx.x * 256 + threadIdx.x;
    if (e < NE) atomicAdd(&cnt[dst[e]], 1);
}

// ---------------- 3-kernel exclusive scan over cnt[NN] ----------------
__global__ void k_scanA(const int* __restrict__ cnt, int* __restrict__ bsum) {
    __shared__ int red[256];
    int i = blockIdx.x * 256 + threadIdx.x;
    red[threadIdx.x] = (i < NN) ? cnt[i] : 0;
    __syncthreads();
    for (int off = 128; off >= 1; off >>= 1) {
        if (threadIdx.x < off) red[threadIdx.x] += red[threadIdx.x + off];
        __syncthreads();
    }
    if (threadIdx.x == 0) bsum[blockIdx.x] = red[0];
}

__global__ void k_scanB(int* __restrict__ bsum) {
    __shared__ int sh[512];
    int t = threadIdx.x;
    int v = (t < SCAN_NB) ? bsum[t] : 0;
    sh[t] = v;
    __syncthreads();
    for (int off = 1; off < 512; off <<= 1) {
        int add = (t >= off) ? sh[t - off] : 0;
        __syncthreads();
        sh[t] += add;
        __syncthreads();
    }
    if (t < SCAN_NB) bsum[t] = sh[t] - v;   // exclusive
}

__global__ void k_scanC(const int* __restrict__ cnt, const int* __restrict__ bsum,
                        int* __restrict__ row_start, int* __restrict__ cursor) {
    __shared__ int sh[256];
    int i = blockIdx.x * 256 + threadIdx.x;
    int t = threadIdx.x;
    int v = (i < NN) ? cnt[i] : 0;
    sh[t] = v;
    __syncthreads();
    for (int off = 1; off < 256; off <<= 1) {
        int add = (t >= off) ? sh[t - off] : 0;
        __syncthreads();
        sh[t] += add;
        __syncthreads();
    }
    if (i < NN) {
        int ex = bsum[blockIdx.x] + sh[t] - v;
        row_start[i] = ex;
        cursor[i] = ex;
    }
}

// ---------------- bucket: permuted src/etype/dst grouped by dst ----------------
__global__ void k_bucket(const int* __restrict__ src, const int* __restrict__ dst,
                         const int* __restrict__ etype, int* __restrict__ cursor,
                         int* __restrict__ srcs, int* __restrict__ ets,
                         int* __restrict__ dsts) {
    int e = blockIdx.x * 256 + threadIdx.x;
    if (e < NE) {
        int d = dst[e];
        int p = atomicAdd(&cursor[d], 1);
        srcs[p] = src[e];
        ets[p]  = etype[e];
        dsts[p] = d;
    }
}

// ---------------- setup: weight packing + folds + cnt zeroing (one launch) ---
__global__ void k_setup(const float* __restrict__ mw1, const float* __restrict__ mb1,
                        const float* __restrict__ mw2, const float* __restrict__ mb2,
                        const float* __restrict__ aw1, const float* __restrict__ rel,
                        const float* __restrict__ fw1, const float* __restrict__ fw2,
                        unsigned short* __restrict__ mw1p,
                        unsigned short* __restrict__ mw2p,
                        unsigned short* __restrict__ awTp,
                        unsigned short* __restrict__ mwBp,
                        unsigned short* __restrict__ fw1p,
                        unsigned short* __restrict__ fw2p,
                        unsigned short* __restrict__ relcb,
                        float* __restrict__ zb, int* __restrict__ cnt) {
    int idx = blockIdx.x * 256 + threadIdx.x;   // 322336 total
    if (idx < 16384) {            // mw1 TOP: K=128, N=128
        int i = idx & 7, l = (idx >> 3) & 63, ks = (idx >> 9) & 3, nt = idx >> 11;
        int k = ks * 32 + (l >> 4) * 8 + i, n = nt * 16 + (l & 15);
        mw1p[idx] = bf16s(mw1[k * 128 + n]);
    } else if (idx < 32768) {     // mw2: K=128, N=128
        int j = idx - 16384;
        int i = j & 7, l = (j >> 3) & 63, ks = (j >> 9) & 3, nt = j >> 11;
        int k = ks * 32 + (l >> 4) * 8 + i, n = nt * 16 + (l & 15);
        mw2p[j] = bf16s(mw2[k * 128 + n]);
    } else if (idx < 49152) {     // aw1 TOP: K=128, N=128
        int j = idx - 32768;
        int i = j & 7, l = (j >> 3) & 63, ks = (j >> 9) & 3, nt = j >> 11;
        int k = ks * 32 + (l >> 4) * 8 + i, n = nt * 16 + (l & 15);
        awTp[j] = bf16s(aw1[k * 128 + n]);
    } else if (idx < 65536) {     // mwB = mw2 @ aw1_bot (direct dot)
        int j = idx - 49152;
        int i = j & 7, l = (j >> 3) & 63, ks = (j >> 9) & 3, nt = j >> 11;
        int k = ks * 32 + (l >> 4) * 8 + i, n = nt * 16 + (l & 15);
        float s = 0.0f;
        for (int j2 = 0; j2 < 128; ++j2)
            s = fmaf(mw2[k * 128 + j2], aw1[(128 + j2) * 128 + n], s);
        mwBp[j] = bf16s(s);
    } else if (idx < 131072) {    // fw1: K=128, N=512
        int j = idx - 65536;
        int i = j & 7, l = (j >> 3) & 63, ks = (j >> 9) & 3, nt = j >> 11;
        int k = ks * 32 + (l >> 4) * 8 + i, n = nt * 16 + (l & 15);
        fw1p[j] = bf16s(fw1[k * 512 + n]);
    } else if (idx < 196608) {    // fw2: K=512 (KS=16), N=128
        int j = idx - 131072;
        int i = j & 7, l = (j >> 3) & 63, ks = (j >> 9) & 15, nt = j >> 13;
        int k = ks * 32 + (l >> 4) * 8 + i, n = nt * 16 + (l & 15);
        fw2p[j] = bf16s(fw2[k * 128 + n]);
    } else if (idx < 222208) {    // relcb = bf16(rel @ mw1_bot + mb1)
        int j = idx - 196608;
        int r = j >> 7, n = j & 127;
        float s = mb1[n];
        for (int k = 0; k < 128; ++k)
            s = fmaf(rel[r * 128 + k], mw1[(128 + k) * 128 + n], s);
        relcb[j] = bf16s(s);
    } else if (idx < 222336) {    // zb = mb2 @ aw1_bot
        int n = idx - 222208;
        float s = 0.0f;
        for (int j2 = 0; j2 < 128; ++j2)
            s = fmaf(mb2[j2], aw1[(128 + j2) * 128 + n], s);
        zb[n] = s;
    } else if (idx < 322336) {    // zero cnt
        cnt[idx - 222336] = 0;
    }
}

// ---------------- prep+nfa fused: nfb = bf16(nf); nfa = nf @ aw1_top + ab1 ---
__global__ __launch_bounds__(256) void k_prepnfa(
    const float* __restrict__ nf, const unsigned short* __restrict__ awTp,
    const float* __restrict__ ab1,
    unsigned short* __restrict__ nfb, unsigned short* __restrict__ nfa)
{
    __shared__ alignas(16) unsigned short XB[64 * 128]; // 16 KB
    const int t = threadIdx.x;
    const int w = t >> 6, l = t & 63;
    const int wm = w >> 1, wn = w & 1;
    const int lm = l & 15, lk = l >> 4;
    const int n0 = blockIdx.x * 64;

    {
        const int row = t >> 2, seg = t & 3;
        long ng = n0 + row; if (ng >= NN) ng = NN - 1;
        const float* sp = nf + ng * DD + seg * 32;
        uint4 o[4];
        #pragma unroll
        for (int i = 0; i < 4; ++i) {
            float4 f0 = *reinterpret_cast<const float4*>(sp + i * 8);
            float4 f1 = *reinterpret_cast<const float4*>(sp + i * 8 + 4);
            o[i].x = pk2(f0.x, f0.y); o[i].y = pk2(f0.z, f0.w);
            o[i].z = pk2(f1.x, f1.y); o[i].w = pk2(f1.z, f1.w);
        }
        if (n0 + row < NN) {
            #pragma unroll
            for (int i = 0; i < 4; ++i)
                *reinterpret_cast<uint4*>(&nfb[(size_t)(n0 + row) * DD + (seg * 4 + i) * 8]) = o[i];
        }
        #pragma unroll
        for (int i = 0; i < 4; ++i) {
            int c = seg * 4 + i, slot = c ^ (row & 7);
            *reinterpret_cast<uint4*>(&XB[row * 128 + slot * 8]) = o[i];
        }
    }
    __syncthreads();

    f32x4 acc[2][4];
    #pragma unroll
    for (int mf = 0; mf < 2; ++mf)
        #pragma unroll
        for (int nfr = 0; nfr < 4; ++nfr) acc[mf][nfr] = (f32x4){0.f, 0.f, 0.f, 0.f};

    #pragma unroll
    for (int ks = 0; ks < 4; ++ks) {
        bf16x8 a[2];
        #pragma unroll
        for (int mf = 0; mf < 2; ++mf) {
            int m = wm * 32 + mf * 16 + lm;
            int slot = (ks * 4 + lk) ^ (m & 7);
            a[mf] = *reinterpret_cast<const bf16x8*>(&XB[m * 128 + slot * 8]);
        }
        #pragma unroll
        for (int nfr = 0; nfr < 4; ++nfr) {
            int nt = wn * 4 + nfr;
            bf16x8 b = *reinterpret_cast<const bf16x8*>(&awTp[((nt * 4 + ks) * 64 + l) * 8]);
            acc[0][nfr] = __builtin_amdgcn_mfma_f32_16x16x32_bf16(a[0], b, acc[0][nfr], 0, 0, 0);
            acc[1][nfr] = __builtin_amdgcn_mfma_f32_16x16x32_bf16(a[1], b, acc[1][nfr], 0, 0, 0);
        }
    }
    __syncthreads();

    #pragma unroll
    for (int nfr = 0; nfr < 4; ++nfr) {
        int n = wn * 64 + nfr * 16 + lm;
        float bv = ab1[n];
        #pragma unroll
        for (int mf = 0; mf < 2; ++mf)
            #pragma unroll
            for (int r = 0; r < 4; ++r) {
                int m = wm * 32 + mf * 16 + lk * 4 + r;
                XB[m * 128 + n] = bf16s(acc[mf][nfr][r] + bv);
            }
    }
    __syncthreads();

    #pragma unroll
    for (int j = 0; j < 4; ++j) {
        int q = j * 256 + t;
        int row = q >> 4, c16 = q & 15;
        if (n0 + row < NN)
            *reinterpret_cast<uint4*>(&nfa[(size_t)(n0 + row) * DD + c16 * 8]) =
                *reinterpret_cast<const uint4*>(&XB[row * 128 + c16 * 8]);
    }
}

// ---------------- edge kernel: GEMM1(hidden) + GEMM-z(logits) ---------------
__global__ __launch_bounds__(512) void k_edge(
    const unsigned short* __restrict__ nfb, const int* __restrict__ srcs,
    const int* __restrict__ dsts, const int* __restrict__ ets,
    const unsigned short* __restrict__ nfa, const unsigned short* __restrict__ relcb,
    const unsigned short* __restrict__ mw1p, const unsigned short* __restrict__ mwBp,
    const float* __restrict__ zb, const float* __restrict__ aw2,
    const float* __restrict__ ab2,
    unsigned char* __restrict__ hid_out, float* __restrict__ attn_raw)
{
    __shared__ alignas(16) unsigned short S[64 * 128];  // src rows, then nfa[dst]
    __shared__ alignas(16) unsigned short H[64 * 128];  // relc, then hidden
    __shared__ float RED[64][4];

    const int t = threadIdx.x;
    const int w = t >> 6, l = t & 63;
    const int wm = w >> 2, wn = w & 3;
    const int lm = l & 15, lk = l >> 4;
    const int lrow = l >> 4, lslot = l & 15;
    const int e0 = blockIdx.x * 64;

    #pragma unroll
    for (int it = 0; it < 2; ++it) {
        int rb = w * 8 + it * 4;
        int row = rb + lrow;
        int c = lslot ^ (row & 7);
        gload_lds16(nfb + (size_t)srcs[e0 + row] * DD + c * 8, &S[rb * 128]);
    }
    #pragma unroll
    for (int it = 0; it < 2; ++it) {
        int rb = w * 8 + it * 4;
        int row = rb + lrow;
        int c = lslot ^ (row & 7);
        gload_lds16(relcb + (size_t)ets[e0 + row] * DD + c * 8, &H[rb * 128]);
    }
    __syncthreads();

    // ---- GEMM1: hidden = relu(src @ mw1_top + relc), K=128; H slot RMW ----
    {
        f32x4 acc1[2][2];
        #pragma unroll
        for (int mf = 0; mf < 2; ++mf)
            #pragma unroll
            for (int nfr = 0; nfr < 2; ++nfr) acc1[mf][nfr] = (f32x4){0.f, 0.f, 0.f, 0.f};

        #pragma unroll
        for (int ks = 0; ks < 4; ++ks) {
            bf16x8 a[2];
            #pragma unroll
            for (int mf = 0; mf < 2; ++mf) {
                int m = wm * 32 + mf * 16 + lm;
                int slot = (ks * 4 + lk) ^ (m & 7);
                a[mf] = *reinterpret_cast<const bf16x8*>(&S[m * 128 + slot * 8]);
            }
            #pragma unroll
            for (int nfr = 0; nfr < 2; ++nfr) {
                int nt = wn * 2 + nfr;
                bf16x8 b = *reinterpret_cast<const bf16x8*>(&mw1p[((nt * 4 + ks) * 64 + l) * 8]);
                acc1[0][nfr] = __builtin_amdgcn_mfma_f32_16x16x32_bf16(a[0], b, acc1[0][nfr], 0, 0, 0);
                acc1[1][nfr] = __builtin_amdgcn_mfma_f32_16x16x32_bf16(a[1], b, acc1[1][nfr], 0, 0, 0);
            }
        }
        #pragma unroll
        for (int nfr = 0; nfr < 2; ++nfr) {
            int n = (wn * 2 + nfr) * 16 + lm;
            #pragma unroll
            for (int mf = 0; mf < 2; ++mf)
                #pragma unroll
                for (int r = 0; r < 4; ++r) {
                    int m = wm * 32 + mf * 16 + lk * 4 + r;
                    int sl = m * 128 + ((n >> 3) ^ (m & 7)) * 8 + (n & 7);
                    float v = acc1[mf][nfr][r] + unbf(H[sl]);
                    v = fmaxf(v, 0.0f);
                    H[sl] = bf16s(v);
                }
        }
    }
    __syncthreads(); // hidden complete; S (src) reads done

    // ---- copy hidden -> global fp8 (cheap codec); stage S <- nfa[dsts] ----
    #pragma unroll
    for (int j = 0; j < 2; ++j) {
        int q = j * 512 + t;
        int row = q >> 4, c16 = q & 15;
        int slot = c16 ^ (row & 7);
        uint4 v = *reinterpret_cast<const uint4*>(&H[row * 128 + slot * 8]);
        uint2 o;
        o.x = f8enc4(unlo(v.x), unhi(v.x), unlo(v.y), unhi(v.y));
        o.y = f8enc4(unlo(v.z), unhi(v.z), unlo(v.w), unhi(v.w));
        *reinterpret_cast<uint2*>(&hid_out[(size_t)(e0 + row) * DD + c16 * 8]) = o;
    }
    #pragma unroll
    for (int it = 0; it < 2; ++it) {
        int rb = w * 8 + it * 4;
        int row = rb + lrow;
        int c = lslot ^ (row & 7);
        gload_lds16(nfa + (size_t)dsts[e0 + row] * DD + c * 8, &S[rb * 128]);
    }

    // ---- GEMM-z: zpre = hidden @ mwB, K=128, N=128 ----
    f32x4 acc[2][2];
    #pragma unroll
    for (int mf = 0; mf < 2; ++mf)
        #pragma unroll
        for (int nfr = 0; nfr < 2; ++nfr) acc[mf][nfr] = (f32x4){0.f, 0.f, 0.f, 0.f};

    #pragma unroll
    for (int ks = 0; ks < 4; ++ks) {
        bf16x8 a[2];
        #pragma unroll
        for (int mf = 0; mf < 2; ++mf) {
            int m = wm * 32 + mf * 16 + lm;
            int slot = (ks * 4 + lk) ^ (m & 7);
            a[mf] = *reinterpret_cast<const bf16x8*>(&H[m * 128 + slot * 8]);
        }
        #pragma unroll
        for (int nfr = 0; nfr < 2; ++nfr) {
            int nt = wn * 2 + nfr;
            bf16x8 b = *reinterpret_cast<const bf16x8*>(&mwBp[((nt * 4 + ks) * 64 + l) * 8]);
            acc[0][nfr] = __builtin_amdgcn_mfma_f32_16x16x32_bf16(a[0], b, acc[0][nfr], 0, 0, 0);
            acc[1][nfr] = __builtin_amdgcn_mfma_f32_16x16x32_bf16(a[1], b, acc[1][nfr], 0, 0, 0);
        }
    }
    __syncthreads(); // nfa staged into S; H reads done

    // ---- z epilogue (all 8 waves) ----
    {
        float zbv[2], aw2v[2];
        #pragma unroll
        for (int nfr = 0; nfr < 2; ++nfr) {
            int nc = (wn * 2 + nfr) * 16 + lm;
            zbv[nfr] = zb[nc];
            aw2v[nfr] = aw2[nc];
        }
        #pragma unroll
        for (int mf = 0; mf < 2; ++mf)
            #pragma unroll
            for (int r = 0; r < 4; ++r) {
                int m = wm * 32 + mf * 16 + lk * 4 + r;
                float s = 0.0f;
                #pragma unroll
                for (int nfr = 0; nfr < 2; ++nfr) {
                    int nc = (wn * 2 + nfr) * 16 + lm;
                    float v = acc[mf][nfr][r] + zbv[nfr]
                            + unbf(S[m * 128 + ((nc >> 3) ^ (m & 7)) * 8 + (nc & 7)]);
                    v = (v > 0.0f) ? v : 0.2f * v;
                    s = fmaf(v, aw2v[nfr], s);
                }
                s += __shfl_xor(s, 1, 64);
                s += __shfl_xor(s, 2, 64);
                s += __shfl_xor(s, 4, 64);
                s += __shfl_xor(s, 8, 64);
                if (lm == 0) RED[m][wn] = s;
            }
    }
    __syncthreads();

    if (t < 64) {
        attn_raw[e0 + t] = RED[t][0] + RED[t][1] + RED[t][2] + RED[t][3] + ab2[0];
    }
}

// ---------------- fused per-node softmax + hidden(fp8) aggregate ------------
__global__ __launch_bounds__(256) void k_aggr(
    const unsigned char* __restrict__ hid, const float* __restrict__ raw,
    const int* __restrict__ row_start, const int* __restrict__ cnt,
    unsigned short* __restrict__ haggrb)
{
    __shared__ float wbuf[4][64];
    const int l = threadIdx.x & 63;
    const int nib = threadIdx.x >> 6;
    const int n = blockIdx.x * 4 + nib;
    if (n >= NN) return;
    const int rs = row_start[n], deg = cnt[n];

    float m = -INFINITY;
    for (int j = l; j < deg; j += 64) m = fmaxf(m, raw[rs + j]);
    #pragma unroll
    for (int off = 32; off >= 1; off >>= 1) m = fmaxf(m, __shfl_xor(m, off, 64));

    float s = 0.0f;
    for (int j = l; j < deg; j += 64) s += expf(raw[rs + j] - m);
    #pragma unroll
    for (int off = 32; off >= 1; off >>= 1) s += __shfl_xor(s, off, 64);
    const float rinv = 1.0f / (s + 1e-8f);

    float a0 = 0.0f, a1 = 0.0f;
    for (int base = 0; base < deg; base += 64) {
        int ntc = min(64, deg - base);
        if (l < ntc) wbuf[nib][l] = expf(raw[rs + base + l] - m) * rinv;
        // wave-private LDS (wave64 lockstep): no barrier needed
        for (int j = 0; j < ntc; ++j) {
            float w = wbuf[nib][j];     // broadcast read
            unsigned short v = *reinterpret_cast<const unsigned short*>(
                &hid[(size_t)(rs + base + j) * DD + l * 2]);
            f32x2 d = f8dec2(v);
            a0 = fmaf(w, d.x, a0);
            a1 = fmaf(w, d.y, a1);
        }
    }
    *reinterpret_cast<unsigned int*>(&haggrb[(size_t)n * DD + l * 2]) = pk2(a0, a1);
}

// ---------------- node kernel: GEMM0(mw2) + LN1 + FFN(4 chunks) + LN2 -------
__global__ __launch_bounds__(512) void k_node(
    const float* __restrict__ nf, const unsigned short* __restrict__ haggrb,
    const unsigned short* __restrict__ mw2p, const float* __restrict__ mb2,
    const float* __restrict__ g1, const float* __restrict__ b1,
    const unsigned short* __restrict__ fw1p, const float* __restrict__ fb1,
    const unsigned short* __restrict__ fw2p, const float* __restrict__ fb2,
    const float* __restrict__ g2, const float* __restrict__ b2,
    float* __restrict__ out)
{
    __shared__ alignas(16) unsigned short XB[64 * 128]; // 16 KB
    __shared__ alignas(16) unsigned short HB[64 * 128]; // 16 KB (also HG staging)

    const int t = threadIdx.x;
    const int w = t >> 6, l = t & 63;
    const int wm = w >> 2, wn = w & 3;
    const int lm = l & 15, lk = l >> 4;
    const int lrow = l >> 4, lslot = l & 15;
    const int row = t >> 3;      // 0..63
    const int q = t & 7;         // 16-col segment
    const long n0 = (long)blockIdx.x * 64;
    const long rg = n0 + row;
    const long rc = (rg < NN) ? rg : (NN - 1);

    // ---- stage HG <- haggrb (swizzled src) ----
    unsigned short* HG = HB;
    #pragma unroll
    for (int it = 0; it < 2; ++it) {
        int rb = w * 8 + it * 4;
        int rr = rb + lrow;
        long grow = n0 + rr; if (grow >= NN) grow = NN - 1;
        int c = lslot ^ (rr & 7);
        gload_lds16(haggrb + grow * DD + c * 8, &HG[rb * 128]);
    }
    __syncthreads();

    // ---- GEMM0: aggr = haggr @ mw2 + mb2 -> XB (bf16, swizzled) ----
    {
        f32x4 acc0[2][2];
        #pragma unroll
        for (int mf = 0; mf < 2; ++mf)
            #pragma unroll
            for (int nfr = 0; nfr < 2; ++nfr) acc0[mf][nfr] = (f32x4){0.f, 0.f, 0.f, 0.f};

        #pragma unroll
        for (int ks = 0; ks < 4; ++ks) {
            bf16x8 a[2];
            #pragma unroll
            for (int mf = 0; mf < 2; ++mf) {
                int m = wm * 32 + mf * 16 + lm;
                int slot = (ks * 4 + lk) ^ (m & 7);
                a[mf] = *reinterpret_cast<const bf16x8*>(&HG[m * 128 + slot * 8]);
            }
            #pragma unroll
            for (int nfr = 0; nfr < 2; ++nfr) {
                int nt = wn * 2 + nfr;
                bf16x8 b = *reinterpret_cast<const bf16x8*>(&mw2p[((nt * 4 + ks) * 64 + l) * 8]);
                acc0[0][nfr] = __builtin_amdgcn_mfma_f32_16x16x32_bf16(a[0], b, acc0[0][nfr], 0, 0, 0);
                acc0[1][nfr] = __builtin_amdgcn_mfma_f32_16x16x32_bf16(a[1], b, acc0[1][nfr], 0, 0, 0);
            }
        }
        __syncthreads(); // HG reads done (HB reused by FFN chunks)
        #pragma unroll
        for (int nfr = 0; nfr < 2; ++nfr) {
            int n = (wn * 2 + nfr) * 16 + lm;
            float bv = mb2[n];
            #pragma unroll
            for (int mf = 0; mf < 2; ++mf)
                #pragma unroll
                for (int r = 0; r < 4; ++r) {
                    int m = wm * 32 + mf * 16 + lk * 4 + r;
                    XB[m * 128 + ((n >> 3) ^ (m & 7)) * 8 + (n & 7)] = bf16s(acc0[mf][nfr][r] + bv);
                }
        }
    }
    __syncthreads(); // XB = aggr (bf16)

    // ---- LN1: x = nf + aggr ----
    float xr[16];
    float s = 0.0f, ss = 0.0f;
    {
        const float* xp = nf + rc * DD + q * 16;
        #pragma unroll
        for (int i = 0; i < 2; ++i) {
            int c = q * 2 + i, slot = c ^ (row & 7);
            uint4 v = *reinterpret_cast<const uint4*>(&XB[row * 128 + slot * 8]);
            float f[8];
            f[0] = unlo(v.x); f[1] = unhi(v.x); f[2] = unlo(v.y); f[3] = unhi(v.y);
            f[4] = unlo(v.z); f[5] = unhi(v.z); f[6] = unlo(v.w); f[7] = unhi(v.w);
            float4 a = *reinterpret_cast<const float4*>(xp + i * 8);
            float4 b = *reinterpret_cast<const float4*>(xp + i * 8 + 4);
            float vv[8] = {a.x + f[0], a.y + f[1], a.z + f[2], a.w + f[3],
                           b.x + f[4], b.y + f[5], b.z + f[6], b.w + f[7]};
            #pragma unroll
            for (int j = 0; j < 8; ++j) {
                xr[i * 8 + j] = vv[j];
                s += vv[j];
                ss = fmaf(vv[j], vv[j], ss);
            }
        }
    }
    s  += __shfl_xor(s, 1, 64);  s  += __shfl_xor(s, 2, 64);  s  += __shfl_xor(s, 4, 64);
    ss += __shfl_xor(ss, 1, 64); ss += __shfl_xor(ss, 2, 64); ss += __shfl_xor(ss, 4, 64);
    {
        float mu = s * (1.0f / DD);
        float var = ss * (1.0f / DD) - mu * mu;
        float rstd = rsqrtf(var + 1e-5f);
        #pragma unroll
        for (int i = 0; i < 4; ++i) {
            float4 gv = *reinterpret_cast<const float4*>(g1 + q * 16 + i * 4);
            float4 bv = *reinterpret_cast<const float4*>(b1 + q * 16 + i * 4);
            xr[i * 4 + 0] = (xr[i * 4 + 0] - mu) * rstd * gv.x + bv.x;
            xr[i * 4 + 1] = (xr[i * 4 + 1] - mu) * rstd * gv.y + bv.y;
            xr[i * 4 + 2] = (xr[i * 4 + 2] - mu) * rstd * gv.z + bv.z;
            xr[i * 4 + 3] = (xr[i * 4 + 3] - mu) * rstd * gv.w + bv.w;
        }
        #pragma unroll
        for (int i = 0; i < 2; ++i) {
            int c = q * 2 + i, slot = c ^ (row & 7);
            uint4 v;
            v.x = pk2(xr[i * 8 + 0], xr[i * 8 + 1]);
            v.y = pk2(xr[i * 8 + 2], xr[i * 8 + 3]);
            v.z = pk2(xr[i * 8 + 4], xr[i * 8 + 5]);
            v.w = pk2(xr[i * 8 + 6], xr[i * 8 + 7]);
            *reinterpret_cast<uint4*>(&XB[row * 128 + slot * 8]) = v;
        }
    }
    __syncthreads();

    // ---- FFN: four 128-col chunks of the 512-wide hidden ----
    f32x4 acc2[2][2];
    #pragma unroll
    for (int mf = 0; mf < 2; ++mf)
        #pragma unroll
        for (int nfr = 0; nfr < 2; ++nfr) acc2[mf][nfr] = (f32x4){0.f, 0.f, 0.f, 0.f};

    #pragma unroll
    for (int ch = 0; ch < 4; ++ch) {
        f32x4 acc[2][2];
        #pragma unroll
        for (int mf = 0; mf < 2; ++mf)
            #pragma unroll
            for (int nfr = 0; nfr < 2; ++nfr) acc[mf][nfr] = (f32x4){0.f, 0.f, 0.f, 0.f};

        #pragma unroll
        for (int ks = 0; ks < 4; ++ks) {
            bf16x8 a[2];
            #pragma unroll
            for (int mf = 0; mf < 2; ++mf) {
                int m = wm * 32 + mf * 16 + lm;
                int slot = (ks * 4 + lk) ^ (m & 7);
                a[mf] = *reinterpret_cast<const bf16x8*>(&XB[m * 128 + slot * 8]);
            }
            #pragma unroll
            for (int nfr = 0; nfr < 2; ++nfr) {
                int nt = ch * 8 + wn * 2 + nfr;
                bf16x8 b = *reinterpret_cast<const bf16x8*>(&fw1p[((nt * 4 + ks) * 64 + l) * 8]);
                acc[0][nfr] = __builtin_amdgcn_mfma_f32_16x16x32_bf16(a[0], b, acc[0][nfr], 0, 0, 0);
                acc[1][nfr] = __builtin_amdgcn_mfma_f32_16x16x32_bf16(a[1], b, acc[1][nfr], 0, 0, 0);
            }
        }
        #pragma unroll
        for (int nfr = 0; nfr < 2; ++nfr) {
            int nl = (wn * 2 + nfr) * 16 + lm;
            float bv = fb1[ch * 128 + nl];
            #pragma unroll
            for (int mf = 0; mf < 2; ++mf)
                #pragma unroll
                for (int r = 0; r < 4; ++r) {
                    int m = wm * 32 + mf * 16 + lk * 4 + r;
                    float h = acc[mf][nfr][r] + bv;
                    float e = __expf(h * -1.702f);
                    float gvv = h * __builtin_amdgcn_rcpf(1.0f + e);
                    HB[m * 128 + (((nl >> 3) ^ (m & 7)) * 8) + (nl & 7)] = bf16s(gvv);
                }
        }
        __syncthreads();

        #pragma unroll
        for (int ks = 0; ks < 4; ++ks) {
            bf16x8 a[2];
            #pragma unroll
            for (int mf = 0; mf < 2; ++mf) {
                int m = wm * 32 + mf * 16 + lm;
                int slot = (ks * 4 + lk) ^ (m & 7);
                a[mf] = *reinterpret_cast<const bf16x8*>(&HB[m * 128 + slot * 8]);
            }
            #pragma unroll
            for (int nfr = 0; nfr < 2; ++nfr) {
                int nt = wn * 2 + nfr;
                int kg = ch * 4 + ks;
                bf16x8 b = *reinterpret_cast<const bf16x8*>(&fw2p[((nt * 16 + kg) * 64 + l) * 8]);
                acc2[0][nfr] = __builtin_amdgcn_mfma_f32_16x16x32_bf16(a[0], b, acc2[0][nfr], 0, 0, 0);
                acc2[1][nfr] = __builtin_amdgcn_mfma_f32_16x16x32_bf16(a[1], b, acc2[1][nfr], 0, 0, 0);
            }
        }
        __syncthreads();
    }

    // ---- ffn -> XB (bf16) ----
    #pragma unroll
    for (int nfr = 0; nfr < 2; ++nfr) {
        int n = (wn * 2 + nfr) * 16 + lm;
        float bv = fb2[n];
        #pragma unroll
        for (int mf = 0; mf < 2; ++mf)
            #pragma unroll
            for (int r = 0; r < 4; ++r) {
                int m = wm * 32 + mf * 16 + lk * 4 + r;
                XB[m * 128 + (((n >> 3) ^ (m & 7)) * 8) + (n & 7)] = bf16s(acc2[mf][nfr][r] + bv);
            }
    }
    __syncthreads();

    // ---- residual + LN2 ----
    float s2 = 0.0f, ss2 = 0.0f;
    #pragma unroll
    for (int i = 0; i < 2; ++i) {
        int c = q * 2 + i, slot = c ^ (row & 7);
        uint4 v = *reinterpret_cast<const uint4*>(&XB[row * 128 + slot * 8]);
        float f[8];
        f[0] = unlo(v.x); f[1] = unhi(v.x); f[2] = unlo(v.y); f[3] = unhi(v.y);
        f[4] = unlo(v.z); f[5] = unhi(v.z); f[6] = unlo(v.w); f[7] = unhi(v.w);
        #pragma unroll
        for (int j = 0; j < 8; ++j) {
            float vv = xr[i * 8 + j] + f[j];
            xr[i * 8 + j] = vv;
            s2 += vv;
            ss2 = fmaf(vv, vv, ss2);
        }
    }
    s2  += __shfl_xor(s2, 1, 64);  s2  += __shfl_xor(s2, 2, 64);  s2  += __shfl_xor(s2, 4, 64);
    ss2 += __shfl_xor(ss2, 1, 64); ss2 += __shfl_xor(ss2, 2, 64); ss2 += __shfl_xor(ss2, 4, 64);
    {
        float mu = s2 * (1.0f / DD);
        float var = ss2 * (1.0f / DD) - mu * mu;
        float rstd = rsqrtf(var + 1e-5f);
        if (rg < NN) {
            float* op = out + rg * DD + q * 16;
            #pragma unroll
            for (int i = 0; i < 4; ++i) {
                float4 gv = *reinterpret_cast<const float4*>(g2 + q * 16 + i * 4);
                float4 bv = *reinterpret_cast<const float4*>(b2 + q * 16 + i * 4);
                float4 o;
                o.x = (xr[i * 4 + 0] - mu) * rstd * gv.x + bv.x;
                o.y = (xr[i * 4 + 1] - mu) * rstd * gv.y + bv.y;
                o.z = (xr[i * 4 + 2] - mu) * rstd * gv.z + bv.z;
                o.w = (xr[i * 4 + 3] - mu) * rstd * gv.w + bv.w;
                *reinterpret_cast<float4*>(op + i * 4) = o;
            }
        }
    }
}

extern "C" void kernel_launch(void* const* d_in, const int* in_sizes, int n_in,
                              void* d_out, int out_size, void* d_ws, size_t ws_size,
                              hipStream_t stream)
{
    const float* nf  = (const float*)d_in[0];
    const int*   ei  = (const int*)d_in[1];
    const int*   et  = (const int*)d_in[2];
    const float* rel = (const float*)d_in[3];
    const float* mw1 = (const float*)d_in[4];
    const float* mb1 = (const float*)d_in[5];
    const float* mw2 = (const float*)d_in[6];
    const float* mb2 = (const float*)d_in[7];
    const float* aw1 = (const float*)d_in[8];
    const float* ab1 = (const float*)d_in[9];
    const float* aw2 = (const float*)d_in[10];
    const float* ab2 = (const float*)d_in[11];
    const float* g1  = (const float*)d_in[12];
    const float* b1  = (const float*)d_in[13];
    const float* fw1 = (const float*)d_in[14];
    const float* fb1 = (const float*)d_in[15];
    const float* fw2 = (const float*)d_in[16];
    const float* fb2 = (const float*)d_in[17];
    const float* g2  = (const float*)d_in[18];
    const float* b2  = (const float*)d_in[19];
    float* out = (float*)d_out;

    char* ws = (char*)d_ws;
    size_t off = 0;
    auto alloc = [&](size_t bytes) -> char* {
        char* p = ws + off;
        off += (bytes + 255) & ~(size_t)255;
        return p;
    };
    unsigned char* hid = (unsigned char*)alloc((size_t)NE * DD);
    float* attn_raw = (float*)alloc((size_t)NE * 4);
    unsigned short* haggrb = (unsigned short*)alloc((size_t)NN * DD * 2);
    unsigned short* nfa = (unsigned short*)alloc((size_t)NN * DD * 2);
    unsigned short* nfb = (unsigned short*)alloc((size_t)NN * DD * 2);
    unsigned short* relcb = (unsigned short*)alloc((size_t)RR * DD * 2);
    float* zb  = (float*)alloc((size_t)128 * 4);
    int* cnt       = (int*)alloc((size_t)NN * 4);
    int* row_start = (int*)alloc((size_t)NN * 4);
    int* cursor    = (int*)alloc((size_t)NN * 4);
    int* srcs      = (int*)alloc((size_t)NE * 4);
    int* ets       = (int*)alloc((size_t)NE * 4);
    int* dsts      = (int*)alloc((size_t)NE * 4);
    int* bsum      = (int*)alloc((size_t)SCAN_NB * 4);
    unsigned short* mw1p = (unsigned short*)alloc(16384 * 2);
    unsigned short* mw2p = (unsigned short*)alloc(16384 * 2);
    unsigned short* awTp = (unsigned short*)alloc(16384 * 2);
    unsigned short* mwBp = (unsigned short*)alloc(16384 * 2);
    unsigned short* fw1p = (unsigned short*)alloc(65536 * 2);
    unsigned short* fw2p = (unsigned short*)alloc(65536 * 2);

    const int* srcp = ei;
    const int* dstp = ei + NE;

    hipLaunchKernelGGL(k_setup, dim3(1260), dim3(256), 0, stream,
                       mw1, mb1, mw2, mb2, aw1, rel, fw1, fw2,
                       mw1p, mw2p, awTp, mwBp, fw1p, fw2p, relcb, zb, cnt);
    hipLaunchKernelGGL(k_hist, dim3((NE + 255) / 256), dim3(256), 0, stream, dstp, cnt);
    hipLaunchKernelGGL(k_scanA, dim3(SCAN_NB), dim3(256), 0, stream, cnt, bsum);
    hipLaunchKernelGGL(k_scanB, dim3(1), dim3(512), 0, stream, bsum);
    hipLaunchKernelGGL(k_scanC, dim3(SCAN_NB), dim3(256), 0, stream, cnt, bsum, row_start, cursor);
    hipLaunchKernelGGL(k_bucket, dim3((NE + 255) / 256), dim3(256), 0, stream,
                       srcp, dstp, et, cursor, srcs, ets, dsts);
    hipLaunchKernelGGL(k_prepnfa, dim3((NN + 63) / 64), dim3(256), 0, stream,
                       nf, awTp, ab1, nfb, nfa);
    hipLaunchKernelGGL(k_edge, dim3(NE / 64), dim3(512), 0, stream,
                       nfb, srcs, dsts, ets, nfa, relcb,
                       mw1p, mwBp, zb, aw2, ab2,
                       hid, attn_raw);
    hipLaunchKernelGGL(k_aggr, dim3((NN + 3) / 4), dim3(256), 0, stream,
                       hid, attn_raw, row_start, cnt, haggrb);
    hipLaunchKernelGGL(k_node, dim3((NN + 63) / 64), dim3(512), 0, stream,
                       nf, haggrb, mw2p, mb2, g1, b1, fw1p, fb1, fw2p, fb2, g2, b2, out);
}

// Round 17
// 387.968 us; speedup vs baseline: 1.5206x; 1.0216x over previous
//
#include <hip/hip_runtime.h>
#include <hip/hip_bf16.h>

#define NN 100000
#define NE 600000
#define DD 128
#define RR 200
#define SCAN_NB ((NN + 255) / 256)   // 391

typedef __attribute__((ext_vector_type(8))) short bf16x8;
typedef __attribute__((ext_vector_type(4))) float f32x4;
typedef __attribute__((ext_vector_type(2))) float f32x2;

__device__ __forceinline__ unsigned int bfbits(float x) {
    return (unsigned int)__builtin_bit_cast(unsigned short, __float2bfloat16(x));
}
__device__ __forceinline__ unsigned int pk2(float a, float b) {
    return bfbits(a) | (bfbits(b) << 16);
}
__device__ __forceinline__ unsigned short bf16s(float x) {
    return __builtin_bit_cast(unsigned short, __float2bfloat16(x));
}
__device__ __forceinline__ float unbf(unsigned short u) {
    return __builtin_bit_cast(float, ((unsigned int)u) << 16);
}
__device__ __forceinline__ float unlo(unsigned int u) {
    return __builtin_bit_cast(float, u << 16);
}
__device__ __forceinline__ float unhi(unsigned int u) {
    return __builtin_bit_cast(float, u & 0xffff0000u);
}

// ---- fp8 e4m3 codec for NON-NEGATIVE values (post-relu hidden) ----
__device__ __forceinline__ unsigned int f8e(float x) {
    unsigned int u = __float_as_uint(x);
    unsigned int r = u + 0x7FFFFu + ((u >> 20) & 1u);
    int n = (int)(r >> 20) - 960;            // (exp<<3)|mant for normals
    int d = (int)rintf(x * 512.0f);          // denormal: round(x * 2^9)
    if (d > 7) d = 7;
    return (unsigned int)((n >= 8) ? n : d) & 0xFFu;
}
__device__ __forceinline__ unsigned int f8enc4(float a, float b, float c, float d) {
    return f8e(a) | (f8e(b) << 8) | (f8e(c) << 16) | (f8e(d) << 24);
}
__device__ __forceinline__ float f8d(unsigned int f8) {
    float nrm = __uint_as_float((f8 << 20) + 0x3C000000u);
    float den = (float)(int)f8 * 0.001953125f;
    return (f8 & 0x78u) ? nrm : den;
}
__device__ __forceinline__ f32x2 f8dec2(unsigned short v) {
    f32x2 r;
    r.x = f8d((unsigned int)(v & 0xFFu));
    r.y = f8d((unsigned int)(v >> 8));
    return r;
}

__device__ __forceinline__ void gload_lds16(const void* g, void* l) {
    __builtin_amdgcn_global_load_lds(
        (const __attribute__((address_space(1))) void*)g,
        (__attribute__((address_space(3))) void*)l, 16, 0, 0);
}

// ---------------- histogram of dst ----------------
__global__ void k_hist(const int* __restrict__ dst, int* __restrict__ cnt) {
    int e = blockIdx.x * 256 + threadIdx.x;
    if (e < NE) atomicAdd(&cnt[dst[e]], 1);
}

// ---------------- 3-kernel exclusive scan over cnt[NN] ----------------
__global__ void k_scanA(const int* __restrict__ cnt, int* __restrict__ bsum) {
    __shared__ int red[256];
    int i = blockIdx.x * 256 + threadIdx.x;
    red[threadIdx.x] = (i < NN) ? cnt[i] : 0;
    __syncthreads();
    for (int off = 128; off >= 1; off >>= 1) {
        if (threadIdx.x < off) red[threadIdx.x] += red[threadIdx.x + off];
        __syncthreads();
    }
    if (threadIdx.x == 0) bsum[blockIdx.x] = red[0];
}

__global__ void k_scanB(int* __restrict__ bsum) {
    __shared__ int sh[512];
    int t = threadIdx.x;
    int v = (t < SCAN_NB) ? bsum[t] : 0;
    sh[t] = v;
    __syncthreads();
    for (int off = 1; off < 512; off <<= 1) {
        int add = (t >= off) ? sh[t - off] : 0;
        __syncthreads();
        sh[t] += add;
        __syncthreads();
    }
    if (t < SCAN_NB) bsum[t] = sh[t] - v;   // exclusive
}

__global__ void k_scanC(const int* __restrict__ cnt, const int* __restrict__ bsum,
                        int* __restrict__ row_start, int* __restrict__ cursor) {
    __shared__ int sh[256];
    int i = blockIdx.x * 256 + threadIdx.x;
    int t = threadIdx.x;
    int v = (i < NN) ? cnt[i] : 0;
    sh[t] = v;
    __syncthreads();
    for (int off = 1; off < 256; off <<= 1) {
        int add = (t >= off) ? sh[t - off] : 0;
        __syncthreads();
        sh[t] += add;
        __syncthreads();
    }
    if (i < NN) {
        int ex = bsum[blockIdx.x] + sh[t] - v;
        row_start[i] = ex;
        cursor[i] = ex;
    }
}

// ---------------- bucket: permuted src/etype/dst grouped by dst ----------------
__global__ void k_bucket(const int* __restrict__ src, const int* __restrict__ dst,
                         const int* __restrict__ etype, int* __restrict__ cursor,
                         int* __restrict__ srcs, int* __restrict__ ets,
                         int* __restrict__ dsts) {
    int e = blockIdx.x * 256 + threadIdx.x;
    if (e < NE) {
        int d = dst[e];
        int p = atomicAdd(&cursor[d], 1);
        srcs[p] = src[e];
        ets[p]  = etype[e];
        dsts[p] = d;
    }
}

// ---------------- setup: weight packing + folds + cnt zeroing (one launch) ---
__global__ void k_setup(const float* __restrict__ mw1, const float* __restrict__ mb1,
                        const float* __restrict__ mw2, const float* __restrict__ mb2,
                        const float* __restrict__ aw1, const float* __restrict__ rel,
                        const float* __restrict__ fw1, const float* __restrict__ fw2,
                        unsigned short* __restrict__ mw1p,
                        unsigned short* __restrict__ mw2p,
                        unsigned short* __restrict__ awTp,
                        unsigned short* __restrict__ mwBp,
                        unsigned short* __restrict__ fw1p,
                        unsigned short* __restrict__ fw2p,
                        unsigned short* __restrict__ relcb,
                        float* __restrict__ zb, int* __restrict__ cnt) {
    int idx = blockIdx.x * 256 + threadIdx.x;   // 322336 total
    if (idx < 16384) {            // mw1 TOP: K=128, N=128
        int i = idx & 7, l = (idx >> 3) & 63, ks = (idx >> 9) & 3, nt = idx >> 11;
        int k = ks * 32 + (l >> 4) * 8 + i, n = nt * 16 + (l & 15);
        mw1p[idx] = bf16s(mw1[k * 128 + n]);
    } else if (idx < 32768) {     // mw2: K=128, N=128
        int j = idx - 16384;
        int i = j & 7, l = (j >> 3) & 63, ks = (j >> 9) & 3, nt = j >> 11;
        int k = ks * 32 + (l >> 4) * 8 + i, n = nt * 16 + (l & 15);
        mw2p[j] = bf16s(mw2[k * 128 + n]);
    } else if (idx < 49152) {     // aw1 TOP: K=128, N=128
        int j = idx - 32768;
        int i = j & 7, l = (j >> 3) & 63, ks = (j >> 9) & 3, nt = j >> 11;
        int k = ks * 32 + (l >> 4) * 8 + i, n = nt * 16 + (l & 15);
        awTp[j] = bf16s(aw1[k * 128 + n]);
    } else if (idx < 65536) {     // mwB = mw2 @ aw1_bot (direct dot)
        int j = idx - 49152;
        int i = j & 7, l = (j >> 3) & 63, ks = (j >> 9) & 3, nt = j >> 11;
        int k = ks * 32 + (l >> 4) * 8 + i, n = nt * 16 + (l & 15);
        float s = 0.0f;
        for (int j2 = 0; j2 < 128; ++j2)
            s = fmaf(mw2[k * 128 + j2], aw1[(128 + j2) * 128 + n], s);
        mwBp[j] = bf16s(s);
    } else if (idx < 131072) {    // fw1: K=128, N=512
        int j = idx - 65536;
        int i = j & 7, l = (j >> 3) & 63, ks = (j >> 9) & 3, nt = j >> 11;
        int k = ks * 32 + (l >> 4) * 8 + i, n = nt * 16 + (l & 15);
        fw1p[j] = bf16s(fw1[k * 512 + n]);
    } else if (idx < 196608) {    // fw2: K=512 (KS=16), N=128
        int j = idx - 131072;
        int i = j & 7, l = (j >> 3) & 63, ks = (j >> 9) & 15, nt = j >> 13;
        int k = ks * 32 + (l >> 4) * 8 + i, n = nt * 16 + (l & 15);
        fw2p[j] = bf16s(fw2[k * 128 + n]);
    } else if (idx < 222208) {    // relcb = bf16(rel @ mw1_bot + mb1)
        int j = idx - 196608;
        int r = j >> 7, n = j & 127;
        float s = mb1[n];
        for (int k = 0; k < 128; ++k)
            s = fmaf(rel[r * 128 + k], mw1[(128 + k) * 128 + n], s);
        relcb[j] = bf16s(s);
    } else if (idx < 222336) {    // zb = mb2 @ aw1_bot
        int n = idx - 222208;
        float s = 0.0f;
        for (int j2 = 0; j2 < 128; ++j2)
            s = fmaf(mb2[j2], aw1[(128 + j2) * 128 + n], s);
        zb[n] = s;
    } else if (idx < 322336) {    // zero cnt
        cnt[idx - 222336] = 0;
    }
}

// ---------------- prep+nfa fused: nfb = bf16(nf); nfa = nf @ aw1_top + ab1 ---
__global__ __launch_bounds__(256) void k_prepnfa(
    const float* __restrict__ nf, const unsigned short* __restrict__ awTp,
    const float* __restrict__ ab1,
    unsigned short* __restrict__ nfb, unsigned short* __restrict__ nfa)
{
    __shared__ alignas(16) unsigned short XB[64 * 128]; // 16 KB
    const int t = threadIdx.x;
    const int w = t >> 6, l = t & 63;
    const int wm = w >> 1, wn = w & 1;
    const int lm = l & 15, lk = l >> 4;
    const int n0 = blockIdx.x * 64;

    {
        const int row = t >> 2, seg = t & 3;
        long ng = n0 + row; if (ng >= NN) ng = NN - 1;
        const float* sp = nf + ng * DD + seg * 32;
        uint4 o[4];
        #pragma unroll
        for (int i = 0; i < 4; ++i) {
            float4 f0 = *reinterpret_cast<const float4*>(sp + i * 8);
            float4 f1 = *reinterpret_cast<const float4*>(sp + i * 8 + 4);
            o[i].x = pk2(f0.x, f0.y); o[i].y = pk2(f0.z, f0.w);
            o[i].z = pk2(f1.x, f1.y); o[i].w = pk2(f1.z, f1.w);
        }
        if (n0 + row < NN) {
            #pragma unroll
            for (int i = 0; i < 4; ++i)
                *reinterpret_cast<uint4*>(&nfb[(size_t)(n0 + row) * DD + (seg * 4 + i) * 8]) = o[i];
        }
        #pragma unroll
        for (int i = 0; i < 4; ++i) {
            int c = seg * 4 + i, slot = c ^ (row & 7);
            *reinterpret_cast<uint4*>(&XB[row * 128 + slot * 8]) = o[i];
        }
    }
    __syncthreads();

    f32x4 acc[2][4];
    #pragma unroll
    for (int mf = 0; mf < 2; ++mf)
        #pragma unroll
        for (int nfr = 0; nfr < 4; ++nfr) acc[mf][nfr] = (f32x4){0.f, 0.f, 0.f, 0.f};

    #pragma unroll
    for (int ks = 0; ks < 4; ++ks) {
        bf16x8 a[2];
        #pragma unroll
        for (int mf = 0; mf < 2; ++mf) {
            int m = wm * 32 + mf * 16 + lm;
            int slot = (ks * 4 + lk) ^ (m & 7);
            a[mf] = *reinterpret_cast<const bf16x8*>(&XB[m * 128 + slot * 8]);
        }
        #pragma unroll
        for (int nfr = 0; nfr < 4; ++nfr) {
            int nt = wn * 4 + nfr;
            bf16x8 b = *reinterpret_cast<const bf16x8*>(&awTp[((nt * 4 + ks) * 64 + l) * 8]);
            acc[0][nfr] = __builtin_amdgcn_mfma_f32_16x16x32_bf16(a[0], b, acc[0][nfr], 0, 0, 0);
            acc[1][nfr] = __builtin_amdgcn_mfma_f32_16x16x32_bf16(a[1], b, acc[1][nfr], 0, 0, 0);
        }
    }
    __syncthreads();

    #pragma unroll
    for (int nfr = 0; nfr < 4; ++nfr) {
        int n = wn * 64 + nfr * 16 + lm;
        float bv = ab1[n];
        #pragma unroll
        for (int mf = 0; mf < 2; ++mf)
            #pragma unroll
            for (int r = 0; r < 4; ++r) {
                int m = wm * 32 + mf * 16 + lk * 4 + r;
                XB[m * 128 + n] = bf16s(acc[mf][nfr][r] + bv);
            }
    }
    __syncthreads();

    #pragma unroll
    for (int j = 0; j < 4; ++j) {
        int q = j * 256 + t;
        int row = q >> 4, c16 = q & 15;
        if (n0 + row < NN)
            *reinterpret_cast<uint4*>(&nfa[(size_t)(n0 + row) * DD + c16 * 8]) =
                *reinterpret_cast<const uint4*>(&XB[row * 128 + c16 * 8]);
    }
}

// ---------------- edge kernel: GEMM1(hidden) + GEMM-z(logits) ---------------
__global__ __launch_bounds__(512) void k_edge(
    const unsigned short* __restrict__ nfb, const int* __restrict__ srcs,
    const int* __restrict__ dsts, const int* __restrict__ ets,
    const unsigned short* __restrict__ nfa, const unsigned short* __restrict__ relcb,
    const unsigned short* __restrict__ mw1p, const unsigned short* __restrict__ mwBp,
    const float* __restrict__ zb, const float* __restrict__ aw2,
    const float* __restrict__ ab2,
    unsigned char* __restrict__ hid_out, float* __restrict__ attn_raw)
{
    __shared__ alignas(16) unsigned short S[64 * 128];  // src rows, then nfa[dst]
    __shared__ alignas(16) unsigned short H[64 * 128];  // relc, then hidden
    __shared__ float RED[64][4];

    const int t = threadIdx.x;
    const int w = t >> 6, l = t & 63;
    const int wm = w >> 2, wn = w & 3;
    const int lm = l & 15, lk = l >> 4;
    const int lrow = l >> 4, lslot = l & 15;
    const int e0 = blockIdx.x * 64;

    #pragma unroll
    for (int it = 0; it < 2; ++it) {
        int rb = w * 8 + it * 4;
        int row = rb + lrow;
        int c = lslot ^ (row & 7);
        gload_lds16(nfb + (size_t)srcs[e0 + row] * DD + c * 8, &S[rb * 128]);
    }
    #pragma unroll
    for (int it = 0; it < 2; ++it) {
        int rb = w * 8 + it * 4;
        int row = rb + lrow;
        int c = lslot ^ (row & 7);
        gload_lds16(relcb + (size_t)ets[e0 + row] * DD + c * 8, &H[rb * 128]);
    }
    __syncthreads();

    // ---- GEMM1: hidden = relu(src @ mw1_top + relc), K=128; H slot RMW ----
    {
        f32x4 acc1[2][2];
        #pragma unroll
        for (int mf = 0; mf < 2; ++mf)
            #pragma unroll
            for (int nfr = 0; nfr < 2; ++nfr) acc1[mf][nfr] = (f32x4){0.f, 0.f, 0.f, 0.f};

        #pragma unroll
        for (int ks = 0; ks < 4; ++ks) {
            bf16x8 a[2];
            #pragma unroll
            for (int mf = 0; mf < 2; ++mf) {
                int m = wm * 32 + mf * 16 + lm;
                int slot = (ks * 4 + lk) ^ (m & 7);
                a[mf] = *reinterpret_cast<const bf16x8*>(&S[m * 128 + slot * 8]);
            }
            #pragma unroll
            for (int nfr = 0; nfr < 2; ++nfr) {
                int nt = wn * 2 + nfr;
                bf16x8 b = *reinterpret_cast<const bf16x8*>(&mw1p[((nt * 4 + ks) * 64 + l) * 8]);
                acc1[0][nfr] = __builtin_amdgcn_mfma_f32_16x16x32_bf16(a[0], b, acc1[0][nfr], 0, 0, 0);
                acc1[1][nfr] = __builtin_amdgcn_mfma_f32_16x16x32_bf16(a[1], b, acc1[1][nfr], 0, 0, 0);
            }
        }
        #pragma unroll
        for (int nfr = 0; nfr < 2; ++nfr) {
            int n = (wn * 2 + nfr) * 16 + lm;
            #pragma unroll
            for (int mf = 0; mf < 2; ++mf)
                #pragma unroll
                for (int r = 0; r < 4; ++r) {
                    int m = wm * 32 + mf * 16 + lk * 4 + r;
                    int sl = m * 128 + ((n >> 3) ^ (m & 7)) * 8 + (n & 7);
                    float v = acc1[mf][nfr][r] + unbf(H[sl]);
                    v = fmaxf(v, 0.0f);
                    H[sl] = bf16s(v);
                }
        }
    }
    __syncthreads(); // hidden complete; S (src) reads done

    // ---- copy hidden -> global fp8 (cheap codec); stage S <- nfa[dsts] ----
    #pragma unroll
    for (int j = 0; j < 2; ++j) {
        int q = j * 512 + t;
        int row = q >> 4, c16 = q & 15;
        int slot = c16 ^ (row & 7);
        uint4 v = *reinterpret_cast<const uint4*>(&H[row * 128 + slot * 8]);
        uint2 o;
        o.x = f8enc4(unlo(v.x), unhi(v.x), unlo(v.y), unhi(v.y));
        o.y = f8enc4(unlo(v.z), unhi(v.z), unlo(v.w), unhi(v.w));
        *reinterpret_cast<uint2*>(&hid_out[(size_t)(e0 + row) * DD + c16 * 8]) = o;
    }
    #pragma unroll
    for (int it = 0; it < 2; ++it) {
        int rb = w * 8 + it * 4;
        int row = rb + lrow;
        int c = lslot ^ (row & 7);
        gload_lds16(nfa + (size_t)dsts[e0 + row] * DD + c * 8, &S[rb * 128]);
    }

    // ---- GEMM-z: zpre = hidden @ mwB, K=128, N=128 ----
    f32x4 acc[2][2];
    #pragma unroll
    for (int mf = 0; mf < 2; ++mf)
        #pragma unroll
        for (int nfr = 0; nfr < 2; ++nfr) acc[mf][nfr] = (f32x4){0.f, 0.f, 0.f, 0.f};

    #pragma unroll
    for (int ks = 0; ks < 4; ++ks) {
        bf16x8 a[2];
        #pragma unroll
        for (int mf = 0; mf < 2; ++mf) {
            int m = wm * 32 + mf * 16 + lm;
            int slot = (ks * 4 + lk) ^ (m & 7);
            a[mf] = *reinterpret_cast<const bf16x8*>(&H[m * 128 + slot * 8]);
        }
        #pragma unroll
        for (int nfr = 0; nfr < 2; ++nfr) {
            int nt = wn * 2 + nfr;
            bf16x8 b = *reinterpret_cast<const bf16x8*>(&mwBp[((nt * 4 + ks) * 64 + l) * 8]);
            acc[0][nfr] = __builtin_amdgcn_mfma_f32_16x16x32_bf16(a[0], b, acc[0][nfr], 0, 0, 0);
            acc[1][nfr] = __builtin_amdgcn_mfma_f32_16x16x32_bf16(a[1], b, acc[1][nfr], 0, 0, 0);
        }
    }
    __syncthreads(); // nfa staged into S; H reads done

    // ---- z epilogue (all 8 waves) ----
    {
        float zbv[2], aw2v[2];
        #pragma unroll
        for (int nfr = 0; nfr < 2; ++nfr) {
            int nc = (wn * 2 + nfr) * 16 + lm;
            zbv[nfr] = zb[nc];
            aw2v[nfr] = aw2[nc];
        }
        #pragma unroll
        for (int mf = 0; mf < 2; ++mf)
            #pragma unroll
            for (int r = 0; r < 4; ++r) {
                int m = wm * 32 + mf * 16 + lk * 4 + r;
                float s = 0.0f;
                #pragma unroll
                for (int nfr = 0; nfr < 2; ++nfr) {
                    int nc = (wn * 2 + nfr) * 16 + lm;
                    float v = acc[mf][nfr][r] + zbv[nfr]
                            + unbf(S[m * 128 + ((nc >> 3) ^ (m & 7)) * 8 + (nc & 7)]);
                    v = (v > 0.0f) ? v : 0.2f * v;
                    s = fmaf(v, aw2v[nfr], s);
                }
                s += __shfl_xor(s, 1, 64);
                s += __shfl_xor(s, 2, 64);
                s += __shfl_xor(s, 4, 64);
                s += __shfl_xor(s, 8, 64);
                if (lm == 0) RED[m][wn] = s;
            }
    }
    __syncthreads();

    if (t < 64) {
        attn_raw[e0 + t] = RED[t][0] + RED[t][1] + RED[t][2] + RED[t][3] + ab2[0];
    }
}

// ---------------- fused per-node softmax + hidden(fp8) aggregate ------------
__global__ __launch_bounds__(256) void k_aggr(
    const unsigned char* __restrict__ hid, const float* __restrict__ raw,
    const int* __restrict__ row_start, const int* __restrict__ cnt,
    unsigned short* __restrict__ haggrb)
{
    __shared__ float wbuf[4][64];
    const int l = threadIdx.x & 63;
    const int nib = threadIdx.x >> 6;
    const int n = blockIdx.x * 4 + nib;
    if (n >= NN) return;
    const int rs = row_start[n], deg = cnt[n];

    float a0 = 0.0f, a1 = 0.0f;
    if (deg <= 64) {
        // fast path: raw read once, exp once (deg ~ Poisson(6), always taken)
        float r_l = (l < deg) ? raw[rs + l] : -INFINITY;
        float m = r_l;
        #pragma unroll
        for (int off = 32; off >= 1; off >>= 1) m = fmaxf(m, __shfl_xor(m, off, 64));
        float e_l = (l < deg) ? expf(r_l - m) : 0.0f;
        float s = e_l;
        #pragma unroll
        for (int off = 32; off >= 1; off >>= 1) s += __shfl_xor(s, off, 64);
        wbuf[nib][l] = e_l * (1.0f / (s + 1e-8f));
        // wave-private LDS (wave64 lockstep): no barrier needed
        for (int j = 0; j < deg; ++j) {
            float w = wbuf[nib][j];
            unsigned short v = *reinterpret_cast<const unsigned short*>(
                &hid[(size_t)(rs + j) * DD + l * 2]);
            f32x2 d = f8dec2(v);
            a0 = fmaf(w, d.x, a0);
            a1 = fmaf(w, d.y, a1);
        }
    } else {
        float m = -INFINITY;
        for (int j = l; j < deg; j += 64) m = fmaxf(m, raw[rs + j]);
        #pragma unroll
        for (int off = 32; off >= 1; off >>= 1) m = fmaxf(m, __shfl_xor(m, off, 64));
        float s = 0.0f;
        for (int j = l; j < deg; j += 64) s += expf(raw[rs + j] - m);
        #pragma unroll
        for (int off = 32; off >= 1; off >>= 1) s += __shfl_xor(s, off, 64);
        const float rinv = 1.0f / (s + 1e-8f);
        for (int base = 0; base < deg; base += 64) {
            int ntc = min(64, deg - base);
            if (l < ntc) wbuf[nib][l] = expf(raw[rs + base + l] - m) * rinv;
            for (int j = 0; j < ntc; ++j) {
                float w = wbuf[nib][j];
                unsigned short v = *reinterpret_cast<const unsigned short*>(
                    &hid[(size_t)(rs + base + j) * DD + l * 2]);
                f32x2 d = f8dec2(v);
                a0 = fmaf(w, d.x, a0);
                a1 = fmaf(w, d.y, a1);
            }
        }
    }
    *reinterpret_cast<unsigned int*>(&haggrb[(size_t)n * DD + l * 2]) = pk2(a0, a1);
}

// ---------------- node kernel: GEMM0(mw2) + LN1 + FFN(4 chunks) + LN2 -------
__global__ __launch_bounds__(512) void k_node(
    const float* __restrict__ nf, const unsigned short* __restrict__ haggrb,
    const unsigned short* __restrict__ mw2p, const float* __restrict__ mb2,
    const float* __restrict__ g1, const float* __restrict__ b1,
    const unsigned short* __restrict__ fw1p, const float* __restrict__ fb1,
    const unsigned short* __restrict__ fw2p, const float* __restrict__ fb2,
    const float* __restrict__ g2, const float* __restrict__ b2,
    float* __restrict__ out)
{
    __shared__ alignas(16) unsigned short XB[64 * 128]; // 16 KB
    __shared__ alignas(16) unsigned short HB[64 * 128]; // 16 KB (also HG staging)

    const int t = threadIdx.x;
    const int w = t >> 6, l = t & 63;
    const int wm = w >> 2, wn = w & 3;
    const int lm = l & 15, lk = l >> 4;
    const int lrow = l >> 4, lslot = l & 15;
    const int row = t >> 3;      // 0..63
    const int q = t & 7;         // 16-col segment
    const long n0 = (long)blockIdx.x * 64;
    const long rg = n0 + row;
    const long rc = (rg < NN) ? rg : (NN - 1);

    // ---- stage HG <- haggrb (swizzled src) ----
    unsigned short* HG = HB;
    #pragma unroll
    for (int it = 0; it < 2; ++it) {
        int rb = w * 8 + it * 4;
        int rr = rb + lrow;
        long grow = n0 + rr; if (grow >= NN) grow = NN - 1;
        int c = lslot ^ (rr & 7);
        gload_lds16(haggrb + grow * DD + c * 8, &HG[rb * 128]);
    }
    __syncthreads();

    // ---- GEMM0: aggr = haggr @ mw2 + mb2 -> XB (bf16, swizzled) ----
    {
        f32x4 acc0[2][2];
        #pragma unroll
        for (int mf = 0; mf < 2; ++mf)
            #pragma unroll
            for (int nfr = 0; nfr < 2; ++nfr) acc0[mf][nfr] = (f32x4){0.f, 0.f, 0.f, 0.f};

        #pragma unroll
        for (int ks = 0; ks < 4; ++ks) {
            bf16x8 a[2];
            #pragma unroll
            for (int mf = 0; mf < 2; ++mf) {
                int m = wm * 32 + mf * 16 + lm;
                int slot = (ks * 4 + lk) ^ (m & 7);
                a[mf] = *reinterpret_cast<const bf16x8*>(&HG[m * 128 + slot * 8]);
            }
            #pragma unroll
            for (int nfr = 0; nfr < 2; ++nfr) {
                int nt = wn * 2 + nfr;
                bf16x8 b = *reinterpret_cast<const bf16x8*>(&mw2p[((nt * 4 + ks) * 64 + l) * 8]);
                acc0[0][nfr] = __builtin_amdgcn_mfma_f32_16x16x32_bf16(a[0], b, acc0[0][nfr], 0, 0, 0);
                acc0[1][nfr] = __builtin_amdgcn_mfma_f32_16x16x32_bf16(a[1], b, acc0[1][nfr], 0, 0, 0);
            }
        }
        __syncthreads(); // HG reads done (HB reused by FFN chunks)
        #pragma unroll
        for (int nfr = 0; nfr < 2; ++nfr) {
            int n = (wn * 2 + nfr) * 16 + lm;
            float bv = mb2[n];
            #pragma unroll
            for (int mf = 0; mf < 2; ++mf)
                #pragma unroll
                for (int r = 0; r < 4; ++r) {
                    int m = wm * 32 + mf * 16 + lk * 4 + r;
                    XB[m * 128 + ((n >> 3) ^ (m & 7)) * 8 + (n & 7)] = bf16s(acc0[mf][nfr][r] + bv);
                }
        }
    }
    __syncthreads(); // XB = aggr (bf16)

    // ---- LN1: x = nf + aggr ----
    float xr[16];
    float s = 0.0f, ss = 0.0f;
    {
        const float* xp = nf + rc * DD + q * 16;
        #pragma unroll
        for (int i = 0; i < 2; ++i) {
            int c = q * 2 + i, slot = c ^ (row & 7);
            uint4 v = *reinterpret_cast<const uint4*>(&XB[row * 128 + slot * 8]);
            float f[8];
            f[0] = unlo(v.x); f[1] = unhi(v.x); f[2] = unlo(v.y); f[3] = unhi(v.y);
            f[4] = unlo(v.z); f[5] = unhi(v.z); f[6] = unlo(v.w); f[7] = unhi(v.w);
            float4 a = *reinterpret_cast<const float4*>(xp + i * 8);
            float4 b = *reinterpret_cast<const float4*>(xp + i * 8 + 4);
            float vv[8] = {a.x + f[0], a.y + f[1], a.z + f[2], a.w + f[3],
                           b.x + f[4], b.y + f[5], b.z + f[6], b.w + f[7]};
            #pragma unroll
            for (int j = 0; j < 8; ++j) {
                xr[i * 8 + j] = vv[j];
                s += vv[j];
                ss = fmaf(vv[j], vv[j], ss);
            }
        }
    }
    s  += __shfl_xor(s, 1, 64);  s  += __shfl_xor(s, 2, 64);  s  += __shfl_xor(s, 4, 64);
    ss += __shfl_xor(ss, 1, 64); ss += __shfl_xor(ss, 2, 64); ss += __shfl_xor(ss, 4, 64);
    {
        float mu = s * (1.0f / DD);
        float var = ss * (1.0f / DD) - mu * mu;
        float rstd = rsqrtf(var + 1e-5f);
        #pragma unroll
        for (int i = 0; i < 4; ++i) {
            float4 gv = *reinterpret_cast<const float4*>(g1 + q * 16 + i * 4);
            float4 bv = *reinterpret_cast<const float4*>(b1 + q * 16 + i * 4);
            xr[i * 4 + 0] = (xr[i * 4 + 0] - mu) * rstd * gv.x + bv.x;
            xr[i * 4 + 1] = (xr[i * 4 + 1] - mu) * rstd * gv.y + bv.y;
            xr[i * 4 + 2] = (xr[i * 4 + 2] - mu) * rstd * gv.z + bv.z;
            xr[i * 4 + 3] = (xr[i * 4 + 3] - mu) * rstd * gv.w + bv.w;
        }
        #pragma unroll
        for (int i = 0; i < 2; ++i) {
            int c = q * 2 + i, slot = c ^ (row & 7);
            uint4 v;
            v.x = pk2(xr[i * 8 + 0], xr[i * 8 + 1]);
            v.y = pk2(xr[i * 8 + 2], xr[i * 8 + 3]);
            v.z = pk2(xr[i * 8 + 4], xr[i * 8 + 5]);
            v.w = pk2(xr[i * 8 + 6], xr[i * 8 + 7]);
            *reinterpret_cast<uint4*>(&XB[row * 128 + slot * 8]) = v;
        }
    }
    __syncthreads();

    // ---- FFN: four 128-col chunks of the 512-wide hidden ----
    f32x4 acc2[2][2];
    #pragma unroll
    for (int mf = 0; mf < 2; ++mf)
        #pragma unroll
        for (int nfr = 0; nfr < 2; ++nfr) acc2[mf][nfr] = (f32x4){0.f, 0.f, 0.f, 0.f};

    #pragma unroll
    for (int ch = 0; ch < 4; ++ch) {
        f32x4 acc[2][2];
        #pragma unroll
        for (int mf = 0; mf < 2; ++mf)
            #pragma unroll
            for (int nfr = 0; nfr < 2; ++nfr) acc[mf][nfr] = (f32x4){0.f, 0.f, 0.f, 0.f};

        #pragma unroll
        for (int ks = 0; ks < 4; ++ks) {
            bf16x8 a[2];
            #pragma unroll
            for (int mf = 0; mf < 2; ++mf) {
                int m = wm * 32 + mf * 16 + lm;
                int slot = (ks * 4 + lk) ^ (m & 7);
                a[mf] = *reinterpret_cast<const bf16x8*>(&XB[m * 128 + slot * 8]);
            }
            #pragma unroll
            for (int nfr = 0; nfr < 2; ++nfr) {
                int nt = ch * 8 + wn * 2 + nfr;
                bf16x8 b = *reinterpret_cast<const bf16x8*>(&fw1p[((nt * 4 + ks) * 64 + l) * 8]);
                acc[0][nfr] = __builtin_amdgcn_mfma_f32_16x16x32_bf16(a[0], b, acc[0][nfr], 0, 0, 0);
                acc[1][nfr] = __builtin_amdgcn_mfma_f32_16x16x32_bf16(a[1], b, acc[1][nfr], 0, 0, 0);
            }
        }
        #pragma unroll
        for (int nfr = 0; nfr < 2; ++nfr) {
            int nl = (wn * 2 + nfr) * 16 + lm;
            float bv = fb1[ch * 128 + nl];
            #pragma unroll
            for (int mf = 0; mf < 2; ++mf)
                #pragma unroll
                for (int r = 0; r < 4; ++r) {
                    int m = wm * 32 + mf * 16 + lk * 4 + r;
                    float h = acc[mf][nfr][r] + bv;
                    float e = __expf(h * -1.702f);
                    float gvv = h * __builtin_amdgcn_rcpf(1.0f + e);
                    HB[m * 128 + (((nl >> 3) ^ (m & 7)) * 8) + (nl & 7)] = bf16s(gvv);
                }
        }
        __syncthreads();

        #pragma unroll
        for (int ks = 0; ks < 4; ++ks) {
            bf16x8 a[2];
            #pragma unroll
            for (int mf = 0; mf < 2; ++mf) {
                int m = wm * 32 + mf * 16 + lm;
                int slot = (ks * 4 + lk) ^ (m & 7);
                a[mf] = *reinterpret_cast<const bf16x8*>(&HB[m * 128 + slot * 8]);
            }
            #pragma unroll
            for (int nfr = 0; nfr < 2; ++nfr) {
                int nt = wn * 2 + nfr;
                int kg = ch * 4 + ks;
                bf16x8 b = *reinterpret_cast<const bf16x8*>(&fw2p[((nt * 16 + kg) * 64 + l) * 8]);
                acc2[0][nfr] = __builtin_amdgcn_mfma_f32_16x16x32_bf16(a[0], b, acc2[0][nfr], 0, 0, 0);
                acc2[1][nfr] = __builtin_amdgcn_mfma_f32_16x16x32_bf16(a[1], b, acc2[1][nfr], 0, 0, 0);
            }
        }
        __syncthreads();
    }

    // ---- ffn -> XB (bf16) ----
    #pragma unroll
    for (int nfr = 0; nfr < 2; ++nfr) {
        int n = (wn * 2 + nfr) * 16 + lm;
        float bv = fb2[n];
        #pragma unroll
        for (int mf = 0; mf < 2; ++mf)
            #pragma unroll
            for (int r = 0; r < 4; ++r) {
                int m = wm * 32 + mf * 16 + lk * 4 + r;
                XB[m * 128 + (((n >> 3) ^ (m & 7)) * 8) + (n & 7)] = bf16s(acc2[mf][nfr][r] + bv);
            }
    }
    __syncthreads();

    // ---- residual + LN2 ----
    float s2 = 0.0f, ss2 = 0.0f;
    #pragma unroll
    for (int i = 0; i < 2; ++i) {
        int c = q * 2 + i, slot = c ^ (row & 7);
        uint4 v = *reinterpret_cast<const uint4*>(&XB[row * 128 + slot * 8]);
        float f[8];
        f[0] = unlo(v.x); f[1] = unhi(v.x); f[2] = unlo(v.y); f[3] = unhi(v.y);
        f[4] = unlo(v.z); f[5] = unhi(v.z); f[6] = unlo(v.w); f[7] = unhi(v.w);
        #pragma unroll
        for (int j = 0; j < 8; ++j) {
            float vv = xr[i * 8 + j] + f[j];
            xr[i * 8 + j] = vv;
            s2 += vv;
            ss2 = fmaf(vv, vv, ss2);
        }
    }
    s2  += __shfl_xor(s2, 1, 64);  s2  += __shfl_xor(s2, 2, 64);  s2  += __shfl_xor(s2, 4, 64);
    ss2 += __shfl_xor(ss2, 1, 64); ss2 += __shfl_xor(ss2, 2, 64); ss2 += __shfl_xor(ss2, 4, 64);
    {
        float mu = s2 * (1.0f / DD);
        float var = ss2 * (1.0f / DD) - mu * mu;
        float rstd = rsqrtf(var + 1e-5f);
        if (rg < NN) {
            float* op = out + rg * DD + q * 16;
            #pragma unroll
            for (int i = 0; i < 4; ++i) {
                float4 gv = *reinterpret_cast<const float4*>(g2 + q * 16 + i * 4);
                float4 bv = *reinterpret_cast<const float4*>(b2 + q * 16 + i * 4);
                float4 o;
                o.x = (xr[i * 4 + 0] - mu) * rstd * gv.x + bv.x;
                o.y = (xr[i * 4 + 1] - mu) * rstd * gv.y + bv.y;
                o.z = (xr[i * 4 + 2] - mu) * rstd * gv.z + bv.z;
                o.w = (xr[i * 4 + 3] - mu) * rstd * gv.w + bv.w;
                *reinterpret_cast<float4*>(op + i * 4) = o;
            }
        }
    }
}

extern "C" void kernel_launch(void* const* d_in, const int* in_sizes, int n_in,
                              void* d_out, int out_size, void* d_ws, size_t ws_size,
                              hipStream_t stream)
{
    const float* nf  = (const float*)d_in[0];
    const int*   ei  = (const int*)d_in[1];
    const int*   et  = (const int*)d_in[2];
    const float* rel = (const float*)d_in[3];
    const float* mw1 = (const float*)d_in[4];
    const float* mb1 = (const float*)d_in[5];
    const float* mw2 = (const float*)d_in[6];
    const float* mb2 = (const float*)d_in[7];
    const float* aw1 = (const float*)d_in[8];
    const float* ab1 = (const float*)d_in[9];
    const float* aw2 = (const float*)d_in[10];
    const float* ab2 = (const float*)d_in[11];
    const float* g1  = (const float*)d_in[12];
    const float* b1  = (const float*)d_in[13];
    const float* fw1 = (const float*)d_in[14];
    const float* fb1 = (const float*)d_in[15];
    const float* fw2 = (const float*)d_in[16];
    const float* fb2 = (const float*)d_in[17];
    const float* g2  = (const float*)d_in[18];
    const float* b2  = (const float*)d_in[19];
    float* out = (float*)d_out;

    char* ws = (char*)d_ws;
    size_t off = 0;
    auto alloc = [&](size_t bytes) -> char* {
        char* p = ws + off;
        off += (bytes + 255) & ~(size_t)255;
        return p;
    };
    unsigned char* hid = (unsigned char*)alloc((size_t)NE * DD);
    float* attn_raw = (float*)alloc((size_t)NE * 4);
    unsigned short* haggrb = (unsigned short*)alloc((size_t)NN * DD * 2);
    unsigned short* nfa = (unsigned short*)alloc((size_t)NN * DD * 2);
    unsigned short* nfb = (unsigned short*)alloc((size_t)NN * DD * 2);
    unsigned short* relcb = (unsigned short*)alloc((size_t)RR * DD * 2);
    float* zb  = (float*)alloc((size_t)128 * 4);
    int* cnt       = (int*)alloc((size_t)NN * 4);
    int* row_start = (int*)alloc((size_t)NN * 4);
    int* cursor    = (int*)alloc((size_t)NN * 4);
    int* srcs      = (int*)alloc((size_t)NE * 4);
    int* ets       = (int*)alloc((size_t)NE * 4);
    int* dsts      = (int*)alloc((size_t)NE * 4);
    int* bsum      = (int*)alloc((size_t)SCAN_NB * 4);
    unsigned short* mw1p = (unsigned short*)alloc(16384 * 2);
    unsigned short* mw2p = (unsigned short*)alloc(16384 * 2);
    unsigned short* awTp = (unsigned short*)alloc(16384 * 2);
    unsigned short* mwBp = (unsigned short*)alloc(16384 * 2);
    unsigned short* fw1p = (unsigned short*)alloc(65536 * 2);
    unsigned short* fw2p = (unsigned short*)alloc(65536 * 2);

    const int* srcp = ei;
    const int* dstp = ei + NE;

    hipLaunchKernelGGL(k_setup, dim3(1260), dim3(256), 0, stream,
                       mw1, mb1, mw2, mb2, aw1, rel, fw1, fw2,
                       mw1p, mw2p, awTp, mwBp, fw1p, fw2p, relcb, zb, cnt);
    hipLaunchKernelGGL(k_hist, dim3((NE + 255) / 256), dim3(256), 0, stream, dstp, cnt);
    hipLaunchKernelGGL(k_scanA, dim3(SCAN_NB), dim3(256), 0, stream, cnt, bsum);
    hipLaunchKernelGGL(k_scanB, dim3(1), dim3(512), 0, stream, bsum);
    hipLaunchKernelGGL(k_scanC, dim3(SCAN_NB), dim3(256), 0, stream, cnt, bsum, row_start, cursor);
    hipLaunchKernelGGL(k_bucket, dim3((NE + 255) / 256), dim3(256), 0, stream,
                       srcp, dstp, et, cursor, srcs, ets, dsts);
    hipLaunchKernelGGL(k_prepnfa, dim3((NN + 63) / 64), dim3(256), 0, stream,
                       nf, awTp, ab1, nfb, nfa);
    hipLaunchKernelGGL(k_edge, dim3(NE / 64), dim3(512), 0, stream,
                       nfb, srcs, dsts, ets, nfa, relcb,
                       mw1p, mwBp, zb, aw2, ab2,
                       hid, attn_raw);
    hipLaunchKernelGGL(k_aggr, dim3((NN + 3) / 4), dim3(256), 0, stream,
                       hid, attn_raw, row_start, cnt, haggrb);
    hipLaunchKernelGGL(k_node, dim3((NN + 63) / 64), dim3(512), 0, stream,
                       nf, haggrb, mw2p, mb2, g1, b1, fw1p, fb1, fw2p, fb2, g2, b2, out);
}